// Round 13
// baseline (451.778 us; speedup 1.0000x reference)
//
#include <hip/hip_runtime.h>
#include <cmath>

#define HW 32768      // H*W
#define NC 128        // chunks per batch (HW/256)
#define NH 2          // heads
#define B4 4          // batch (num groups)

typedef __attribute__((ext_vector_type(8))) short bf16x8;
typedef __attribute__((ext_vector_type(4))) float f32x4;
typedef __attribute__((ext_vector_type(4))) ushort u16x4;
typedef __attribute__((ext_vector_type(8))) ushort u16x8;

__device__ __forceinline__ ushort f2b(float x) {
  union { float f; unsigned u; } v; v.f = x;
  unsigned r = v.u + 0x7FFFu + ((v.u >> 16) & 1u);   // RNE
  return (ushort)(r >> 16);
}
__device__ __forceinline__ float b2f(ushort b) {
  union { unsigned u; float f; } v; v.u = ((unsigned)b) << 16;
  return v.f;
}
// XOR-swizzle of element index k within a row (bf16 tiles, 16B-group spread)
__device__ __forceinline__ int swz(int row, int k) { return k ^ ((row & 7) << 3); }
// A-frag: row-major [M][K] (K contig); B-frag: [N][K] (i.e. B^T row-major).
__device__ __forceinline__ bf16x8 ldfrag(const ushort* base, int row, int k, int stride) {
  return *(const bf16x8*)(base + row * stride + swz(row, k));
}

// ---------------------------------------------------------------------------
// K1a (MFMA): score MLP via split-precision weights.
// ---------------------------------------------------------------------------
__global__ __launch_bounds__(256) void k_score_mfma(
    const float* __restrict__ xx, const float* __restrict__ w1,
    const float* __restrict__ b1, const float* __restrict__ w2,
    const float* __restrict__ b2, float* __restrict__ scores,
    int* __restrict__ cnt)
{
  __shared__ ushort Whi[64*64];     // [d][c] swizzled
  __shared__ ushort Wlo[64*64];
  __shared__ ushort Xt[4][64*64];   // per-wave [t][c] swizzled
  __shared__ float w2b1[128];       // w2[0..63] | b1[64..127]
  int tid = threadIdx.x;
  if (blockIdx.x == 0 && tid == 0) cnt[0] = 0;
  for (int i = tid; i < 4096; i += 256) {
    int d = i >> 6, c = i & 63;
    float v = w1[i];
    ushort hi = f2b(v);
    int off = d*64 + swz(d, c);
    Whi[off] = hi;
    Wlo[off] = f2b(v - b2f(hi));
  }
  if (tid < 64) { w2b1[tid] = w2[tid]; w2b1[64+tid] = b1[tid]; }

  int wid = tid >> 6, lane = tid & 63;
  int n  = blockIdx.x >> 7;             // 1792 blocks = 14 n x 128 tiles
  int t0 = (blockIdx.x & 127)*256 + wid*64;

  {
    const float* px = xx + (size_t)n*64*HW + t0 + lane;
    float xv[64];
    #pragma unroll
    for (int c = 0; c < 64; ++c) xv[c] = px[(size_t)c*HW];
    ushort* xh = Xt[wid];
    #pragma unroll
    for (int c8 = 0; c8 < 8; ++c8) {
      u16x8 p;
      #pragma unroll
      for (int j = 0; j < 8; ++j) p[j] = f2b(xv[c8*8 + j]);
      *(u16x8*)(xh + lane*64 + swz(lane, c8*8)) = p;
    }
  }
  __syncthreads();

  int lr = lane & 15, kb = lane >> 4;
  const ushort* xh = Xt[wid];
  f32x4 acc[4][4];
  #pragma unroll
  for (int m = 0; m < 4; ++m)
    #pragma unroll
    for (int nt = 0; nt < 4; ++nt) acc[m][nt] = (f32x4){0.f,0.f,0.f,0.f};
  #pragma unroll
  for (int k0 = 0; k0 < 64; k0 += 32) {
    bf16x8 ah[4], al[4], bx[4];
    #pragma unroll
    for (int m = 0; m < 4; ++m) {
      ah[m] = ldfrag(Whi, 16*m + lr, k0 + kb*8, 64);
      al[m] = ldfrag(Wlo, 16*m + lr, k0 + kb*8, 64);
    }
    #pragma unroll
    for (int nt = 0; nt < 4; ++nt) bx[nt] = ldfrag(xh, 16*nt + lr, k0 + kb*8, 64);
    #pragma unroll
    for (int m = 0; m < 4; ++m)
      #pragma unroll
      for (int nt = 0; nt < 4; ++nt) {
        acc[m][nt] = __builtin_amdgcn_mfma_f32_16x16x32_bf16(ah[m], bx[nt], acc[m][nt], 0, 0, 0);
        acc[m][nt] = __builtin_amdgcn_mfma_f32_16x16x32_bf16(al[m], bx[nt], acc[m][nt], 0, 0, 0);
      }
  }
  float bb2 = b2[0];
  #pragma unroll
  for (int nt = 0; nt < 4; ++nt) {
    float s = 0.f;
    #pragma unroll
    for (int m = 0; m < 4; ++m)
      #pragma unroll
      for (int r = 0; r < 4; ++r) {
        int d = 16*m + kb*4 + r;
        float h = acc[m][nt][r] + w2b1[64 + d];
        s += fmaxf(h, 0.f) * w2b1[d];
      }
    s += __shfl_xor(s, 16);
    s += __shfl_xor(s, 32);
    if (kb == 0) scores[(size_t)n*HW + t0 + 16*nt + lr] = s + bb2;
  }
}

// ---------------------------------------------------------------------------
// K1b: per-(group,pixel) first-max argmax over fp32 scores; flag near-ties.
// ---------------------------------------------------------------------------
__global__ __launch_bounds__(256) void k_argmax(
    const float* __restrict__ scores, int* __restrict__ idx,
    int* __restrict__ cnt, int* __restrict__ list)
{
  int i = blockIdx.x*256 + threadIdx.x;      // 512 blocks: 4*HW
  int g = i >> 15, t = i & (HW-1);
  const int gs0[4] = {0,5,8,12};
  const int gl0[4] = {5,3,4,2};
  int start = gs0[g], len = gl0[g];
  float best = scores[(size_t)start*HW + t];
  float second = -3.4e38f;
  int bi = start;
  for (int j = 1; j < len; ++j) {
    float s = scores[(size_t)(start+j)*HW + t];
    if (s > best) { second = best; best = s; bi = start + j; }
    else if (s > second) second = s;
  }
  idx[i] = bi;
  if (best - second < 5e-4f) {
    int p = atomicAdd(cnt, 1);
    list[p] = i;
  }
}

// ---------------------------------------------------------------------------
// K1c: fp64 recompute of flagged pixels, ONE WAVE PER ENTRY.
// ---------------------------------------------------------------------------
__global__ __launch_bounds__(256) void k_fix(
    const float* __restrict__ xx, const float* __restrict__ w1,
    const float* __restrict__ b1, const float* __restrict__ w2,
    const float* __restrict__ b2, const int* __restrict__ cnt,
    const int* __restrict__ list, int* __restrict__ idx)
{
  __shared__ float w1f[64*65];     // [d][c] padded -> 2-way bank (free)
  __shared__ float w2f[64], b1f[64];
  int tid = threadIdx.x;
  for (int i = tid; i < 4096; i += 256) w1f[(i >> 6)*65 + (i & 63)] = w1[i];
  if (tid < 64) { w2f[tid] = w2[tid]; b1f[tid] = b1[tid]; }
  __syncthreads();
  int n = cnt[0];
  int wid = tid >> 6, lane = tid & 63;
  int nwaves = gridDim.x * 4;
  const int gs0[4] = {0,5,8,12};
  const int gl0[4] = {5,3,4,2};
  double b2d = (double)b2[0];
  for (int e = blockIdx.x*4 + wid; e < n; e += nwaves) {
    int i = list[e];
    int g = i >> 15, t = i & (HW-1);
    int start = gs0[g], len = gl0[g];
    double best = -1e300;
    int bi = start;
    for (int j = 0; j < len; ++j) {
      double xv = (double)xx[(size_t)(start+j)*64*HW + (size_t)lane*HW + t];
      double acc = (double)b1f[lane];
      #pragma unroll
      for (int c = 0; c < 64; ++c) {
        double xc = __shfl(xv, c);
        acc += xc * (double)w1f[lane*65 + c];
      }
      double sc = (acc > 0.0 ? acc : 0.0) * (double)w2f[lane];
      #pragma unroll
      for (int m = 1; m < 64; m <<= 1) sc += __shfl_xor(sc, m);
      sc += b2d;
      if (sc > best) { best = sc; bi = start + j; }   // first-max
    }
    if (lane == 0) idx[i] = bi;
  }
}

// ---------------------------------------------------------------------------
// K2: gather winner (from idx) + transpose to token-major seq.
// ---------------------------------------------------------------------------
__global__ __launch_bounds__(256) void k_fuse(
    const float* __restrict__ xx, const int* __restrict__ idx,
    float* __restrict__ seq)
{
  __shared__ int idxs[64];
  __shared__ float tile[64*65];
  int tid = threadIdx.x;
  int g  = blockIdx.x >> 9;
  int t0 = (blockIdx.x & 511) << 6;
  if (tid < 64) idxs[tid] = idx[(size_t)g*HW + t0 + tid];
  __syncthreads();
  int tl = tid & 63, cq = tid >> 6;
  for (int r = 0; r < 16; ++r) {
    int c = r*4 + cq;
    tile[c*65 + tl] = xx[(size_t)idxs[tl]*64*HW + (size_t)c*HW + t0 + tl];
  }
  __syncthreads();
  for (int r = 0; r < 16; ++r) {
    int row = r*4 + cq;
    seq[((size_t)g*HW + t0 + row)*64 + tl] = tile[tl*65 + row];
  }
}

// ---------------------------------------------------------------------------
// K3: ctx = seq @ v_w^T + v_b; u = LayerNorm(...) -> PRE-SWIZZLED bf16 usw.
// ---------------------------------------------------------------------------
__global__ __launch_bounds__(256) void k_vln(
    const float* __restrict__ seq, const float* __restrict__ vw,
    const float* __restrict__ vb, const float* __restrict__ lnw,
    const float* __restrict__ lnb, float* __restrict__ ctx,
    ushort* __restrict__ usw)
{
  __shared__ float st[64*64];
  int tid = threadIdx.x;
  size_t p0 = (size_t)blockIdx.x * 64;
  for (int i = tid; i < 64*64; i += 256) st[i] = seq[p0*64 + i];
  int o = tid & 63, wv = tid >> 6;
  float w[64];
  const float4* w4 = (const float4*)(vw + o*64);
  #pragma unroll
  for (int c4 = 0; c4 < 16; ++c4) {
    float4 v = w4[c4];
    w[c4*4+0]=v.x; w[c4*4+1]=v.y; w[c4*4+2]=v.z; w[c4*4+3]=v.w;
  }
  float bias = vb[o], lw = lnw[o], lb = lnb[o];
  __syncthreads();
  const float4* st4 = (const float4*)st;
  for (int j = 0; j < 16; ++j) {
    int p = wv*16 + j;
    float acc = bias;
    #pragma unroll
    for (int c4 = 0; c4 < 16; ++c4) {
      float4 s4 = st4[p*16 + c4];
      acc += s4.x*w[c4*4] + s4.y*w[c4*4+1] + s4.z*w[c4*4+2] + s4.w*w[c4*4+3];
    }
    float s1 = acc, s2 = acc*acc;
    #pragma unroll
    for (int m = 1; m < 64; m <<= 1) {
      s1 += __shfl_xor(s1, m);
      s2 += __shfl_xor(s2, m);
    }
    float mu  = s1*(1.f/64.f);
    float var = s2*(1.f/64.f) - mu*mu;
    float rstd = rsqrtf(var + 1e-5f);
    size_t base = (p0+p)*64;
    int gt = (int)(p0 + p);
    ctx[base + o] = acc;
    usw[base + (o ^ (((gt+3)&7)<<3))] = f2b((acc - mu)*rstd*lw + lb);
  }
}

// ---------------------------------------------------------------------------
// k_prep: ipw -> bf16 pre-swizzled wsw (rows >=386 zeroed; 400x64).
// ---------------------------------------------------------------------------
__global__ __launch_bounds__(256) void k_prep(
    const float* __restrict__ ipw, ushort* __restrict__ wsw)
{
  int i = blockIdx.x*256 + threadIdx.x;   // 100*256 = 25600 = 400*64
  int row = i >> 6, c = i & 63;
  float v = (row < 386) ? ipw[row*64 + c] : 0.f;
  wsw[row*64 + swz(row, c)] = f2b(v);
}

// ---------------------------------------------------------------------------
// k_gemm: in_proj GEMM (M=80 rows incl 3-halo, N=400, K=64). 8 waves.
// xbc output TILE-BLOCKED: xbcB[b][s][ch][64].
// ---------------------------------------------------------------------------
__global__ __launch_bounds__(512) void k_gemm(
    const ushort* __restrict__ usw, const ushort* __restrict__ wsw,
    const float* __restrict__ ipb, const float* __restrict__ dtbias,
    ushort* __restrict__ z, ushort* __restrict__ xbcB, float* __restrict__ dt)
{
  __shared__ ushort Wlds[400*64];   // 51200 B (pre-swizzled copy)
  __shared__ ushort Ulds[80*64];    // 10240 B
  __shared__ ushort trans[8704];    // 17408 B
  int tid = threadIdx.x;
  int b  = blockIdx.x >> 9;
  int s  = blockIdx.x & 511;
  int t0 = s << 6;
  size_t pixbase = (size_t)b*HW + t0;
  size_t tilebase = ((size_t)(b*512 + s))*256*64;

  for (int i = tid; i < 3200; i += 512)
    *(u16x8*)(Wlds + i*8) = *(const u16x8*)(wsw + i*8);
  {
    const ushort* ubase = usw + ((size_t)b*HW + t0 - 3)*64;
    for (int i = tid; i < 536; i += 512) {     // 536*8 = 67*64
      u16x8 v;
      if (t0 == 0 && i < 24) v = (u16x8){0,0,0,0,0,0,0,0};
      else v = *(const u16x8*)(ubase + i*8);
      *(u16x8*)(Ulds + i*8) = v;
    }
  }
  __syncthreads();

  int w = tid >> 6, lane = tid & 63, lr = lane & 15, kb = lane >> 4;
  for (int rd = 0; rd < 3; ++rd) {
    int nt = rd*8 + w;
    f32x4 acc[5];
    #pragma unroll
    for (int mt = 0; mt < 5; ++mt) acc[mt] = (f32x4){0.f,0.f,0.f,0.f};
    #pragma unroll
    for (int kk = 0; kk < 64; kk += 32) {
      bf16x8 bfrag = ldfrag(Wlds, nt*16 + lr, kk + kb*8, 64);
      #pragma unroll
      for (int mt = 0; mt < 5; ++mt) {
        bf16x8 afrag = ldfrag(Ulds, mt*16 + lr, kk + kb*8, 64);
        acc[mt] = __builtin_amdgcn_mfma_f32_16x16x32_bf16(afrag, bfrag, acc[mt], 0, 0, 0);
      }
    }
    float bias = ipb[nt*16 + lr];
    if (rd == 0) {          // z channels: trans[t][132]
      #pragma unroll
      for (int mt = 0; mt < 5; ++mt)
        #pragma unroll
        for (int r = 0; r < 4; ++r) {
          int t = mt*16 + kb*4 + r - 3;
          if (t >= 0 && t < 64) trans[t*132 + w*16 + lr] = f2b(acc[mt][r] + bias);
        }
    } else {                // xbc channels: trans[ch][68]
      #pragma unroll
      for (int mt = 0; mt < 5; ++mt)
        #pragma unroll
        for (int r = 0; r < 4; ++r) {
          int t = mt*16 + kb*4 + r - 3;
          if (t >= 0 && t < 64) trans[(w*16 + lr)*68 + t] = f2b(acc[mt][r] + bias);
        }
    }
    __syncthreads();
    if (rd == 0) {
      for (int i = tid; i < 2048; i += 512) {
        int t = i >> 5, c4 = (i & 31)*4;
        *(u16x4*)(z + (pixbase + t)*128 + c4) = *(const u16x4*)(trans + t*132 + c4);
      }
    } else {
      int chbase = (rd - 1)*128;
      for (int i = tid; i < 2048; i += 512) {   // contiguous 4 KB per pass
        int ch = i >> 4, t4 = (i & 15)*4;
        *(u16x4*)(xbcB + tilebase + (size_t)(chbase + ch)*64 + t4)
            = *(const u16x4*)(trans + ch*68 + t4);
      }
    }
    __syncthreads();
  }

  if (w == 0) {    // dt rows 384/385
    f32x4 acc[5];
    #pragma unroll
    for (int mt = 0; mt < 5; ++mt) acc[mt] = (f32x4){0.f,0.f,0.f,0.f};
    #pragma unroll
    for (int kk = 0; kk < 64; kk += 32) {
      bf16x8 bfrag = ldfrag(Wlds, 384 + lr, kk + kb*8, 64);
      #pragma unroll
      for (int mt = 0; mt < 5; ++mt) {
        bf16x8 afrag = ldfrag(Ulds, mt*16 + lr, kk + kb*8, 64);
        acc[mt] = __builtin_amdgcn_mfma_f32_16x16x32_bf16(afrag, bfrag, acc[mt], 0, 0, 0);
      }
    }
    if (lr < 2) {
      float bias = ipb[384 + lr] + dtbias[lr];
      #pragma unroll
      for (int mt = 0; mt < 5; ++mt)
        #pragma unroll
        for (int r = 0; r < 4; ++r) {
          int t = mt*16 + kb*4 + r - 3;
          if (t >= 0 && t < 64) {
            float a = acc[mt][r] + bias;
            dt[(pixbase + t)*2 + lr] = (a > 20.f) ? a : log1pf(expf(a));
          }
        }
    }
  }
}

// ---------------------------------------------------------------------------
// k_conv: depthwise conv(K=4)+silu from tile-blocked xbcB -> co2 tile-blocked;
// Bm/Cm token-major via bank-swizzled LDS transpose.
// ---------------------------------------------------------------------------
__global__ __launch_bounds__(256) void k_conv(
    const ushort* __restrict__ xbcB, const float* __restrict__ convw,
    const float* __restrict__ convb, ushort* __restrict__ co2,
    ushort* __restrict__ Bm, ushort* __restrict__ Cm)
{
  __shared__ ushort bmc[64*132];    // [t][128] swizzled: col = c ^ ((t>>3)<<2)
  int tid = threadIdx.x;
  int b  = blockIdx.x >> 9;
  int s  = blockIdx.x & 511;
  int lane = tid & 63, wv = tid >> 6;
  int toct = lane & 7, chi = lane >> 3;
  size_t tilebase = ((size_t)(b*512 + s))*256*64;
  const ushort* tsrc = xbcB + tilebase;
  const ushort* psrc = xbcB + tilebase - 256*64;   // prev tile (valid if s>0)

  for (int it = 0; it < 8; ++it) {
    int ch = wv*64 + it*8 + chi;
    u16x8 v = *(const u16x8*)(tsrc + ch*64 + toct*8);
    float x0 = b2f(v[0]), x1 = b2f(v[1]), x2 = b2f(v[2]), x3 = b2f(v[3]);
    float x4 = b2f(v[4]), x5 = b2f(v[5]), x6 = b2f(v[6]), x7 = b2f(v[7]);
    float pm1 = __shfl(x7, lane - 1);
    float pm2 = __shfl(x6, lane - 1);
    float pm3 = __shfl(x5, lane - 1);
    if (toct == 0) {
      if (s > 0) {
        u16x4 hq = *(const u16x4*)(psrc + ch*64 + 60);
        pm3 = b2f(hq[1]); pm2 = b2f(hq[2]); pm1 = b2f(hq[3]);
      } else {
        pm1 = pm2 = pm3 = 0.f;
      }
    }
    float4 cw = ((const float4*)convw)[ch];
    float cb = convb[ch];
    float o0 = cb + cw.x*pm3 + cw.y*pm2 + cw.z*pm1 + cw.w*x0;
    float o1 = cb + cw.x*pm2 + cw.y*pm1 + cw.z*x0  + cw.w*x1;
    float o2 = cb + cw.x*pm1 + cw.y*x0  + cw.z*x1  + cw.w*x2;
    float o3 = cb + cw.x*x0  + cw.y*x1  + cw.z*x2  + cw.w*x3;
    float o4 = cb + cw.x*x1  + cw.y*x2  + cw.z*x3  + cw.w*x4;
    float o5 = cb + cw.x*x2  + cw.y*x3  + cw.z*x4  + cw.w*x5;
    float o6 = cb + cw.x*x3  + cw.y*x4  + cw.z*x5  + cw.w*x6;
    float o7 = cb + cw.x*x4  + cw.y*x5  + cw.z*x6  + cw.w*x7;
    u16x8 ov;
    ov[0] = f2b(o0 / (1.f + __expf(-o0)));
    ov[1] = f2b(o1 / (1.f + __expf(-o1)));
    ov[2] = f2b(o2 / (1.f + __expf(-o2)));
    ov[3] = f2b(o3 / (1.f + __expf(-o3)));
    ov[4] = f2b(o4 / (1.f + __expf(-o4)));
    ov[5] = f2b(o5 / (1.f + __expf(-o5)));
    ov[6] = f2b(o6 / (1.f + __expf(-o6)));
    ov[7] = f2b(o7 / (1.f + __expf(-o7)));
    *(u16x8*)(co2 + tilebase + (size_t)ch*64 + toct*8) = ov;
    if (ch >= 128) {
      int c = ch - 128;
      int csw = c ^ (toct << 2);
      #pragma unroll
      for (int j = 0; j < 8; ++j)
        bmc[(toct*8 + j)*132 + csw] = ov[j];
    }
  }
  __syncthreads();
  size_t tg = (size_t)b*HW + s*64;
  for (int i = tid; i < 1024; i += 256) {
    int tt = i >> 4, n4 = (i & 15)*4;
    int sw = (tt >> 3) << 2;
    *(u16x4*)(Bm + (tg + tt)*64 + n4) = *(const u16x4*)(bmc + tt*132 + (n4 ^ sw));
    *(u16x4*)(Cm + (tg + tt)*64 + n4) = *(const u16x4*)(bmc + tt*132 + ((64 + n4) ^ sw));
  }
}

// ---------------------------------------------------------------------------
// K5 (MFMA): states[p,n] = sum_l xd[l,p]*B[l,n]. Reads tile-blocked co2.
// ---------------------------------------------------------------------------
__global__ __launch_bounds__(256) void k_states(
    const float* __restrict__ dt, const ushort* __restrict__ co2,
    const float* __restrict__ A_log,
    float* __restrict__ states, float* __restrict__ A_last)
{
  extern __shared__ char smem[];
  float* ac  = (float*)smem;            // 256
  float* dec = ac + 256;                // 256
  ushort* xdT = (ushort*)(dec + 256);   // 64 x 256
  ushort* BT  = xdT + 16384;            // 64 x 256
  int tid = threadIdx.x;
  int ci = blockIdx.x, h = blockIdx.y, b = blockIdx.z;
  size_t tg = (size_t)b*HW + (size_t)ci*256;
  float Aneg = -expf(A_log[h]);
  float dv = dt[(tg + tid)*2 + h];
  ac[tid] = dv*Aneg;
  __syncthreads();
  for (int off = 1; off < 256; off <<= 1) {
    float v = (tid >= off) ? ac[tid - off] : 0.f;
    __syncthreads();
    ac[tid] += v;
    __syncthreads();
  }
  float alast = ac[255];
  dec[tid] = dv * __expf(alast - ac[tid]);
  __syncthreads();
  for (int i = tid; i < 64*32; i += 256) {
    int p = i >> 5, lc = (i & 31) * 8;
    int s = (ci << 2) + (lc >> 6);
    const ushort* cb2 = co2 + ((size_t)(b*512 + s))*256*64 + (lc & 63);
    u16x8 xv = *(const u16x8*)(cb2 + (size_t)(h*64 + p)*64);
    u16x8 o;
    #pragma unroll
    for (int e = 0; e < 8; ++e) o[e] = f2b(b2f(xv[e]) * dec[lc + e]);
    *(u16x8*)(xdT + p*256 + swz(p, lc)) = o;
    u16x8 bv = *(const u16x8*)(cb2 + (size_t)(128 + p)*64);
    *(u16x8*)(BT + p*256 + swz(p, lc)) = bv;
  }
  __syncthreads();
  int w = tid >> 6, lane = tid & 63, lr = lane & 15, kb = lane >> 4;
  f32x4 acc[4];
  #pragma unroll
  for (int m = 0; m < 4; ++m) acc[m] = (f32x4){0.f,0.f,0.f,0.f};
  for (int k0 = 0; k0 < 256; k0 += 32) {
    bf16x8 bfrag = ldfrag(BT, 16*w + lr, k0 + kb*8, 256);
    #pragma unroll
    for (int m = 0; m < 4; ++m) {
      bf16x8 afrag = ldfrag(xdT, 16*m + lr, k0 + kb*8, 256);
      acc[m] = __builtin_amdgcn_mfma_f32_16x16x32_bf16(afrag, bfrag, acc[m], 0, 0, 0);
    }
  }
  size_t sb = (((size_t)b*NC + ci)*NH + h)*4096;
  #pragma unroll
  for (int m = 0; m < 4; ++m)
    #pragma unroll
    for (int r = 0; r < 4; ++r)
      states[sb + (size_t)(16*m + kb*4 + r)*64 + 16*w + lr] = acc[m][r];
  if (tid == 0) A_last[((size_t)b*NH + h)*NC + ci] = alast;
}

// ---------------------------------------------------------------------------
// K6: inter-chunk scan with prefetch; 64 blocks (b,h,seg).
// ---------------------------------------------------------------------------
__global__ __launch_bounds__(256) void k_scan(
    const float* __restrict__ states, const float* __restrict__ A_last,
    float* __restrict__ states_in)
{
  __shared__ float ef[NC];
  int tid = threadIdx.x;
  int seg = blockIdx.x & 7, h = (blockIdx.x >> 3) & 1, b = blockIdx.x >> 4;
  if (tid < NC) ef[tid] = __expf(A_last[((size_t)b*NH + h)*NC + tid]);
  __syncthreads();
  size_t base0 = (((size_t)b*NC)*NH + h)*4096 + seg*512 + tid;
  const size_t cstride = (size_t)NH*4096;
  float s0 = 0.f, s1 = 0.f;
  float ld0 = states[base0], ld1 = states[base0 + 256];
  for (int zc = 0; zc < NC; ++zc) {
    size_t cur = base0 + (size_t)zc*cstride;
    float n0 = 0.f, n1 = 0.f;
    if (zc < NC-1) { n0 = states[cur + cstride]; n1 = states[cur + cstride + 256]; }
    states_in[cur] = s0; states_in[cur + 256] = s1;
    float e = ef[zc];
    s0 = ld0 + e*s0; s1 = ld1 + e*s1;
    ld0 = n0; ld1 = n1;
  }
}

// ---------------------------------------------------------------------------
// K7 (MFMA): per chunk-head SSD Y.  y -> bf16.  512 thr / 8 waves.
// LDS only for C-tile + per-wave W' (stride-72, 16B-aligned rows). B, S_in,
// xs fragments read DIRECTLY from global (L2-hot); dt folded into W'.
// 70 KB LDS -> 2 blocks/CU. Barrier-free s-loop.
// ---------------------------------------------------------------------------
__global__ __launch_bounds__(512) void k_ydiag(
    const float* __restrict__ dt, const ushort* __restrict__ co2,
    const ushort* __restrict__ Bm, const ushort* __restrict__ Cm,
    const float* __restrict__ states_in, const float* __restrict__ A_log,
    const float* __restrict__ ssd_D, ushort* __restrict__ y)
{
  extern __shared__ char smem[];
  float* ac   = (float*)smem;           // 256
  float* dts  = ac + 256;               // 256
  float* segs = dts + 256;              // 8 (4 used)
  ushort* Cb  = (ushort*)(segs + 8);    // 256 x 64   [l][n] swizzled
  ushort* Wb  = Cb + 16384;             // 8 x (32 x 72) per-wave [l][s]
  int tid = threadIdx.x;
  int ci = blockIdx.x, h = blockIdx.y, b = blockIdx.z;
  size_t tg = (size_t)b*HW + (size_t)ci*256;
  int w = tid >> 6, lane = tid & 63, lr = lane & 15, kb = lane >> 4;
  float Aneg = -expf(A_log[h]);

  // cumsum of dt*A: per-wave shfl scan + segment combine
  float dv = 0.f, a = 0.f;
  if (tid < 256) {
    dv = dt[(tg + tid)*2 + h];
    a = dv*Aneg;
    #pragma unroll
    for (int d = 1; d < 64; d <<= 1) {
      float t = __shfl_up(a, d);
      if (lane >= d) a += t;
    }
    if (lane == 63) segs[w] = a;
  }
  __syncthreads();
  if (tid < 256) {
    float off = 0.f;
    #pragma unroll
    for (int j = 0; j < 4; ++j) if (j < w) off += segs[j];
    ac[tid] = a + off;
    dts[tid] = dv;
  }
  // stage C tile only
  for (int i = tid; i < 256*16; i += 512) {
    int l = i >> 4, n4 = (i & 15) * 4;
    u16x4 cv = *(const u16x4*)(Cm + (tg + l)*64 + n4);
    *(u16x4*)(Cb + l*64 + swz(l, n4)) = cv;
  }
  __syncthreads();

  int l0 = w*32;
  ushort* Ww = Wb + w*2304;   // 32 x 72
  size_t sbg = (((size_t)b*NC + ci)*NH + h)*4096;
  const ushort* ct0 = co2 + ((size_t)(b*512 + (ci << 2)))*16384 + (size_t)h*4096;

  // Y2 = C @ S_in^T (S_in from global fp32, converted in-register)
  f32x4 yy[2][4];
  #pragma unroll
  for (int m = 0; m < 2; ++m)
    #pragma unroll
    for (int n = 0; n < 4; ++n) yy[m][n] = (f32x4){0.f,0.f,0.f,0.f};
  #pragma unroll
  for (int kk = 0; kk < 64; kk += 32) {
    bf16x8 af[2], bf[4];
    #pragma unroll
    for (int m = 0; m < 2; ++m) af[m] = ldfrag(Cb, l0 + 16*m + lr, kk + kb*8, 64);
    #pragma unroll
    for (int n = 0; n < 4; ++n) {
      const float4* sp = (const float4*)(states_in + sbg + (size_t)(16*n + lr)*64 + kk + kb*8);
      float4 s1 = sp[0], s2 = sp[1];
      u16x8 pk;
      pk[0]=f2b(s1.x); pk[1]=f2b(s1.y); pk[2]=f2b(s1.z); pk[3]=f2b(s1.w);
      pk[4]=f2b(s2.x); pk[5]=f2b(s2.y); pk[6]=f2b(s2.z); pk[7]=f2b(s2.w);
      bf[n] = *(bf16x8*)&pk;
    }
    #pragma unroll
    for (int m = 0; m < 2; ++m)
      #pragma unroll
      for (int n = 0; n < 4; ++n)
        yy[m][n] = __builtin_amdgcn_mfma_f32_16x16x32_bf16(af[m], bf[n], yy[m][n], 0, 0, 0);
  }
  #pragma unroll
  for (int m = 0; m < 2; ++m)
    #pragma unroll
    for (int r = 0; r < 4; ++r) {
      float e = __expf(ac[l0 + 16*m + kb*4 + r]);
      #pragma unroll
      for (int n = 0; n < 4; ++n) yy[m][n][r] *= e;
    }

  // s-tile loop (wave-local, no barriers; W' = tril-decay * G * dts[s])
  int nst = (w >> 1) + 1;
  for (int st = 0; st < nst; ++st) {
    int s0 = st*64;
    f32x4 g[2][4];
    #pragma unroll
    for (int m = 0; m < 2; ++m)
      #pragma unroll
      for (int n = 0; n < 4; ++n) g[m][n] = (f32x4){0.f,0.f,0.f,0.f};
    #pragma unroll
    for (int kk = 0; kk < 64; kk += 32) {
      bf16x8 af[2], bf[4];
      #pragma unroll
      for (int m = 0; m < 2; ++m) af[m] = ldfrag(Cb, l0 + 16*m + lr, kk + kb*8, 64);
      #pragma unroll
      for (int n = 0; n < 4; ++n)
        bf[n] = *(const bf16x8*)(Bm + (tg + s0 + 16*n + lr)*64 + kk + kb*8);
      #pragma unroll
      for (int m = 0; m < 2; ++m)
        #pragma unroll
        for (int n = 0; n < 4; ++n)
          g[m][n] = __builtin_amdgcn_mfma_f32_16x16x32_bf16(af[m], bf[n], g[m][n], 0, 0, 0);
    }
    #pragma unroll
    for (int m = 0; m < 2; ++m)
      #pragma unroll
      for (int r = 0; r < 4; ++r) {
        int lrow = 16*m + kb*4 + r;
        int lg = l0 + lrow;
        float acl = ac[lg];
        #pragma unroll
        for (int n = 0; n < 4; ++n) {
          int sl = 16*n + lr;
          int sg = s0 + sl;
          float v = (sg <= lg) ? g[m][n][r] * __expf(acl - ac[sg]) * dts[sg] : 0.f;
          Ww[lrow*72 + sl] = f2b(v);
        }
      }
    // same-wave LDS write->read: ordered by lgkmcnt, no barrier needed
    const ushort* xt = ct0 + (size_t)st*16384;
    #pragma unroll
    for (int kk = 0; kk < 64; kk += 32) {
      bf16x8 af[2], bf[4];
      #pragma unroll
      for (int m = 0; m < 2; ++m)
        af[m] = *(const bf16x8*)(Ww + (16*m + lr)*72 + kk + kb*8);
      #pragma unroll
      for (int n = 0; n < 4; ++n)
        bf[n] = *(const bf16x8*)(xt + (size_t)(16*n + lr)*64 + kk + kb*8);
      #pragma unroll
      for (int m = 0; m < 2; ++m)
        #pragma unroll
        for (int n = 0; n < 4; ++n)
          yy[m][n] = __builtin_amdgcn_mfma_f32_16x16x32_bf16(af[m], bf[n], yy[m][n], 0, 0, 0);
    }
  }

  // + D*xh (xh from co2 directly) and store
  float Dh = ssd_D[h];
  #pragma unroll
  for (int m = 0; m < 2; ++m)
    #pragma unroll
    for (int r = 0; r < 4; ++r) {
      int lg = l0 + 16*m + kb*4 + r;
      const ushort* xlt = ct0 + (size_t)(lg >> 6)*16384;
      int lc = lg & 63;
      #pragma unroll
      for (int n = 0; n < 4; ++n) {
        int p = 16*n + lr;
        float val = yy[m][n][r] + Dh * b2f(xlt[(size_t)p*64 + lc]);
        y[(tg + lg)*128 + h*64 + p] = f2b(val);
      }
    }
}

// ---------------------------------------------------------------------------
// K8 (MFMA): yz = y*silu(z); RMS over 128; out = ctx + yn @ (opw*rms_w)^T.
// ---------------------------------------------------------------------------
__global__ __launch_bounds__(256) void k_final(
    const ushort* __restrict__ y, const ushort* __restrict__ z,
    const float* __restrict__ ctx, const float* __restrict__ rms_w,
    const float* __restrict__ opw, float* __restrict__ out)
{
  __shared__ ushort yn[64*128];    // swizzled [t][k]
  __shared__ ushort wop[64*128];   // swizzled [c][k]
  __shared__ float otile[64*65];
  int tid = threadIdx.x;
  size_t p0 = (size_t)blockIdx.x * 64;

  for (int i = tid; i < 2048; i += 256) {
    int row = i >> 5, c4 = (i & 31) * 4;
    float4 v = ((const float4*)(opw + row*128))[c4 >> 2];
    float4 rw = ((const float4*)rms_w)[c4 >> 2];
    u16x4 p = { f2b(v.x*rw.x), f2b(v.y*rw.y), f2b(v.z*rw.z), f2b(v.w*rw.w) };
    *(u16x4*)(wop + row*128 + swz(row, c4)) = p;
  }

  {
    int t = tid >> 2, q = tid & 3;
    const u16x4* yp = (const u16x4*)(y + (p0 + t)*128 + q*32);
    const u16x4* zp = (const u16x4*)(z + (p0 + t)*128 + q*32);
    float vals[32];
    float ss = 0.f;
    #pragma unroll
    for (int j = 0; j < 8; ++j) {
      u16x4 yv = yp[j];
      u16x4 zv = zp[j];
      #pragma unroll
      for (int e = 0; e < 4; ++e) {
        float zf = b2f(zv[e]);
        float x = b2f(yv[e]) * (zf / (1.f + __expf(-zf)));
        vals[j*4+e] = x; ss += x*x;
      }
    }
    ss += __shfl_xor(ss, 1);
    ss += __shfl_xor(ss, 2);
    float rinv = rsqrtf(ss*(1.f/128.f) + 1e-5f);
    #pragma unroll
    for (int j = 0; j < 8; ++j) {
      int c4 = q*32 + j*4;
      u16x4 p = { f2b(vals[j*4]*rinv), f2b(vals[j*4+1]*rinv),
                  f2b(vals[j*4+2]*rinv), f2b(vals[j*4+3]*rinv) };
      *(u16x4*)(yn + t*128 + swz(t, c4)) = p;
    }
  }
  __syncthreads();

  int w = tid >> 6, lane = tid & 63, lr = lane & 15, kb = lane >> 4;
  f32x4 acc[4];
  #pragma unroll
  for (int n = 0; n < 4; ++n) acc[n] = (f32x4){0.f,0.f,0.f,0.f};
  #pragma unroll
  for (int kk = 0; kk < 128; kk += 32) {
    bf16x8 a = ldfrag(yn, w*16 + lr, kk + kb*8, 128);
    #pragma unroll
    for (int n = 0; n < 4; ++n) {
      bf16x8 bf = ldfrag(wop, n*16 + lr, kk + kb*8, 128);
      acc[n] = __builtin_amdgcn_mfma_f32_16x16x32_bf16(a, bf, acc[n], 0, 0, 0);
    }
  }
  #pragma unroll
  for (int n = 0; n < 4; ++n)
    #pragma unroll
    for (int r = 0; r < 4; ++r) {
      int tok = w*16 + kb*4 + r, ch = n*16 + lr;
      otile[ch*65 + tok] = acc[n][r] + ctx[(p0 + tok)*64 + ch];
    }
  __syncthreads();
  {
    size_t b  = p0 >> 15;
    size_t t0 = p0 & (HW-1);
    for (int r = 0; r < 16; ++r) {
      int cc = r*4 + (tid >> 6);
      int pp = tid & 63;
      out[(b*64 + cc)*HW + t0 + pp] = otile[cc*65 + pp];
    }
  }
}

// ---------------------------------------------------------------------------
extern "C" void kernel_launch(void* const* d_in, const int* in_sizes, int n_in,
                              void* d_out, int out_size, void* d_ws, size_t ws_size,
                              hipStream_t stream) {
  (void)in_sizes; (void)n_in; (void)out_size; (void)ws_size;
  const float* xx   = (const float*)d_in[0];
  const float* sw1  = (const float*)d_in[2];
  const float* sb1  = (const float*)d_in[3];
  const float* sw2  = (const float*)d_in[4];
  const float* sb2  = (const float*)d_in[5];
  const float* vw   = (const float*)d_in[10];
  const float* vb   = (const float*)d_in[11];
  const float* lnw  = (const float*)d_in[12];
  const float* lnb  = (const float*)d_in[13];
  const float* ipw  = (const float*)d_in[14];
  const float* ipb  = (const float*)d_in[15];
  const float* cw   = (const float*)d_in[16];
  const float* cb   = (const float*)d_in[17];
  const float* dtb  = (const float*)d_in[18];
  const float* alog = (const float*)d_in[19];
  const float* sd   = (const float*)d_in[20];
  const float* rmsw = (const float*)d_in[21];
  const float* opw  = (const float*)d_in[22];

  float* ws = (float*)d_ws;
  float*  scores32 = ws;                       // [0, 458752)
  int*    idxb     = (int*)(ws + 458752);      // [458752, 589824)
  int*    cntb     = (int*)(ws + 589824);      // 1
  int*    listb    = (int*)(ws + 589832);      // [589832, 720904)
  float*  dtp      = ws;                       // alias after k_fix (262144 floats)
  float*  seq      = ws + 917504;              // [917504, 9306112)
  ushort* Cmb      = (ushort*)(ws + 917504);   // alias after k_vln (8.4M ushorts)
  ushort* Bmb      = (ushort*)(ws + 5111808);  // alias after k_vln (8.4M ushorts)
  float*  ctx      = ws + 9306112;             // [9306112, 17694720)
  ushort* uswb     = (ushort*)(ws + 17694720); // dead after k_gemm
  float*  states   = ws + 17694720;            // alias after k_gemm
  float*  states_in= ws + 21889024;
  ushort* zb       = (ushort*)(ws + 26083328); // [26083328, 34471936)
  ushort* xbcBb    = (ushort*)(ws + 34471936); // [34471936, 51249152) tile-blocked
  ushort* co2b     = (ushort*)(ws + 51249152); // [51249152, 68026368) tile-blocked
  ushort* yb       = (ushort*)(ws + 68026368); // [68026368, 76414976)
  float*  Alast    = ws + 84803584;
  ushort* wswb     = (ushort*)(ws + 84804608); // 25600 ushorts

  k_score_mfma<<<1792, 256, 0, stream>>>(xx, sw1, sb1, sw2, sb2, scores32, cntb);
  k_argmax<<<512, 256, 0, stream>>>(scores32, idxb, cntb, listb);
  k_fix<<<512, 256, 0, stream>>>(xx, sw1, sb1, sw2, sb2, cntb, listb, idxb);
  k_fuse<<<2048, 256, 0, stream>>>(xx, idxb, seq);
  k_vln<<<2048, 256, 0, stream>>>(seq, vw, vb, lnw, lnb, ctx, uswb);
  k_prep<<<100, 256, 0, stream>>>(ipw, wswb);
  k_gemm<<<2048, 512, 0, stream>>>(uswb, wswb, ipb, dtb, zb, xbcBb, dtp);
  k_conv<<<2048, 256, 0, stream>>>(xbcBb, cw, cb, co2b, Bmb, Cmb);
  dim3 gssd(NC, NH, B4);
  k_states<<<gssd, 256, 67584, stream>>>(dtp, co2b, alog, states, Alast);
  k_scan<<<64, 256, 0, stream>>>(states, Alast, states_in);
  k_ydiag<<<gssd, 512, 71712, stream>>>(dtp, co2b, Bmb, Cmb, states_in, alog, sd, yb);
  k_final<<<2048, 256, 0, stream>>>(yb, zb, ctx, rmsw, opw, (float*)d_out);
}

// Round 14
// 415.723 us; speedup vs baseline: 1.0867x; 1.0867x over previous
//
#include <hip/hip_runtime.h>
#include <cmath>

#define HW 32768      // H*W
#define NC 128        // chunks per batch (HW/256)
#define NH 2          // heads
#define B4 4          // batch (num groups)

typedef __attribute__((ext_vector_type(8))) short bf16x8;
typedef __attribute__((ext_vector_type(4))) float f32x4;
typedef __attribute__((ext_vector_type(4))) ushort u16x4;
typedef __attribute__((ext_vector_type(8))) ushort u16x8;

__device__ __forceinline__ ushort f2b(float x) {
  union { float f; unsigned u; } v; v.f = x;
  unsigned r = v.u + 0x7FFFu + ((v.u >> 16) & 1u);   // RNE
  return (ushort)(r >> 16);
}
__device__ __forceinline__ float b2f(ushort b) {
  union { unsigned u; float f; } v; v.u = ((unsigned)b) << 16;
  return v.f;
}
// XOR-swizzle of element index k within a row (bf16 tiles, 16B-group spread)
__device__ __forceinline__ int swz(int row, int k) { return k ^ ((row & 7) << 3); }
// A-frag: row-major [M][K] (K contig); B-frag: [N][K] (i.e. B^T row-major).
__device__ __forceinline__ bf16x8 ldfrag(const ushort* base, int row, int k, int stride) {
  return *(const bf16x8*)(base + row * stride + swz(row, k));
}

// ---------------------------------------------------------------------------
// K1a (MFMA): score MLP via split-precision weights.
// ---------------------------------------------------------------------------
__global__ __launch_bounds__(256) void k_score_mfma(
    const float* __restrict__ xx, const float* __restrict__ w1,
    const float* __restrict__ b1, const float* __restrict__ w2,
    const float* __restrict__ b2, float* __restrict__ scores,
    int* __restrict__ cnt)
{
  __shared__ ushort Whi[64*64];     // [d][c] swizzled
  __shared__ ushort Wlo[64*64];
  __shared__ ushort Xt[4][64*64];   // per-wave [t][c] swizzled
  __shared__ float w2b1[128];       // w2[0..63] | b1[64..127]
  int tid = threadIdx.x;
  if (blockIdx.x == 0 && tid == 0) cnt[0] = 0;
  for (int i = tid; i < 4096; i += 256) {
    int d = i >> 6, c = i & 63;
    float v = w1[i];
    ushort hi = f2b(v);
    int off = d*64 + swz(d, c);
    Whi[off] = hi;
    Wlo[off] = f2b(v - b2f(hi));
  }
  if (tid < 64) { w2b1[tid] = w2[tid]; w2b1[64+tid] = b1[tid]; }

  int wid = tid >> 6, lane = tid & 63;
  int n  = blockIdx.x >> 7;             // 1792 blocks = 14 n x 128 tiles
  int t0 = (blockIdx.x & 127)*256 + wid*64;

  {
    const float* px = xx + (size_t)n*64*HW + t0 + lane;
    float xv[64];
    #pragma unroll
    for (int c = 0; c < 64; ++c) xv[c] = px[(size_t)c*HW];
    ushort* xh = Xt[wid];
    #pragma unroll
    for (int c8 = 0; c8 < 8; ++c8) {
      u16x8 p;
      #pragma unroll
      for (int j = 0; j < 8; ++j) p[j] = f2b(xv[c8*8 + j]);
      *(u16x8*)(xh + lane*64 + swz(lane, c8*8)) = p;
    }
  }
  __syncthreads();

  int lr = lane & 15, kb = lane >> 4;
  const ushort* xh = Xt[wid];
  f32x4 acc[4][4];
  #pragma unroll
  for (int m = 0; m < 4; ++m)
    #pragma unroll
    for (int nt = 0; nt < 4; ++nt) acc[m][nt] = (f32x4){0.f,0.f,0.f,0.f};
  #pragma unroll
  for (int k0 = 0; k0 < 64; k0 += 32) {
    bf16x8 ah[4], al[4], bx[4];
    #pragma unroll
    for (int m = 0; m < 4; ++m) {
      ah[m] = ldfrag(Whi, 16*m + lr, k0 + kb*8, 64);
      al[m] = ldfrag(Wlo, 16*m + lr, k0 + kb*8, 64);
    }
    #pragma unroll
    for (int nt = 0; nt < 4; ++nt) bx[nt] = ldfrag(xh, 16*nt + lr, k0 + kb*8, 64);
    #pragma unroll
    for (int m = 0; m < 4; ++m)
      #pragma unroll
      for (int nt = 0; nt < 4; ++nt) {
        acc[m][nt] = __builtin_amdgcn_mfma_f32_16x16x32_bf16(ah[m], bx[nt], acc[m][nt], 0, 0, 0);
        acc[m][nt] = __builtin_amdgcn_mfma_f32_16x16x32_bf16(al[m], bx[nt], acc[m][nt], 0, 0, 0);
      }
  }
  float bb2 = b2[0];
  #pragma unroll
  for (int nt = 0; nt < 4; ++nt) {
    float s = 0.f;
    #pragma unroll
    for (int m = 0; m < 4; ++m)
      #pragma unroll
      for (int r = 0; r < 4; ++r) {
        int d = 16*m + kb*4 + r;
        float h = acc[m][nt][r] + w2b1[64 + d];
        s += fmaxf(h, 0.f) * w2b1[d];
      }
    s += __shfl_xor(s, 16);
    s += __shfl_xor(s, 32);
    if (kb == 0) scores[(size_t)n*HW + t0 + 16*nt + lr] = s + bb2;
  }
}

// ---------------------------------------------------------------------------
// K1b: per-(group,pixel) first-max argmax over fp32 scores; flag near-ties.
// ---------------------------------------------------------------------------
__global__ __launch_bounds__(256) void k_argmax(
    const float* __restrict__ scores, int* __restrict__ idx,
    int* __restrict__ cnt, int* __restrict__ list)
{
  int i = blockIdx.x*256 + threadIdx.x;      // 512 blocks: 4*HW
  int g = i >> 15, t = i & (HW-1);
  const int gs0[4] = {0,5,8,12};
  const int gl0[4] = {5,3,4,2};
  int start = gs0[g], len = gl0[g];
  float best = scores[(size_t)start*HW + t];
  float second = -3.4e38f;
  int bi = start;
  for (int j = 1; j < len; ++j) {
    float s = scores[(size_t)(start+j)*HW + t];
    if (s > best) { second = best; best = s; bi = start + j; }
    else if (s > second) second = s;
  }
  idx[i] = bi;
  if (best - second < 5e-4f) {
    int p = atomicAdd(cnt, 1);
    list[p] = i;
  }
}

// ---------------------------------------------------------------------------
// K1c: fp64 recompute of flagged pixels, ONE WAVE PER ENTRY.
// ---------------------------------------------------------------------------
__global__ __launch_bounds__(256) void k_fix(
    const float* __restrict__ xx, const float* __restrict__ w1,
    const float* __restrict__ b1, const float* __restrict__ w2,
    const float* __restrict__ b2, const int* __restrict__ cnt,
    const int* __restrict__ list, int* __restrict__ idx)
{
  __shared__ float w1f[64*65];     // [d][c] padded -> 2-way bank (free)
  __shared__ float w2f[64], b1f[64];
  int tid = threadIdx.x;
  for (int i = tid; i < 4096; i += 256) w1f[(i >> 6)*65 + (i & 63)] = w1[i];
  if (tid < 64) { w2f[tid] = w2[tid]; b1f[tid] = b1[tid]; }
  __syncthreads();
  int n = cnt[0];
  int wid = tid >> 6, lane = tid & 63;
  int nwaves = gridDim.x * 4;
  const int gs0[4] = {0,5,8,12};
  const int gl0[4] = {5,3,4,2};
  double b2d = (double)b2[0];
  for (int e = blockIdx.x*4 + wid; e < n; e += nwaves) {
    int i = list[e];
    int g = i >> 15, t = i & (HW-1);
    int start = gs0[g], len = gl0[g];
    double best = -1e300;
    int bi = start;
    for (int j = 0; j < len; ++j) {
      double xv = (double)xx[(size_t)(start+j)*64*HW + (size_t)lane*HW + t];
      double acc = (double)b1f[lane];
      #pragma unroll
      for (int c = 0; c < 64; ++c) {
        double xc = __shfl(xv, c);
        acc += xc * (double)w1f[lane*65 + c];
      }
      double sc = (acc > 0.0 ? acc : 0.0) * (double)w2f[lane];
      #pragma unroll
      for (int m = 1; m < 64; m <<= 1) sc += __shfl_xor(sc, m);
      sc += b2d;
      if (sc > best) { best = sc; bi = start + j; }   // first-max
    }
    if (lane == 0) idx[i] = bi;
  }
}

// ---------------------------------------------------------------------------
// K2: gather winner (from idx) + transpose to token-major seq.
// ---------------------------------------------------------------------------
__global__ __launch_bounds__(256) void k_fuse(
    const float* __restrict__ xx, const int* __restrict__ idx,
    float* __restrict__ seq)
{
  __shared__ int idxs[64];
  __shared__ float tile[64*65];
  int tid = threadIdx.x;
  int g  = blockIdx.x >> 9;
  int t0 = (blockIdx.x & 511) << 6;
  if (tid < 64) idxs[tid] = idx[(size_t)g*HW + t0 + tid];
  __syncthreads();
  int tl = tid & 63, cq = tid >> 6;
  for (int r = 0; r < 16; ++r) {
    int c = r*4 + cq;
    tile[c*65 + tl] = xx[(size_t)idxs[tl]*64*HW + (size_t)c*HW + t0 + tl];
  }
  __syncthreads();
  for (int r = 0; r < 16; ++r) {
    int row = r*4 + cq;
    seq[((size_t)g*HW + t0 + row)*64 + tl] = tile[tl*65 + row];
  }
}

// ---------------------------------------------------------------------------
// K3: ctx = seq @ v_w^T + v_b; u = LayerNorm(...) -> PRE-SWIZZLED bf16 usw.
// ---------------------------------------------------------------------------
__global__ __launch_bounds__(256) void k_vln(
    const float* __restrict__ seq, const float* __restrict__ vw,
    const float* __restrict__ vb, const float* __restrict__ lnw,
    const float* __restrict__ lnb, float* __restrict__ ctx,
    ushort* __restrict__ usw)
{
  __shared__ float st[64*64];
  int tid = threadIdx.x;
  size_t p0 = (size_t)blockIdx.x * 64;
  for (int i = tid; i < 64*64; i += 256) st[i] = seq[p0*64 + i];
  int o = tid & 63, wv = tid >> 6;
  float w[64];
  const float4* w4 = (const float4*)(vw + o*64);
  #pragma unroll
  for (int c4 = 0; c4 < 16; ++c4) {
    float4 v = w4[c4];
    w[c4*4+0]=v.x; w[c4*4+1]=v.y; w[c4*4+2]=v.z; w[c4*4+3]=v.w;
  }
  float bias = vb[o], lw = lnw[o], lb = lnb[o];
  __syncthreads();
  const float4* st4 = (const float4*)st;
  for (int j = 0; j < 16; ++j) {
    int p = wv*16 + j;
    float acc = bias;
    #pragma unroll
    for (int c4 = 0; c4 < 16; ++c4) {
      float4 s4 = st4[p*16 + c4];
      acc += s4.x*w[c4*4] + s4.y*w[c4*4+1] + s4.z*w[c4*4+2] + s4.w*w[c4*4+3];
    }
    float s1 = acc, s2 = acc*acc;
    #pragma unroll
    for (int m = 1; m < 64; m <<= 1) {
      s1 += __shfl_xor(s1, m);
      s2 += __shfl_xor(s2, m);
    }
    float mu  = s1*(1.f/64.f);
    float var = s2*(1.f/64.f) - mu*mu;
    float rstd = rsqrtf(var + 1e-5f);
    size_t base = (p0+p)*64;
    int gt = (int)(p0 + p);
    ctx[base + o] = acc;
    usw[base + (o ^ (((gt+3)&7)<<3))] = f2b((acc - mu)*rstd*lw + lb);
  }
}

// ---------------------------------------------------------------------------
// k_prep: ipw -> bf16 pre-swizzled wsw (rows >=386 zeroed; 400x64).
// ---------------------------------------------------------------------------
__global__ __launch_bounds__(256) void k_prep(
    const float* __restrict__ ipw, ushort* __restrict__ wsw)
{
  int i = blockIdx.x*256 + threadIdx.x;   // 100*256 = 25600 = 400*64
  int row = i >> 6, c = i & 63;
  float v = (row < 386) ? ipw[row*64 + c] : 0.f;
  wsw[row*64 + swz(row, c)] = f2b(v);
}

// ---------------------------------------------------------------------------
// k_gemm: in_proj GEMM (M=80 rows incl 3-halo, N=400, K=64). 8 waves.
// xbc output TILE-BLOCKED: xbcB[b][s][ch][64].
// ---------------------------------------------------------------------------
__global__ __launch_bounds__(512) void k_gemm(
    const ushort* __restrict__ usw, const ushort* __restrict__ wsw,
    const float* __restrict__ ipb, const float* __restrict__ dtbias,
    ushort* __restrict__ z, ushort* __restrict__ xbcB, float* __restrict__ dt)
{
  __shared__ ushort Wlds[400*64];   // 51200 B (pre-swizzled copy)
  __shared__ ushort Ulds[80*64];    // 10240 B
  __shared__ ushort trans[8704];    // 17408 B
  int tid = threadIdx.x;
  int b  = blockIdx.x >> 9;
  int s  = blockIdx.x & 511;
  int t0 = s << 6;
  size_t pixbase = (size_t)b*HW + t0;
  size_t tilebase = ((size_t)(b*512 + s))*256*64;

  for (int i = tid; i < 3200; i += 512)
    *(u16x8*)(Wlds + i*8) = *(const u16x8*)(wsw + i*8);
  {
    const ushort* ubase = usw + ((size_t)b*HW + t0 - 3)*64;
    for (int i = tid; i < 536; i += 512) {     // 536*8 = 67*64
      u16x8 v;
      if (t0 == 0 && i < 24) v = (u16x8){0,0,0,0,0,0,0,0};
      else v = *(const u16x8*)(ubase + i*8);
      *(u16x8*)(Ulds + i*8) = v;
    }
  }
  __syncthreads();

  int w = tid >> 6, lane = tid & 63, lr = lane & 15, kb = lane >> 4;
  for (int rd = 0; rd < 3; ++rd) {
    int nt = rd*8 + w;
    f32x4 acc[5];
    #pragma unroll
    for (int mt = 0; mt < 5; ++mt) acc[mt] = (f32x4){0.f,0.f,0.f,0.f};
    #pragma unroll
    for (int kk = 0; kk < 64; kk += 32) {
      bf16x8 bfrag = ldfrag(Wlds, nt*16 + lr, kk + kb*8, 64);
      #pragma unroll
      for (int mt = 0; mt < 5; ++mt) {
        bf16x8 afrag = ldfrag(Ulds, mt*16 + lr, kk + kb*8, 64);
        acc[mt] = __builtin_amdgcn_mfma_f32_16x16x32_bf16(afrag, bfrag, acc[mt], 0, 0, 0);
      }
    }
    float bias = ipb[nt*16 + lr];
    if (rd == 0) {          // z channels: trans[t][132]
      #pragma unroll
      for (int mt = 0; mt < 5; ++mt)
        #pragma unroll
        for (int r = 0; r < 4; ++r) {
          int t = mt*16 + kb*4 + r - 3;
          if (t >= 0 && t < 64) trans[t*132 + w*16 + lr] = f2b(acc[mt][r] + bias);
        }
    } else {                // xbc channels: trans[ch][68]
      #pragma unroll
      for (int mt = 0; mt < 5; ++mt)
        #pragma unroll
        for (int r = 0; r < 4; ++r) {
          int t = mt*16 + kb*4 + r - 3;
          if (t >= 0 && t < 64) trans[(w*16 + lr)*68 + t] = f2b(acc[mt][r] + bias);
        }
    }
    __syncthreads();
    if (rd == 0) {
      for (int i = tid; i < 2048; i += 512) {
        int t = i >> 5, c4 = (i & 31)*4;
        *(u16x4*)(z + (pixbase + t)*128 + c4) = *(const u16x4*)(trans + t*132 + c4);
      }
    } else {
      int chbase = (rd - 1)*128;
      for (int i = tid; i < 2048; i += 512) {   // contiguous 4 KB per pass
        int ch = i >> 4, t4 = (i & 15)*4;
        *(u16x4*)(xbcB + tilebase + (size_t)(chbase + ch)*64 + t4)
            = *(const u16x4*)(trans + ch*68 + t4);
      }
    }
    __syncthreads();
  }

  if (w == 0) {    // dt rows 384/385
    f32x4 acc[5];
    #pragma unroll
    for (int mt = 0; mt < 5; ++mt) acc[mt] = (f32x4){0.f,0.f,0.f,0.f};
    #pragma unroll
    for (int kk = 0; kk < 64; kk += 32) {
      bf16x8 bfrag = ldfrag(Wlds, 384 + lr, kk + kb*8, 64);
      #pragma unroll
      for (int mt = 0; mt < 5; ++mt) {
        bf16x8 afrag = ldfrag(Ulds, mt*16 + lr, kk + kb*8, 64);
        acc[mt] = __builtin_amdgcn_mfma_f32_16x16x32_bf16(afrag, bfrag, acc[mt], 0, 0, 0);
      }
    }
    if (lr < 2) {
      float bias = ipb[384 + lr] + dtbias[lr];
      #pragma unroll
      for (int mt = 0; mt < 5; ++mt)
        #pragma unroll
        for (int r = 0; r < 4; ++r) {
          int t = mt*16 + kb*4 + r - 3;
          if (t >= 0 && t < 64) {
            float a = acc[mt][r] + bias;
            dt[(pixbase + t)*2 + lr] = (a > 20.f) ? a : log1pf(expf(a));
          }
        }
    }
  }
}

// ---------------------------------------------------------------------------
// k_conv: depthwise conv(K=4)+silu from tile-blocked xbcB -> co2 tile-blocked;
// Bm/Cm token-major via bank-swizzled LDS transpose.
// ---------------------------------------------------------------------------
__global__ __launch_bounds__(256) void k_conv(
    const ushort* __restrict__ xbcB, const float* __restrict__ convw,
    const float* __restrict__ convb, ushort* __restrict__ co2,
    ushort* __restrict__ Bm, ushort* __restrict__ Cm)
{
  __shared__ ushort bmc[64*132];    // [t][128] swizzled: col = c ^ ((t>>3)<<2)
  int tid = threadIdx.x;
  int b  = blockIdx.x >> 9;
  int s  = blockIdx.x & 511;
  int lane = tid & 63, wv = tid >> 6;
  int toct = lane & 7, chi = lane >> 3;
  size_t tilebase = ((size_t)(b*512 + s))*256*64;
  const ushort* tsrc = xbcB + tilebase;
  const ushort* psrc = xbcB + tilebase - 256*64;   // prev tile (valid if s>0)

  for (int it = 0; it < 8; ++it) {
    int ch = wv*64 + it*8 + chi;
    u16x8 v = *(const u16x8*)(tsrc + ch*64 + toct*8);
    float x0 = b2f(v[0]), x1 = b2f(v[1]), x2 = b2f(v[2]), x3 = b2f(v[3]);
    float x4 = b2f(v[4]), x5 = b2f(v[5]), x6 = b2f(v[6]), x7 = b2f(v[7]);
    float pm1 = __shfl(x7, lane - 1);
    float pm2 = __shfl(x6, lane - 1);
    float pm3 = __shfl(x5, lane - 1);
    if (toct == 0) {
      if (s > 0) {
        u16x4 hq = *(const u16x4*)(psrc + ch*64 + 60);
        pm3 = b2f(hq[1]); pm2 = b2f(hq[2]); pm1 = b2f(hq[3]);
      } else {
        pm1 = pm2 = pm3 = 0.f;
      }
    }
    float4 cw = ((const float4*)convw)[ch];
    float cb = convb[ch];
    float o0 = cb + cw.x*pm3 + cw.y*pm2 + cw.z*pm1 + cw.w*x0;
    float o1 = cb + cw.x*pm2 + cw.y*pm1 + cw.z*x0  + cw.w*x1;
    float o2 = cb + cw.x*pm1 + cw.y*x0  + cw.z*x1  + cw.w*x2;
    float o3 = cb + cw.x*x0  + cw.y*x1  + cw.z*x2  + cw.w*x3;
    float o4 = cb + cw.x*x1  + cw.y*x2  + cw.z*x3  + cw.w*x4;
    float o5 = cb + cw.x*x2  + cw.y*x3  + cw.z*x4  + cw.w*x5;
    float o6 = cb + cw.x*x3  + cw.y*x4  + cw.z*x5  + cw.w*x6;
    float o7 = cb + cw.x*x4  + cw.y*x5  + cw.z*x6  + cw.w*x7;
    u16x8 ov;
    ov[0] = f2b(o0 / (1.f + __expf(-o0)));
    ov[1] = f2b(o1 / (1.f + __expf(-o1)));
    ov[2] = f2b(o2 / (1.f + __expf(-o2)));
    ov[3] = f2b(o3 / (1.f + __expf(-o3)));
    ov[4] = f2b(o4 / (1.f + __expf(-o4)));
    ov[5] = f2b(o5 / (1.f + __expf(-o5)));
    ov[6] = f2b(o6 / (1.f + __expf(-o6)));
    ov[7] = f2b(o7 / (1.f + __expf(-o7)));
    *(u16x8*)(co2 + tilebase + (size_t)ch*64 + toct*8) = ov;
    if (ch >= 128) {
      int c = ch - 128;
      int csw = c ^ (toct << 2);
      #pragma unroll
      for (int j = 0; j < 8; ++j)
        bmc[(toct*8 + j)*132 + csw] = ov[j];
    }
  }
  __syncthreads();
  size_t tg = (size_t)b*HW + s*64;
  for (int i = tid; i < 1024; i += 256) {
    int tt = i >> 4, n4 = (i & 15)*4;
    int sw = (tt >> 3) << 2;
    *(u16x4*)(Bm + (tg + tt)*64 + n4) = *(const u16x4*)(bmc + tt*132 + (n4 ^ sw));
    *(u16x4*)(Cm + (tg + tt)*64 + n4) = *(const u16x4*)(bmc + tt*132 + ((64 + n4) ^ sw));
  }
}

// ---------------------------------------------------------------------------
// K5 (MFMA): states[p,n] = sum_l xd[l,p]*B[l,n]. Reads tile-blocked co2.
// ---------------------------------------------------------------------------
__global__ __launch_bounds__(256) void k_states(
    const float* __restrict__ dt, const ushort* __restrict__ co2,
    const float* __restrict__ A_log,
    float* __restrict__ states, float* __restrict__ A_last)
{
  extern __shared__ char smem[];
  float* ac  = (float*)smem;            // 256
  float* dec = ac + 256;                // 256
  ushort* xdT = (ushort*)(dec + 256);   // 64 x 256
  ushort* BT  = xdT + 16384;            // 64 x 256
  int tid = threadIdx.x;
  int ci = blockIdx.x, h = blockIdx.y, b = blockIdx.z;
  size_t tg = (size_t)b*HW + (size_t)ci*256;
  float Aneg = -expf(A_log[h]);
  float dv = dt[(tg + tid)*2 + h];
  ac[tid] = dv*Aneg;
  __syncthreads();
  for (int off = 1; off < 256; off <<= 1) {
    float v = (tid >= off) ? ac[tid - off] : 0.f;
    __syncthreads();
    ac[tid] += v;
    __syncthreads();
  }
  float alast = ac[255];
  dec[tid] = dv * __expf(alast - ac[tid]);
  __syncthreads();
  for (int i = tid; i < 64*32; i += 256) {
    int p = i >> 5, lc = (i & 31) * 8;
    int s = (ci << 2) + (lc >> 6);
    const ushort* cb2 = co2 + ((size_t)(b*512 + s))*256*64 + (lc & 63);
    u16x8 xv = *(const u16x8*)(cb2 + (size_t)(h*64 + p)*64);
    u16x8 o;
    #pragma unroll
    for (int e = 0; e < 8; ++e) o[e] = f2b(b2f(xv[e]) * dec[lc + e]);
    *(u16x8*)(xdT + p*256 + swz(p, lc)) = o;
    u16x8 bv = *(const u16x8*)(cb2 + (size_t)(128 + p)*64);
    *(u16x8*)(BT + p*256 + swz(p, lc)) = bv;
  }
  __syncthreads();
  int w = tid >> 6, lane = tid & 63, lr = lane & 15, kb = lane >> 4;
  f32x4 acc[4];
  #pragma unroll
  for (int m = 0; m < 4; ++m) acc[m] = (f32x4){0.f,0.f,0.f,0.f};
  for (int k0 = 0; k0 < 256; k0 += 32) {
    bf16x8 bfrag = ldfrag(BT, 16*w + lr, k0 + kb*8, 256);
    #pragma unroll
    for (int m = 0; m < 4; ++m) {
      bf16x8 afrag = ldfrag(xdT, 16*m + lr, k0 + kb*8, 256);
      acc[m] = __builtin_amdgcn_mfma_f32_16x16x32_bf16(afrag, bfrag, acc[m], 0, 0, 0);
    }
  }
  size_t sb = (((size_t)b*NC + ci)*NH + h)*4096;
  #pragma unroll
  for (int m = 0; m < 4; ++m)
    #pragma unroll
    for (int r = 0; r < 4; ++r)
      states[sb + (size_t)(16*m + kb*4 + r)*64 + 16*w + lr] = acc[m][r];
  if (tid == 0) A_last[((size_t)b*NH + h)*NC + ci] = alast;
}

// ---------------------------------------------------------------------------
// K6: inter-chunk scan with prefetch; 64 blocks (b,h,seg).
// ---------------------------------------------------------------------------
__global__ __launch_bounds__(256) void k_scan(
    const float* __restrict__ states, const float* __restrict__ A_last,
    float* __restrict__ states_in)
{
  __shared__ float ef[NC];
  int tid = threadIdx.x;
  int seg = blockIdx.x & 7, h = (blockIdx.x >> 3) & 1, b = blockIdx.x >> 4;
  if (tid < NC) ef[tid] = __expf(A_last[((size_t)b*NH + h)*NC + tid]);
  __syncthreads();
  size_t base0 = (((size_t)b*NC)*NH + h)*4096 + seg*512 + tid;
  const size_t cstride = (size_t)NH*4096;
  float s0 = 0.f, s1 = 0.f;
  float ld0 = states[base0], ld1 = states[base0 + 256];
  for (int zc = 0; zc < NC; ++zc) {
    size_t cur = base0 + (size_t)zc*cstride;
    float n0 = 0.f, n1 = 0.f;
    if (zc < NC-1) { n0 = states[cur + cstride]; n1 = states[cur + cstride + 256]; }
    states_in[cur] = s0; states_in[cur + 256] = s1;
    float e = ef[zc];
    s0 = ld0 + e*s0; s1 = ld1 + e*s1;
    ld0 = n0; ld1 = n1;
  }
}

// ---------------------------------------------------------------------------
// K7 (MFMA): per chunk-head SSD Y.  y -> bf16.  512 thr / 8 waves.
// HYBRID: LDS staging for C/B/xh/S (round-12 structure, fast fragment feeds)
// + stride-72 no-XOR Ww (round-13 conflict fix) + dt folded into W'
// (xh staging = pure copy; D-term = Dh*xh). Barrier-free s-loop.
// ---------------------------------------------------------------------------
__global__ __launch_bounds__(512) void k_ydiag(
    const float* __restrict__ dt, const ushort* __restrict__ co2,
    const ushort* __restrict__ Bm, const ushort* __restrict__ Cm,
    const float* __restrict__ states_in, const float* __restrict__ A_log,
    const float* __restrict__ ssd_D, ushort* __restrict__ y)
{
  extern __shared__ char smem[];
  float* ac   = (float*)smem;           // 256
  float* dts  = ac + 256;               // 256
  float* segs = dts + 256;              // 8 (4 used)
  ushort* Cb  = (ushort*)(segs + 8);    // 256 x 64   [l][n] swizzled
  ushort* Bb  = Cb + 16384;             // 256 x 64   [s][n] swizzled
  ushort* xsT = Bb + 16384;             // 64 x 256   [p][s] swizzled (pure xh)
  ushort* Sb  = xsT + 16384;            // 64 x 64    [p][n] swizzled
  ushort* Wb  = Sb + 4096;              // 8 x (32 x 72) per-wave [l][s]
  int tid = threadIdx.x;
  int ci = blockIdx.x, h = blockIdx.y, b = blockIdx.z;
  size_t tg = (size_t)b*HW + (size_t)ci*256;
  int w = tid >> 6, lane = tid & 63, lr = lane & 15, kb = lane >> 4;
  float Aneg = -expf(A_log[h]);

  // cumsum of dt*A: per-wave shfl scan + segment combine
  float dv = 0.f, a = 0.f;
  if (tid < 256) {
    dv = dt[(tg + tid)*2 + h];
    a = dv*Aneg;
    #pragma unroll
    for (int d = 1; d < 64; d <<= 1) {
      float t = __shfl_up(a, d);
      if (lane >= d) a += t;
    }
    if (lane == 63) segs[w] = a;
  }
  __syncthreads();
  if (tid < 256) {
    float off = 0.f;
    #pragma unroll
    for (int j = 0; j < 4; ++j) if (j < w) off += segs[j];
    ac[tid] = a + off;
    dts[tid] = dv;
  }

  // staging (512 threads)
  for (int i = tid; i < 256*16; i += 512) {
    int l = i >> 4, n4 = (i & 15) * 4;
    u16x4 cv = *(const u16x4*)(Cm + (tg + l)*64 + n4);
    *(u16x4*)(Cb + l*64 + swz(l, n4)) = cv;
    u16x4 bv = *(const u16x4*)(Bm + (tg + l)*64 + n4);
    *(u16x4*)(Bb + l*64 + swz(l, n4)) = bv;
  }
  {
    const ushort* ct0 = co2 + ((size_t)(b*512 + (ci << 2)))*16384 + (size_t)h*4096;
    for (int i = tid; i < 64*32; i += 512) {
      int p = i >> 5, sc = (i & 31) * 8;
      u16x8 xv = *(const u16x8*)(ct0 + (size_t)(sc >> 6)*16384 + (size_t)p*64 + (sc & 63));
      *(u16x8*)(xsT + p*256 + swz(p, sc)) = xv;
    }
  }
  size_t sbg = (((size_t)b*NC + ci)*NH + h)*4096;
  for (int i = tid; i < 1024; i += 512) {
    int p = i >> 4, n4 = (i & 15) * 4;
    float4 sv = *(const float4*)(states_in + sbg + p*64 + n4);
    u16x4 pk = { f2b(sv.x), f2b(sv.y), f2b(sv.z), f2b(sv.w) };
    *(u16x4*)(Sb + p*64 + swz(p, n4)) = pk;
  }
  __syncthreads();

  int l0 = w*32;
  ushort* Ww = Wb + w*2304;   // 32 x 72

  // Y2 = C @ S_in^T, row-scaled by exp(ac[l])
  f32x4 yy[2][4];
  #pragma unroll
  for (int m = 0; m < 2; ++m)
    #pragma unroll
    for (int n = 0; n < 4; ++n) yy[m][n] = (f32x4){0.f,0.f,0.f,0.f};
  #pragma unroll
  for (int kk = 0; kk < 64; kk += 32) {
    bf16x8 af[2], bf[4];
    #pragma unroll
    for (int m = 0; m < 2; ++m) af[m] = ldfrag(Cb, l0 + 16*m + lr, kk + kb*8, 64);
    #pragma unroll
    for (int n = 0; n < 4; ++n) bf[n] = ldfrag(Sb, 16*n + lr, kk + kb*8, 64);
    #pragma unroll
    for (int m = 0; m < 2; ++m)
      #pragma unroll
      for (int n = 0; n < 4; ++n)
        yy[m][n] = __builtin_amdgcn_mfma_f32_16x16x32_bf16(af[m], bf[n], yy[m][n], 0, 0, 0);
  }
  #pragma unroll
  for (int m = 0; m < 2; ++m)
    #pragma unroll
    for (int r = 0; r < 4; ++r) {
      float e = __expf(ac[l0 + 16*m + kb*4 + r]);
      #pragma unroll
      for (int n = 0; n < 4; ++n) yy[m][n][r] *= e;
    }

  // s-tile loop (wave-local; no barriers; W' = tril-decay * G * dts[s])
  int nst = (w >> 1) + 1;
  for (int st = 0; st < nst; ++st) {
    int s0 = st*64;
    f32x4 g[2][4];
    #pragma unroll
    for (int m = 0; m < 2; ++m)
      #pragma unroll
      for (int n = 0; n < 4; ++n) g[m][n] = (f32x4){0.f,0.f,0.f,0.f};
    #pragma unroll
    for (int kk = 0; kk < 64; kk += 32) {
      bf16x8 af[2], bf[4];
      #pragma unroll
      for (int m = 0; m < 2; ++m) af[m] = ldfrag(Cb, l0 + 16*m + lr, kk + kb*8, 64);
      #pragma unroll
      for (int n = 0; n < 4; ++n) bf[n] = ldfrag(Bb, s0 + 16*n + lr, kk + kb*8, 64);
      #pragma unroll
      for (int m = 0; m < 2; ++m)
        #pragma unroll
        for (int n = 0; n < 4; ++n)
          g[m][n] = __builtin_amdgcn_mfma_f32_16x16x32_bf16(af[m], bf[n], g[m][n], 0, 0, 0);
    }
    #pragma unroll
    for (int m = 0; m < 2; ++m)
      #pragma unroll
      for (int r = 0; r < 4; ++r) {
        int lrow = 16*m + kb*4 + r;
        int lg = l0 + lrow;
        float acl = ac[lg];
        #pragma unroll
        for (int n = 0; n < 4; ++n) {
          int sl = 16*n + lr;
          int sg = s0 + sl;
          float v = (sg <= lg) ? g[m][n][r] * __expf(acl - ac[sg]) * dts[sg] : 0.f;
          Ww[lrow*72 + sl] = f2b(v);
        }
      }
    // same-wave LDS write->read: ordered by lgkmcnt, no barrier needed
    #pragma unroll
    for (int kk = 0; kk < 64; kk += 32) {
      bf16x8 af[2], bf[4];
      #pragma unroll
      for (int m = 0; m < 2; ++m)
        af[m] = *(const bf16x8*)(Ww + (16*m + lr)*72 + kk + kb*8);
      #pragma unroll
      for (int n = 0; n < 4; ++n) bf[n] = ldfrag(xsT, 16*n + lr, s0 + kk + kb*8, 256);
      #pragma unroll
      for (int m = 0; m < 2; ++m)
        #pragma unroll
        for (int n = 0; n < 4; ++n)
          yy[m][n] = __builtin_amdgcn_mfma_f32_16x16x32_bf16(af[m], bf[n], yy[m][n], 0, 0, 0);
    }
  }

  // + D*xh and store
  float Dh = ssd_D[h];
  #pragma unroll
  for (int m = 0; m < 2; ++m)
    #pragma unroll
    for (int r = 0; r < 4; ++r) {
      int lg = l0 + 16*m + kb*4 + r;
      #pragma unroll
      for (int n = 0; n < 4; ++n) {
        int p = 16*n + lr;
        float val = yy[m][n][r] + Dh * b2f(xsT[p*256 + swz(p, lg)]);
        y[(tg + lg)*128 + h*64 + p] = f2b(val);
      }
    }
}

// ---------------------------------------------------------------------------
// K8 (MFMA): yz = y*silu(z); RMS over 128; out = ctx + yn @ (opw*rms_w)^T.
// ---------------------------------------------------------------------------
__global__ __launch_bounds__(256) void k_final(
    const ushort* __restrict__ y, const ushort* __restrict__ z,
    const float* __restrict__ ctx, const float* __restrict__ rms_w,
    const float* __restrict__ opw, float* __restrict__ out)
{
  __shared__ ushort yn[64*128];    // swizzled [t][k]
  __shared__ ushort wop[64*128];   // swizzled [c][k]
  __shared__ float otile[64*65];
  int tid = threadIdx.x;
  size_t p0 = (size_t)blockIdx.x * 64;

  for (int i = tid; i < 2048; i += 256) {
    int row = i >> 5, c4 = (i & 31) * 4;
    float4 v = ((const float4*)(opw + row*128))[c4 >> 2];
    float4 rw = ((const float4*)rms_w)[c4 >> 2];
    u16x4 p = { f2b(v.x*rw.x), f2b(v.y*rw.y), f2b(v.z*rw.z), f2b(v.w*rw.w) };
    *(u16x4*)(wop + row*128 + swz(row, c4)) = p;
  }

  {
    int t = tid >> 2, q = tid & 3;
    const u16x4* yp = (const u16x4*)(y + (p0 + t)*128 + q*32);
    const u16x4* zp = (const u16x4*)(z + (p0 + t)*128 + q*32);
    float vals[32];
    float ss = 0.f;
    #pragma unroll
    for (int j = 0; j < 8; ++j) {
      u16x4 yv = yp[j];
      u16x4 zv = zp[j];
      #pragma unroll
      for (int e = 0; e < 4; ++e) {
        float zf = b2f(zv[e]);
        float x = b2f(yv[e]) * (zf / (1.f + __expf(-zf)));
        vals[j*4+e] = x; ss += x*x;
      }
    }
    ss += __shfl_xor(ss, 1);
    ss += __shfl_xor(ss, 2);
    float rinv = rsqrtf(ss*(1.f/128.f) + 1e-5f);
    #pragma unroll
    for (int j = 0; j < 8; ++j) {
      int c4 = q*32 + j*4;
      u16x4 p = { f2b(vals[j*4]*rinv), f2b(vals[j*4+1]*rinv),
                  f2b(vals[j*4+2]*rinv), f2b(vals[j*4+3]*rinv) };
      *(u16x4*)(yn + t*128 + swz(t, c4)) = p;
    }
  }
  __syncthreads();

  int w = tid >> 6, lane = tid & 63, lr = lane & 15, kb = lane >> 4;
  f32x4 acc[4];
  #pragma unroll
  for (int n = 0; n < 4; ++n) acc[n] = (f32x4){0.f,0.f,0.f,0.f};
  #pragma unroll
  for (int kk = 0; kk < 128; kk += 32) {
    bf16x8 a = ldfrag(yn, w*16 + lr, kk + kb*8, 128);
    #pragma unroll
    for (int n = 0; n < 4; ++n) {
      bf16x8 bf = ldfrag(wop, n*16 + lr, kk + kb*8, 128);
      acc[n] = __builtin_amdgcn_mfma_f32_16x16x32_bf16(a, bf, acc[n], 0, 0, 0);
    }
  }
  #pragma unroll
  for (int n = 0; n < 4; ++n)
    #pragma unroll
    for (int r = 0; r < 4; ++r) {
      int tok = w*16 + kb*4 + r, ch = n*16 + lr;
      otile[ch*65 + tok] = acc[n][r] + ctx[(p0 + tok)*64 + ch];
    }
  __syncthreads();
  {
    size_t b  = p0 >> 15;
    size_t t0 = p0 & (HW-1);
    for (int r = 0; r < 16; ++r) {
      int cc = r*4 + (tid >> 6);
      int pp = tid & 63;
      out[(b*64 + cc)*HW + t0 + pp] = otile[cc*65 + pp];
    }
  }
}

// ---------------------------------------------------------------------------
extern "C" void kernel_launch(void* const* d_in, const int* in_sizes, int n_in,
                              void* d_out, int out_size, void* d_ws, size_t ws_size,
                              hipStream_t stream) {
  (void)in_sizes; (void)n_in; (void)out_size; (void)ws_size;
  const float* xx   = (const float*)d_in[0];
  const float* sw1  = (const float*)d_in[2];
  const float* sb1  = (const float*)d_in[3];
  const float* sw2  = (const float*)d_in[4];
  const float* sb2  = (const float*)d_in[5];
  const float* vw   = (const float*)d_in[10];
  const float* vb   = (const float*)d_in[11];
  const float* lnw  = (const float*)d_in[12];
  const float* lnb  = (const float*)d_in[13];
  const float* ipw  = (const float*)d_in[14];
  const float* ipb  = (const float*)d_in[15];
  const float* cw   = (const float*)d_in[16];
  const float* cb   = (const float*)d_in[17];
  const float* dtb  = (const float*)d_in[18];
  const float* alog = (const float*)d_in[19];
  const float* sd   = (const float*)d_in[20];
  const float* rmsw = (const float*)d_in[21];
  const float* opw  = (const float*)d_in[22];

  float* ws = (float*)d_ws;
  float*  scores32 = ws;                       // [0, 458752)
  int*    idxb     = (int*)(ws + 458752);      // [458752, 589824)
  int*    cntb     = (int*)(ws + 589824);      // 1
  int*    listb    = (int*)(ws + 589832);      // [589832, 720904)
  float*  dtp      = ws;                       // alias after k_fix (262144 floats)
  float*  seq      = ws + 917504;              // [917504, 9306112)
  ushort* Cmb      = (ushort*)(ws + 917504);   // alias after k_vln (8.4M ushorts)
  ushort* Bmb      = (ushort*)(ws + 5111808);  // alias after k_vln (8.4M ushorts)
  float*  ctx      = ws + 9306112;             // [9306112, 17694720)
  ushort* uswb     = (ushort*)(ws + 17694720); // dead after k_gemm
  float*  states   = ws + 17694720;            // alias after k_gemm
  float*  states_in= ws + 21889024;
  ushort* zb       = (ushort*)(ws + 26083328); // [26083328, 34471936)
  ushort* xbcBb    = (ushort*)(ws + 34471936); // [34471936, 51249152) tile-blocked
  ushort* co2b     = (ushort*)(ws + 51249152); // [51249152, 68026368) tile-blocked
  ushort* yb       = (ushort*)(ws + 68026368); // [68026368, 76414976)
  float*  Alast    = ws + 84803584;
  ushort* wswb     = (ushort*)(ws + 84804608); // 25600 ushorts

  k_score_mfma<<<1792, 256, 0, stream>>>(xx, sw1, sb1, sw2, sb2, scores32, cntb);
  k_argmax<<<512, 256, 0, stream>>>(scores32, idxb, cntb, listb);
  k_fix<<<512, 256, 0, stream>>>(xx, sw1, sb1, sw2, sb2, cntb, listb, idxb);
  k_fuse<<<2048, 256, 0, stream>>>(xx, idxb, seq);
  k_vln<<<2048, 256, 0, stream>>>(seq, vw, vb, lnw, lnb, ctx, uswb);
  k_prep<<<100, 256, 0, stream>>>(ipw, wswb);
  k_gemm<<<2048, 512, 0, stream>>>(uswb, wswb, ipb, dtb, zb, xbcBb, dtp);
  k_conv<<<2048, 256, 0, stream>>>(xbcBb, cw, cb, co2b, Bmb, Cmb);
  dim3 gssd(NC, NH, B4);
  k_states<<<gssd, 256, 67584, stream>>>(dtp, co2b, alog, states, Alast);
  k_scan<<<64, 256, 0, stream>>>(states, Alast, states_in);
  k_ydiag<<<gssd, 512, 145440, stream>>>(dtp, co2b, Bmb, Cmb, states_in, alog, sd, yb);
  k_final<<<2048, 256, 0, stream>>>(yb, zb, ctx, rmsw, opw, (float*)d_out);
}

// Round 15
// 397.191 us; speedup vs baseline: 1.1374x; 1.0467x over previous
//
#include <hip/hip_runtime.h>
#include <cmath>

#define HW 32768      // H*W
#define NC 128        // chunks per batch (HW/256)
#define NH 2          // heads
#define B4 4          // batch (num groups)

typedef __attribute__((ext_vector_type(8))) short bf16x8;
typedef __attribute__((ext_vector_type(4))) float f32x4;
typedef __attribute__((ext_vector_type(4))) ushort u16x4;
typedef __attribute__((ext_vector_type(8))) ushort u16x8;

__device__ __forceinline__ ushort f2b(float x) {
  union { float f; unsigned u; } v; v.f = x;
  unsigned r = v.u + 0x7FFFu + ((v.u >> 16) & 1u);   // RNE
  return (ushort)(r >> 16);
}
__device__ __forceinline__ float b2f(ushort b) {
  union { unsigned u; float f; } v; v.u = ((unsigned)b) << 16;
  return v.f;
}
// XOR-swizzle of element index k within a row (bf16 tiles, 16B-group spread)
__device__ __forceinline__ int swz(int row, int k) { return k ^ ((row & 7) << 3); }
// A-frag: row-major [M][K] (K contig); B-frag: [N][K] (i.e. B^T row-major).
__device__ __forceinline__ bf16x8 ldfrag(const ushort* base, int row, int k, int stride) {
  return *(const bf16x8*)(base + row * stride + swz(row, k));
}

// ---------------------------------------------------------------------------
// K1a (MFMA): score MLP via split-precision weights.
// ---------------------------------------------------------------------------
__global__ __launch_bounds__(256) void k_score_mfma(
    const float* __restrict__ xx, const float* __restrict__ w1,
    const float* __restrict__ b1, const float* __restrict__ w2,
    const float* __restrict__ b2, float* __restrict__ scores,
    int* __restrict__ cnt)
{
  __shared__ ushort Whi[64*64];     // [d][c] swizzled
  __shared__ ushort Wlo[64*64];
  __shared__ ushort Xt[4][64*64];   // per-wave [t][c] swizzled
  __shared__ float w2b1[128];       // w2[0..63] | b1[64..127]
  int tid = threadIdx.x;
  if (blockIdx.x == 0 && tid == 0) cnt[0] = 0;
  for (int i = tid; i < 4096; i += 256) {
    int d = i >> 6, c = i & 63;
    float v = w1[i];
    ushort hi = f2b(v);
    int off = d*64 + swz(d, c);
    Whi[off] = hi;
    Wlo[off] = f2b(v - b2f(hi));
  }
  if (tid < 64) { w2b1[tid] = w2[tid]; w2b1[64+tid] = b1[tid]; }

  int wid = tid >> 6, lane = tid & 63;
  int n  = blockIdx.x >> 7;             // 1792 blocks = 14 n x 128 tiles
  int t0 = (blockIdx.x & 127)*256 + wid*64;

  {
    const float* px = xx + (size_t)n*64*HW + t0 + lane;
    float xv[64];
    #pragma unroll
    for (int c = 0; c < 64; ++c) xv[c] = px[(size_t)c*HW];
    ushort* xh = Xt[wid];
    #pragma unroll
    for (int c8 = 0; c8 < 8; ++c8) {
      u16x8 p;
      #pragma unroll
      for (int j = 0; j < 8; ++j) p[j] = f2b(xv[c8*8 + j]);
      *(u16x8*)(xh + lane*64 + swz(lane, c8*8)) = p;
    }
  }
  __syncthreads();

  int lr = lane & 15, kb = lane >> 4;
  const ushort* xh = Xt[wid];
  f32x4 acc[4][4];
  #pragma unroll
  for (int m = 0; m < 4; ++m)
    #pragma unroll
    for (int nt = 0; nt < 4; ++nt) acc[m][nt] = (f32x4){0.f,0.f,0.f,0.f};
  #pragma unroll
  for (int k0 = 0; k0 < 64; k0 += 32) {
    bf16x8 ah[4], al[4], bx[4];
    #pragma unroll
    for (int m = 0; m < 4; ++m) {
      ah[m] = ldfrag(Whi, 16*m + lr, k0 + kb*8, 64);
      al[m] = ldfrag(Wlo, 16*m + lr, k0 + kb*8, 64);
    }
    #pragma unroll
    for (int nt = 0; nt < 4; ++nt) bx[nt] = ldfrag(xh, 16*nt + lr, k0 + kb*8, 64);
    #pragma unroll
    for (int m = 0; m < 4; ++m)
      #pragma unroll
      for (int nt = 0; nt < 4; ++nt) {
        acc[m][nt] = __builtin_amdgcn_mfma_f32_16x16x32_bf16(ah[m], bx[nt], acc[m][nt], 0, 0, 0);
        acc[m][nt] = __builtin_amdgcn_mfma_f32_16x16x32_bf16(al[m], bx[nt], acc[m][nt], 0, 0, 0);
      }
  }
  float bb2 = b2[0];
  #pragma unroll
  for (int nt = 0; nt < 4; ++nt) {
    float s = 0.f;
    #pragma unroll
    for (int m = 0; m < 4; ++m)
      #pragma unroll
      for (int r = 0; r < 4; ++r) {
        int d = 16*m + kb*4 + r;
        float h = acc[m][nt][r] + w2b1[64 + d];
        s += fmaxf(h, 0.f) * w2b1[d];
      }
    s += __shfl_xor(s, 16);
    s += __shfl_xor(s, 32);
    if (kb == 0) scores[(size_t)n*HW + t0 + 16*nt + lr] = s + bb2;
  }
}

// ---------------------------------------------------------------------------
// K1b: per-(group,pixel) first-max argmax over fp32 scores; flag near-ties.
// ---------------------------------------------------------------------------
__global__ __launch_bounds__(256) void k_argmax(
    const float* __restrict__ scores, int* __restrict__ idx,
    int* __restrict__ cnt, int* __restrict__ list)
{
  int i = blockIdx.x*256 + threadIdx.x;      // 512 blocks: 4*HW
  int g = i >> 15, t = i & (HW-1);
  const int gs0[4] = {0,5,8,12};
  const int gl0[4] = {5,3,4,2};
  int start = gs0[g], len = gl0[g];
  float best = scores[(size_t)start*HW + t];
  float second = -3.4e38f;
  int bi = start;
  for (int j = 1; j < len; ++j) {
    float s = scores[(size_t)(start+j)*HW + t];
    if (s > best) { second = best; best = s; bi = start + j; }
    else if (s > second) second = s;
  }
  idx[i] = bi;
  if (best - second < 5e-4f) {
    int p = atomicAdd(cnt, 1);
    list[p] = i;
  }
}

// ---------------------------------------------------------------------------
// K1c: fp64 recompute of flagged pixels, ONE WAVE PER ENTRY.
// ---------------------------------------------------------------------------
__global__ __launch_bounds__(256) void k_fix(
    const float* __restrict__ xx, const float* __restrict__ w1,
    const float* __restrict__ b1, const float* __restrict__ w2,
    const float* __restrict__ b2, const int* __restrict__ cnt,
    const int* __restrict__ list, int* __restrict__ idx)
{
  __shared__ float w1f[64*65];     // [d][c] padded -> 2-way bank (free)
  __shared__ float w2f[64], b1f[64];
  int tid = threadIdx.x;
  for (int i = tid; i < 4096; i += 256) w1f[(i >> 6)*65 + (i & 63)] = w1[i];
  if (tid < 64) { w2f[tid] = w2[tid]; b1f[tid] = b1[tid]; }
  __syncthreads();
  int n = cnt[0];
  int wid = tid >> 6, lane = tid & 63;
  int nwaves = gridDim.x * 4;
  const int gs0[4] = {0,5,8,12};
  const int gl0[4] = {5,3,4,2};
  double b2d = (double)b2[0];
  for (int e = blockIdx.x*4 + wid; e < n; e += nwaves) {
    int i = list[e];
    int g = i >> 15, t = i & (HW-1);
    int start = gs0[g], len = gl0[g];
    double best = -1e300;
    int bi = start;
    for (int j = 0; j < len; ++j) {
      double xv = (double)xx[(size_t)(start+j)*64*HW + (size_t)lane*HW + t];
      double acc = (double)b1f[lane];
      #pragma unroll
      for (int c = 0; c < 64; ++c) {
        double xc = __shfl(xv, c);
        acc += xc * (double)w1f[lane*65 + c];
      }
      double sc = (acc > 0.0 ? acc : 0.0) * (double)w2f[lane];
      #pragma unroll
      for (int m = 1; m < 64; m <<= 1) sc += __shfl_xor(sc, m);
      sc += b2d;
      if (sc > best) { best = sc; bi = start + j; }   // first-max
    }
    if (lane == 0) idx[i] = bi;
  }
}

// ---------------------------------------------------------------------------
// K2: gather winner (from idx) + transpose to token-major seq.
// ---------------------------------------------------------------------------
__global__ __launch_bounds__(256) void k_fuse(
    const float* __restrict__ xx, const int* __restrict__ idx,
    float* __restrict__ seq)
{
  __shared__ int idxs[64];
  __shared__ float tile[64*65];
  int tid = threadIdx.x;
  int g  = blockIdx.x >> 9;
  int t0 = (blockIdx.x & 511) << 6;
  if (tid < 64) idxs[tid] = idx[(size_t)g*HW + t0 + tid];
  __syncthreads();
  int tl = tid & 63, cq = tid >> 6;
  for (int r = 0; r < 16; ++r) {
    int c = r*4 + cq;
    tile[c*65 + tl] = xx[(size_t)idxs[tl]*64*HW + (size_t)c*HW + t0 + tl];
  }
  __syncthreads();
  for (int r = 0; r < 16; ++r) {
    int row = r*4 + cq;
    seq[((size_t)g*HW + t0 + row)*64 + tl] = tile[tl*65 + row];
  }
}

// ---------------------------------------------------------------------------
// K3: ctx = seq @ v_w^T + v_b; u = LayerNorm(...) -> PRE-SWIZZLED bf16 usw.
// ---------------------------------------------------------------------------
__global__ __launch_bounds__(256) void k_vln(
    const float* __restrict__ seq, const float* __restrict__ vw,
    const float* __restrict__ vb, const float* __restrict__ lnw,
    const float* __restrict__ lnb, float* __restrict__ ctx,
    ushort* __restrict__ usw)
{
  __shared__ float st[64*64];
  int tid = threadIdx.x;
  size_t p0 = (size_t)blockIdx.x * 64;
  for (int i = tid; i < 64*64; i += 256) st[i] = seq[p0*64 + i];
  int o = tid & 63, wv = tid >> 6;
  float w[64];
  const float4* w4 = (const float4*)(vw + o*64);
  #pragma unroll
  for (int c4 = 0; c4 < 16; ++c4) {
    float4 v = w4[c4];
    w[c4*4+0]=v.x; w[c4*4+1]=v.y; w[c4*4+2]=v.z; w[c4*4+3]=v.w;
  }
  float bias = vb[o], lw = lnw[o], lb = lnb[o];
  __syncthreads();
  const float4* st4 = (const float4*)st;
  for (int j = 0; j < 16; ++j) {
    int p = wv*16 + j;
    float acc = bias;
    #pragma unroll
    for (int c4 = 0; c4 < 16; ++c4) {
      float4 s4 = st4[p*16 + c4];
      acc += s4.x*w[c4*4] + s4.y*w[c4*4+1] + s4.z*w[c4*4+2] + s4.w*w[c4*4+3];
    }
    float s1 = acc, s2 = acc*acc;
    #pragma unroll
    for (int m = 1; m < 64; m <<= 1) {
      s1 += __shfl_xor(s1, m);
      s2 += __shfl_xor(s2, m);
    }
    float mu  = s1*(1.f/64.f);
    float var = s2*(1.f/64.f) - mu*mu;
    float rstd = rsqrtf(var + 1e-5f);
    size_t base = (p0+p)*64;
    int gt = (int)(p0 + p);
    ctx[base + o] = acc;
    usw[base + (o ^ (((gt+3)&7)<<3))] = f2b((acc - mu)*rstd*lw + lb);
  }
}

// ---------------------------------------------------------------------------
// k_prep: ipw -> bf16 pre-swizzled wsw (rows >=386 zeroed; 400x64).
// ---------------------------------------------------------------------------
__global__ __launch_bounds__(256) void k_prep(
    const float* __restrict__ ipw, ushort* __restrict__ wsw)
{
  int i = blockIdx.x*256 + threadIdx.x;   // 100*256 = 25600 = 400*64
  int row = i >> 6, c = i & 63;
  float v = (row < 386) ? ipw[row*64 + c] : 0.f;
  wsw[row*64 + swz(row, c)] = f2b(v);
}

// ---------------------------------------------------------------------------
// k_gemm (persistent): 512 blocks, each owns 4 consecutive token tiles.
// W staged ONCE per block; per tile: U stage -> 3 rounds -> dt tail.
// ---------------------------------------------------------------------------
__global__ __launch_bounds__(512) void k_gemm(
    const ushort* __restrict__ usw, const ushort* __restrict__ wsw,
    const float* __restrict__ ipb, const float* __restrict__ dtbias,
    ushort* __restrict__ z, ushort* __restrict__ xbcB, float* __restrict__ dt)
{
  __shared__ ushort Wlds[400*64];   // 51200 B (pre-swizzled copy)
  __shared__ ushort Ulds[80*64];    // 10240 B
  __shared__ ushort trans[8704];    // 17408 B
  int tid = threadIdx.x;
  int b     = blockIdx.x >> 7;
  int chunk = blockIdx.x & 127;
  int w = tid >> 6, lane = tid & 63, lr = lane & 15, kb = lane >> 4;

  for (int i = tid; i < 3200; i += 512)
    *(u16x8*)(Wlds + i*8) = *(const u16x8*)(wsw + i*8);

  for (int it = 0; it < 4; ++it) {
    int s = chunk*4 + it;
    int t0 = s << 6;
    size_t pixbase = (size_t)b*HW + t0;
    size_t tilebase = ((size_t)(b*512 + s))*256*64;
    {
      const ushort* ubase = usw + ((size_t)b*HW + t0 - 3)*64;
      for (int i = tid; i < 536; i += 512) {     // 536*8 = 67*64
        u16x8 v;
        if (t0 == 0 && i < 24) v = (u16x8){0,0,0,0,0,0,0,0};
        else v = *(const u16x8*)(ubase + i*8);
        *(u16x8*)(Ulds + i*8) = v;
      }
    }
    __syncthreads();

    for (int rd = 0; rd < 3; ++rd) {
      int nt = rd*8 + w;
      f32x4 acc[5];
      #pragma unroll
      for (int mt = 0; mt < 5; ++mt) acc[mt] = (f32x4){0.f,0.f,0.f,0.f};
      #pragma unroll
      for (int kk = 0; kk < 64; kk += 32) {
        bf16x8 bfrag = ldfrag(Wlds, nt*16 + lr, kk + kb*8, 64);
        #pragma unroll
        for (int mt = 0; mt < 5; ++mt) {
          bf16x8 afrag = ldfrag(Ulds, mt*16 + lr, kk + kb*8, 64);
          acc[mt] = __builtin_amdgcn_mfma_f32_16x16x32_bf16(afrag, bfrag, acc[mt], 0, 0, 0);
        }
      }
      float bias = ipb[nt*16 + lr];
      if (rd == 0) {          // z channels: trans[t][132]
        #pragma unroll
        for (int mt = 0; mt < 5; ++mt)
          #pragma unroll
          for (int r = 0; r < 4; ++r) {
            int t = mt*16 + kb*4 + r - 3;
            if (t >= 0 && t < 64) trans[t*132 + w*16 + lr] = f2b(acc[mt][r] + bias);
          }
      } else {                // xbc channels: trans[ch][68]
        #pragma unroll
        for (int mt = 0; mt < 5; ++mt)
          #pragma unroll
          for (int r = 0; r < 4; ++r) {
            int t = mt*16 + kb*4 + r - 3;
            if (t >= 0 && t < 64) trans[(w*16 + lr)*68 + t] = f2b(acc[mt][r] + bias);
          }
      }
      __syncthreads();
      if (rd == 0) {
        for (int i = tid; i < 2048; i += 512) {
          int t = i >> 5, c4 = (i & 31)*4;
          *(u16x4*)(z + (pixbase + t)*128 + c4) = *(const u16x4*)(trans + t*132 + c4);
        }
      } else {
        int chbase = (rd - 1)*128;
        for (int i = tid; i < 2048; i += 512) {
          int ch = i >> 4, t4 = (i & 15)*4;
          *(u16x4*)(xbcB + tilebase + (size_t)(chbase + ch)*64 + t4)
              = *(const u16x4*)(trans + ch*68 + t4);
        }
      }
      __syncthreads();
    }

    if (w == 0) {    // dt rows 384/385
      f32x4 acc[5];
      #pragma unroll
      for (int mt = 0; mt < 5; ++mt) acc[mt] = (f32x4){0.f,0.f,0.f,0.f};
      #pragma unroll
      for (int kk = 0; kk < 64; kk += 32) {
        bf16x8 bfrag = ldfrag(Wlds, 384 + lr, kk + kb*8, 64);
        #pragma unroll
        for (int mt = 0; mt < 5; ++mt) {
          bf16x8 afrag = ldfrag(Ulds, mt*16 + lr, kk + kb*8, 64);
          acc[mt] = __builtin_amdgcn_mfma_f32_16x16x32_bf16(afrag, bfrag, acc[mt], 0, 0, 0);
        }
      }
      if (lr < 2) {
        float bias = ipb[384 + lr] + dtbias[lr];
        #pragma unroll
        for (int mt = 0; mt < 5; ++mt)
          #pragma unroll
          for (int r = 0; r < 4; ++r) {
            int t = mt*16 + kb*4 + r - 3;
            if (t >= 0 && t < 64) {
              float a = acc[mt][r] + bias;
              dt[(pixbase + t)*2 + lr] = (a > 20.f) ? a : log1pf(expf(a));
            }
          }
      }
    }
    __syncthreads();   // Ulds reuse hazard (dt tail reads it)
  }
}

// ---------------------------------------------------------------------------
// k_conv: depthwise conv(K=4)+silu from tile-blocked xbcB -> co2 tile-blocked;
// Bm/Cm token-major via bank-swizzled LDS transpose.
// ---------------------------------------------------------------------------
__global__ __launch_bounds__(256) void k_conv(
    const ushort* __restrict__ xbcB, const float* __restrict__ convw,
    const float* __restrict__ convb, ushort* __restrict__ co2,
    ushort* __restrict__ Bm, ushort* __restrict__ Cm)
{
  __shared__ ushort bmc[64*132];    // [t][128] swizzled: col = c ^ ((t>>3)<<2)
  int tid = threadIdx.x;
  int b  = blockIdx.x >> 9;
  int s  = blockIdx.x & 511;
  int lane = tid & 63, wv = tid >> 6;
  int toct = lane & 7, chi = lane >> 3;
  size_t tilebase = ((size_t)(b*512 + s))*256*64;
  const ushort* tsrc = xbcB + tilebase;
  const ushort* psrc = xbcB + tilebase - 256*64;   // prev tile (valid if s>0)

  for (int it = 0; it < 8; ++it) {
    int ch = wv*64 + it*8 + chi;
    u16x8 v = *(const u16x8*)(tsrc + ch*64 + toct*8);
    float x0 = b2f(v[0]), x1 = b2f(v[1]), x2 = b2f(v[2]), x3 = b2f(v[3]);
    float x4 = b2f(v[4]), x5 = b2f(v[5]), x6 = b2f(v[6]), x7 = b2f(v[7]);
    float pm1 = __shfl(x7, lane - 1);
    float pm2 = __shfl(x6, lane - 1);
    float pm3 = __shfl(x5, lane - 1);
    if (toct == 0) {
      if (s > 0) {
        u16x4 hq = *(const u16x4*)(psrc + ch*64 + 60);
        pm3 = b2f(hq[1]); pm2 = b2f(hq[2]); pm1 = b2f(hq[3]);
      } else {
        pm1 = pm2 = pm3 = 0.f;
      }
    }
    float4 cw = ((const float4*)convw)[ch];
    float cb = convb[ch];
    float o0 = cb + cw.x*pm3 + cw.y*pm2 + cw.z*pm1 + cw.w*x0;
    float o1 = cb + cw.x*pm2 + cw.y*pm1 + cw.z*x0  + cw.w*x1;
    float o2 = cb + cw.x*pm1 + cw.y*x0  + cw.z*x1  + cw.w*x2;
    float o3 = cb + cw.x*x0  + cw.y*x1  + cw.z*x2  + cw.w*x3;
    float o4 = cb + cw.x*x1  + cw.y*x2  + cw.z*x3  + cw.w*x4;
    float o5 = cb + cw.x*x2  + cw.y*x3  + cw.z*x4  + cw.w*x5;
    float o6 = cb + cw.x*x3  + cw.y*x4  + cw.z*x5  + cw.w*x6;
    float o7 = cb + cw.x*x4  + cw.y*x5  + cw.z*x6  + cw.w*x7;
    u16x8 ov;
    ov[0] = f2b(o0 / (1.f + __expf(-o0)));
    ov[1] = f2b(o1 / (1.f + __expf(-o1)));
    ov[2] = f2b(o2 / (1.f + __expf(-o2)));
    ov[3] = f2b(o3 / (1.f + __expf(-o3)));
    ov[4] = f2b(o4 / (1.f + __expf(-o4)));
    ov[5] = f2b(o5 / (1.f + __expf(-o5)));
    ov[6] = f2b(o6 / (1.f + __expf(-o6)));
    ov[7] = f2b(o7 / (1.f + __expf(-o7)));
    *(u16x8*)(co2 + tilebase + (size_t)ch*64 + toct*8) = ov;
    if (ch >= 128) {
      int c = ch - 128;
      int csw = c ^ (toct << 2);
      #pragma unroll
      for (int j = 0; j < 8; ++j)
        bmc[(toct*8 + j)*132 + csw] = ov[j];
    }
  }
  __syncthreads();
  size_t tg = (size_t)b*HW + s*64;
  for (int i = tid; i < 1024; i += 256) {
    int tt = i >> 4, n4 = (i & 15)*4;
    int sw = (tt >> 3) << 2;
    *(u16x4*)(Bm + (tg + tt)*64 + n4) = *(const u16x4*)(bmc + tt*132 + (n4 ^ sw));
    *(u16x4*)(Cm + (tg + tt)*64 + n4) = *(const u16x4*)(bmc + tt*132 + ((64 + n4) ^ sw));
  }
}

// ---------------------------------------------------------------------------
// K5 (MFMA): states[p,n] = sum_l xd[l,p]*B[l,n]. Reads tile-blocked co2.
// ---------------------------------------------------------------------------
__global__ __launch_bounds__(256) void k_states(
    const float* __restrict__ dt, const ushort* __restrict__ co2,
    const float* __restrict__ A_log,
    float* __restrict__ states, float* __restrict__ A_last)
{
  extern __shared__ char smem[];
  float* ac  = (float*)smem;            // 256
  float* dec = ac + 256;                // 256
  ushort* xdT = (ushort*)(dec + 256);   // 64 x 256
  ushort* BT  = xdT + 16384;            // 64 x 256
  int tid = threadIdx.x;
  int ci = blockIdx.x, h = blockIdx.y, b = blockIdx.z;
  size_t tg = (size_t)b*HW + (size_t)ci*256;
  float Aneg = -expf(A_log[h]);
  float dv = dt[(tg + tid)*2 + h];
  ac[tid] = dv*Aneg;
  __syncthreads();
  for (int off = 1; off < 256; off <<= 1) {
    float v = (tid >= off) ? ac[tid - off] : 0.f;
    __syncthreads();
    ac[tid] += v;
    __syncthreads();
  }
  float alast = ac[255];
  dec[tid] = dv * __expf(alast - ac[tid]);
  __syncthreads();
  for (int i = tid; i < 64*32; i += 256) {
    int p = i >> 5, lc = (i & 31) * 8;
    int s = (ci << 2) + (lc >> 6);
    const ushort* cb2 = co2 + ((size_t)(b*512 + s))*256*64 + (lc & 63);
    u16x8 xv = *(const u16x8*)(cb2 + (size_t)(h*64 + p)*64);
    u16x8 o;
    #pragma unroll
    for (int e = 0; e < 8; ++e) o[e] = f2b(b2f(xv[e]) * dec[lc + e]);
    *(u16x8*)(xdT + p*256 + swz(p, lc)) = o;
    u16x8 bv = *(const u16x8*)(cb2 + (size_t)(128 + p)*64);
    *(u16x8*)(BT + p*256 + swz(p, lc)) = bv;
  }
  __syncthreads();
  int w = tid >> 6, lane = tid & 63, lr = lane & 15, kb = lane >> 4;
  f32x4 acc[4];
  #pragma unroll
  for (int m = 0; m < 4; ++m) acc[m] = (f32x4){0.f,0.f,0.f,0.f};
  for (int k0 = 0; k0 < 256; k0 += 32) {
    bf16x8 bfrag = ldfrag(BT, 16*w + lr, k0 + kb*8, 256);
    #pragma unroll
    for (int m = 0; m < 4; ++m) {
      bf16x8 afrag = ldfrag(xdT, 16*m + lr, k0 + kb*8, 256);
      acc[m] = __builtin_amdgcn_mfma_f32_16x16x32_bf16(afrag, bfrag, acc[m], 0, 0, 0);
    }
  }
  size_t sb = (((size_t)b*NC + ci)*NH + h)*4096;
  #pragma unroll
  for (int m = 0; m < 4; ++m)
    #pragma unroll
    for (int r = 0; r < 4; ++r)
      states[sb + (size_t)(16*m + kb*4 + r)*64 + 16*w + lr] = acc[m][r];
  if (tid == 0) A_last[((size_t)b*NH + h)*NC + ci] = alast;
}

// ---------------------------------------------------------------------------
// K6: inter-chunk scan with prefetch; 64 blocks (b,h,seg).
// ---------------------------------------------------------------------------
__global__ __launch_bounds__(256) void k_scan(
    const float* __restrict__ states, const float* __restrict__ A_last,
    float* __restrict__ states_in)
{
  __shared__ float ef[NC];
  int tid = threadIdx.x;
  int seg = blockIdx.x & 7, h = (blockIdx.x >> 3) & 1, b = blockIdx.x >> 4;
  if (tid < NC) ef[tid] = __expf(A_last[((size_t)b*NH + h)*NC + tid]);
  __syncthreads();
  size_t base0 = (((size_t)b*NC)*NH + h)*4096 + seg*512 + tid;
  const size_t cstride = (size_t)NH*4096;
  float s0 = 0.f, s1 = 0.f;
  float ld0 = states[base0], ld1 = states[base0 + 256];
  for (int zc = 0; zc < NC; ++zc) {
    size_t cur = base0 + (size_t)zc*cstride;
    float n0 = 0.f, n1 = 0.f;
    if (zc < NC-1) { n0 = states[cur + cstride]; n1 = states[cur + cstride + 256]; }
    states_in[cur] = s0; states_in[cur + 256] = s1;
    float e = ef[zc];
    s0 = ld0 + e*s0; s1 = ld1 + e*s1;
    ld0 = n0; ld1 = n1;
  }
}

// ---------------------------------------------------------------------------
// K7 (MFMA): per chunk-head SSD Y.  y -> bf16.  512 thr / 8 waves.
// BALANCED: wave w owns 16-row strips {w, 15-w} -> 5 strip-tile units each.
// LDS staging (C/B/xh/S) + stride-72 per-wave W' (16x72); dt folded into W'.
// ---------------------------------------------------------------------------
__global__ __launch_bounds__(512) void k_ydiag(
    const float* __restrict__ dt, const ushort* __restrict__ co2,
    const ushort* __restrict__ Bm, const ushort* __restrict__ Cm,
    const float* __restrict__ states_in, const float* __restrict__ A_log,
    const float* __restrict__ ssd_D, ushort* __restrict__ y)
{
  extern __shared__ char smem[];
  float* ac   = (float*)smem;           // 256
  float* dts  = ac + 256;               // 256
  float* segs = dts + 256;              // 8 (4 used)
  ushort* Cb  = (ushort*)(segs + 8);    // 256 x 64   [l][n] swizzled
  ushort* Bb  = Cb + 16384;             // 256 x 64   [s][n] swizzled
  ushort* xsT = Bb + 16384;             // 64 x 256   [p][s] swizzled (pure xh)
  ushort* Sb  = xsT + 16384;            // 64 x 64    [p][n] swizzled
  ushort* Wb  = Sb + 4096;              // 8 x (16 x 72) per-wave [l][s]
  int tid = threadIdx.x;
  int ci = blockIdx.x, h = blockIdx.y, b = blockIdx.z;
  size_t tg = (size_t)b*HW + (size_t)ci*256;
  int w = tid >> 6, lane = tid & 63, lr = lane & 15, kb = lane >> 4;
  float Aneg = -expf(A_log[h]);

  // cumsum of dt*A: per-wave shfl scan + segment combine
  float dv = 0.f, a = 0.f;
  if (tid < 256) {
    dv = dt[(tg + tid)*2 + h];
    a = dv*Aneg;
    #pragma unroll
    for (int d = 1; d < 64; d <<= 1) {
      float t = __shfl_up(a, d);
      if (lane >= d) a += t;
    }
    if (lane == 63) segs[w] = a;
  }
  __syncthreads();
  if (tid < 256) {
    float off = 0.f;
    #pragma unroll
    for (int j = 0; j < 4; ++j) if (j < w) off += segs[j];
    ac[tid] = a + off;
    dts[tid] = dv;
  }

  // staging (512 threads)
  for (int i = tid; i < 256*16; i += 512) {
    int l = i >> 4, n4 = (i & 15) * 4;
    u16x4 cv = *(const u16x4*)(Cm + (tg + l)*64 + n4);
    *(u16x4*)(Cb + l*64 + swz(l, n4)) = cv;
    u16x4 bv = *(const u16x4*)(Bm + (tg + l)*64 + n4);
    *(u16x4*)(Bb + l*64 + swz(l, n4)) = bv;
  }
  {
    const ushort* ct0 = co2 + ((size_t)(b*512 + (ci << 2)))*16384 + (size_t)h*4096;
    for (int i = tid; i < 64*32; i += 512) {
      int p = i >> 5, sc = (i & 31) * 8;
      u16x8 xv = *(const u16x8*)(ct0 + (size_t)(sc >> 6)*16384 + (size_t)p*64 + (sc & 63));
      *(u16x8*)(xsT + p*256 + swz(p, sc)) = xv;
    }
  }
  size_t sbg = (((size_t)b*NC + ci)*NH + h)*4096;
  for (int i = tid; i < 1024; i += 512) {
    int p = i >> 4, n4 = (i & 15) * 4;
    float4 sv = *(const float4*)(states_in + sbg + p*64 + n4);
    u16x4 pk = { f2b(sv.x), f2b(sv.y), f2b(sv.z), f2b(sv.w) };
    *(u16x4*)(Sb + p*64 + swz(p, n4)) = pk;
  }
  __syncthreads();

  int strips[2] = { w, 15 - w };
  ushort* Ww = Wb + w*1152;   // 16 x 72

  // Y2 = C @ S_in^T (both strips), row-scaled by exp(ac[l])
  f32x4 yy[2][4];
  #pragma unroll
  for (int sp = 0; sp < 2; ++sp)
    #pragma unroll
    for (int n = 0; n < 4; ++n) yy[sp][n] = (f32x4){0.f,0.f,0.f,0.f};
  #pragma unroll
  for (int kk = 0; kk < 64; kk += 32) {
    bf16x8 af[2], bf[4];
    #pragma unroll
    for (int sp = 0; sp < 2; ++sp) af[sp] = ldfrag(Cb, strips[sp]*16 + lr, kk + kb*8, 64);
    #pragma unroll
    for (int n = 0; n < 4; ++n) bf[n] = ldfrag(Sb, 16*n + lr, kk + kb*8, 64);
    #pragma unroll
    for (int sp = 0; sp < 2; ++sp)
      #pragma unroll
      for (int n = 0; n < 4; ++n)
        yy[sp][n] = __builtin_amdgcn_mfma_f32_16x16x32_bf16(af[sp], bf[n], yy[sp][n], 0, 0, 0);
  }
  #pragma unroll
  for (int sp = 0; sp < 2; ++sp)
    #pragma unroll
    for (int r = 0; r < 4; ++r) {
      float e = __expf(ac[strips[sp]*16 + kb*4 + r]);
      #pragma unroll
      for (int n = 0; n < 4; ++n) yy[sp][n][r] *= e;
    }

  // per-strip s-tile loop (wave-local; no barriers; W' = tril-decay*G*dts[s])
  #pragma unroll
  for (int sp = 0; sp < 2; ++sp) {
    int strip = strips[sp];
    int l0 = strip*16;
    int nst = (strip >> 2) + 1;
    for (int st = 0; st < nst; ++st) {
      int s0 = st*64;
      f32x4 g[4];
      #pragma unroll
      for (int n = 0; n < 4; ++n) g[n] = (f32x4){0.f,0.f,0.f,0.f};
      #pragma unroll
      for (int kk = 0; kk < 64; kk += 32) {
        bf16x8 af = ldfrag(Cb, l0 + lr, kk + kb*8, 64);
        bf16x8 bf[4];
        #pragma unroll
        for (int n = 0; n < 4; ++n) bf[n] = ldfrag(Bb, s0 + 16*n + lr, kk + kb*8, 64);
        #pragma unroll
        for (int n = 0; n < 4; ++n)
          g[n] = __builtin_amdgcn_mfma_f32_16x16x32_bf16(af, bf[n], g[n], 0, 0, 0);
      }
      #pragma unroll
      for (int r = 0; r < 4; ++r) {
        int lrow = kb*4 + r;
        int lg = l0 + lrow;
        float acl = ac[lg];
        #pragma unroll
        for (int n = 0; n < 4; ++n) {
          int sl = 16*n + lr;
          int sg = s0 + sl;
          float v = (sg <= lg) ? g[n][r] * __expf(acl - ac[sg]) * dts[sg] : 0.f;
          Ww[lrow*72 + sl] = f2b(v);
        }
      }
      // same-wave LDS write->read: ordered by lgkmcnt, no barrier needed
      #pragma unroll
      for (int kk = 0; kk < 64; kk += 32) {
        bf16x8 af = *(const bf16x8*)(Ww + lr*72 + kk + kb*8);
        bf16x8 bf[4];
        #pragma unroll
        for (int n = 0; n < 4; ++n) bf[n] = ldfrag(xsT, 16*n + lr, s0 + kk + kb*8, 256);
        #pragma unroll
        for (int n = 0; n < 4; ++n)
          yy[sp][n] = __builtin_amdgcn_mfma_f32_16x16x32_bf16(af, bf[n], yy[sp][n], 0, 0, 0);
      }
    }
  }

  // + D*xh and store
  float Dh = ssd_D[h];
  #pragma unroll
  for (int sp = 0; sp < 2; ++sp)
    #pragma unroll
    for (int r = 0; r < 4; ++r) {
      int lg = strips[sp]*16 + kb*4 + r;
      #pragma unroll
      for (int n = 0; n < 4; ++n) {
        int p = 16*n + lr;
        float val = yy[sp][n][r] + Dh * b2f(xsT[p*256 + swz(p, lg)]);
        y[(tg + lg)*128 + h*64 + p] = f2b(val);
      }
    }
}

// ---------------------------------------------------------------------------
// K8 (MFMA): yz = y*silu(z); RMS over 128; out = ctx + yn @ (opw*rms_w)^T.
// ---------------------------------------------------------------------------
__global__ __launch_bounds__(256) void k_final(
    const ushort* __restrict__ y, const ushort* __restrict__ z,
    const float* __restrict__ ctx, const float* __restrict__ rms_w,
    const float* __restrict__ opw, float* __restrict__ out)
{
  __shared__ ushort yn[64*128];    // swizzled [t][k]
  __shared__ ushort wop[64*128];   // swizzled [c][k]
  __shared__ float otile[64*65];
  int tid = threadIdx.x;
  size_t p0 = (size_t)blockIdx.x * 64;

  for (int i = tid; i < 2048; i += 256) {
    int row = i >> 5, c4 = (i & 31) * 4;
    float4 v = ((const float4*)(opw + row*128))[c4 >> 2];
    float4 rw = ((const float4*)rms_w)[c4 >> 2];
    u16x4 p = { f2b(v.x*rw.x), f2b(v.y*rw.y), f2b(v.z*rw.z), f2b(v.w*rw.w) };
    *(u16x4*)(wop + row*128 + swz(row, c4)) = p;
  }

  {
    int t = tid >> 2, q = tid & 3;
    const u16x4* yp = (const u16x4*)(y + (p0 + t)*128 + q*32);
    const u16x4* zp = (const u16x4*)(z + (p0 + t)*128 + q*32);
    float vals[32];
    float ss = 0.f;
    #pragma unroll
    for (int j = 0; j < 8; ++j) {
      u16x4 yv = yp[j];
      u16x4 zv = zp[j];
      #pragma unroll
      for (int e = 0; e < 4; ++e) {
        float zf = b2f(zv[e]);
        float x = b2f(yv[e]) * (zf / (1.f + __expf(-zf)));
        vals[j*4+e] = x; ss += x*x;
      }
    }
    ss += __shfl_xor(ss, 1);
    ss += __shfl_xor(ss, 2);
    float rinv = rsqrtf(ss*(1.f/128.f) + 1e-5f);
    #pragma unroll
    for (int j = 0; j < 8; ++j) {
      int c4 = q*32 + j*4;
      u16x4 p = { f2b(vals[j*4]*rinv), f2b(vals[j*4+1]*rinv),
                  f2b(vals[j*4+2]*rinv), f2b(vals[j*4+3]*rinv) };
      *(u16x4*)(yn + t*128 + swz(t, c4)) = p;
    }
  }
  __syncthreads();

  int w = tid >> 6, lane = tid & 63, lr = lane & 15, kb = lane >> 4;
  f32x4 acc[4];
  #pragma unroll
  for (int n = 0; n < 4; ++n) acc[n] = (f32x4){0.f,0.f,0.f,0.f};
  #pragma unroll
  for (int kk = 0; kk < 128; kk += 32) {
    bf16x8 a = ldfrag(yn, w*16 + lr, kk + kb*8, 128);
    #pragma unroll
    for (int n = 0; n < 4; ++n) {
      bf16x8 bf = ldfrag(wop, n*16 + lr, kk + kb*8, 128);
      acc[n] = __builtin_amdgcn_mfma_f32_16x16x32_bf16(a, bf, acc[n], 0, 0, 0);
    }
  }
  #pragma unroll
  for (int n = 0; n < 4; ++n)
    #pragma unroll
    for (int r = 0; r < 4; ++r) {
      int tok = w*16 + kb*4 + r, ch = n*16 + lr;
      otile[ch*65 + tok] = acc[n][r] + ctx[(p0 + tok)*64 + ch];
    }
  __syncthreads();
  {
    size_t b  = p0 >> 15;
    size_t t0 = p0 & (HW-1);
    for (int r = 0; r < 16; ++r) {
      int cc = r*4 + (tid >> 6);
      int pp = tid & 63;
      out[(b*64 + cc)*HW + t0 + pp] = otile[cc*65 + pp];
    }
  }
}

// ---------------------------------------------------------------------------
extern "C" void kernel_launch(void* const* d_in, const int* in_sizes, int n_in,
                              void* d_out, int out_size, void* d_ws, size_t ws_size,
                              hipStream_t stream) {
  (void)in_sizes; (void)n_in; (void)out_size; (void)ws_size;
  const float* xx   = (const float*)d_in[0];
  const float* sw1  = (const float*)d_in[2];
  const float* sb1  = (const float*)d_in[3];
  const float* sw2  = (const float*)d_in[4];
  const float* sb2  = (const float*)d_in[5];
  const float* vw   = (const float*)d_in[10];
  const float* vb   = (const float*)d_in[11];
  const float* lnw  = (const float*)d_in[12];
  const float* lnb  = (const float*)d_in[13];
  const float* ipw  = (const float*)d_in[14];
  const float* ipb  = (const float*)d_in[15];
  const float* cw   = (const float*)d_in[16];
  const float* cb   = (const float*)d_in[17];
  const float* dtb  = (const float*)d_in[18];
  const float* alog = (const float*)d_in[19];
  const float* sd   = (const float*)d_in[20];
  const float* rmsw = (const float*)d_in[21];
  const float* opw  = (const float*)d_in[22];

  float* ws = (float*)d_ws;
  float*  scores32 = ws;                       // [0, 458752)
  int*    idxb     = (int*)(ws + 458752);      // [458752, 589824)
  int*    cntb     = (int*)(ws + 589824);      // 1
  int*    listb    = (int*)(ws + 589832);      // [589832, 720904)
  float*  dtp      = ws;                       // alias after k_fix (262144 floats)
  float*  seq      = ws + 917504;              // [917504, 9306112)
  ushort* Cmb      = (ushort*)(ws + 917504);   // alias after k_vln (8.4M ushorts)
  ushort* Bmb      = (ushort*)(ws + 5111808);  // alias after k_vln (8.4M ushorts)
  float*  ctx      = ws + 9306112;             // [9306112, 17694720)
  ushort* uswb     = (ushort*)(ws + 17694720); // dead after k_gemm
  float*  states   = ws + 17694720;            // alias after k_gemm
  float*  states_in= ws + 21889024;
  ushort* zb       = (ushort*)(ws + 26083328); // [26083328, 34471936)
  ushort* xbcBb    = (ushort*)(ws + 34471936); // [34471936, 51249152) tile-blocked
  ushort* co2b     = (ushort*)(ws + 51249152); // [51249152, 68026368) tile-blocked
  ushort* yb       = (ushort*)(ws + 68026368); // [68026368, 76414976)
  float*  Alast    = ws + 84803584;
  ushort* wswb     = (ushort*)(ws + 84804608); // 25600 ushorts

  k_score_mfma<<<1792, 256, 0, stream>>>(xx, sw1, sb1, sw2, sb2, scores32, cntb);
  k_argmax<<<512, 256, 0, stream>>>(scores32, idxb, cntb, listb);
  k_fix<<<512, 256, 0, stream>>>(xx, sw1, sb1, sw2, sb2, cntb, listb, idxb);
  k_fuse<<<2048, 256, 0, stream>>>(xx, idxb, seq);
  k_vln<<<2048, 256, 0, stream>>>(seq, vw, vb, lnw, lnb, ctx, uswb);
  k_prep<<<100, 256, 0, stream>>>(ipw, wswb);
  k_gemm<<<512, 512, 0, stream>>>(uswb, wswb, ipb, dtb, zb, xbcBb, dtp);
  k_conv<<<2048, 256, 0, stream>>>(xbcBb, cw, cb, co2b, Bmb, Cmb);
  dim3 gssd(NC, NH, B4);
  k_states<<<gssd, 256, 67584, stream>>>(dtp, co2b, alog, states, Alast);
  k_scan<<<64, 256, 0, stream>>>(states, Alast, states_in);
  k_ydiag<<<gssd, 512, 127008, stream>>>(dtp, co2b, Bmb, Cmb, states_in, alog, sd, yb);
  k_final<<<2048, 256, 0, stream>>>(yb, zb, ctx, rmsw, opw, (float*)d_out);
}

// Round 16
// 388.062 us; speedup vs baseline: 1.1642x; 1.0235x over previous
//
#include <hip/hip_runtime.h>
#include <cmath>

#define HW 32768      // H*W
#define NC 128        // chunks per batch (HW/256)
#define NH 2          // heads
#define B4 4          // batch (num groups)

typedef __attribute__((ext_vector_type(8))) short bf16x8;
typedef __attribute__((ext_vector_type(4))) float f32x4;
typedef __attribute__((ext_vector_type(4))) ushort u16x4;
typedef __attribute__((ext_vector_type(8))) ushort u16x8;

__device__ __forceinline__ ushort f2b(float x) {
  union { float f; unsigned u; } v; v.f = x;
  unsigned r = v.u + 0x7FFFu + ((v.u >> 16) & 1u);   // RNE
  return (ushort)(r >> 16);
}
__device__ __forceinline__ float b2f(ushort b) {
  union { unsigned u; float f; } v; v.u = ((unsigned)b) << 16;
  return v.f;
}
// XOR-swizzle of element index k within a row (bf16 tiles, 16B-group spread)
__device__ __forceinline__ int swz(int row, int k) { return k ^ ((row & 7) << 3); }
// A-frag: row-major [M][K] (K contig); B-frag: [N][K] (i.e. B^T row-major).
__device__ __forceinline__ bf16x8 ldfrag(const ushort* base, int row, int k, int stride) {
  return *(const bf16x8*)(base + row * stride + swz(row, k));
}

// ---------------------------------------------------------------------------
// K1a (MFMA): score MLP via split-precision weights.
// ---------------------------------------------------------------------------
__global__ __launch_bounds__(256) void k_score_mfma(
    const float* __restrict__ xx, const float* __restrict__ w1,
    const float* __restrict__ b1, const float* __restrict__ w2,
    const float* __restrict__ b2, float* __restrict__ scores,
    int* __restrict__ cnt)
{
  __shared__ ushort Whi[64*64];     // [d][c] swizzled
  __shared__ ushort Wlo[64*64];
  __shared__ ushort Xt[4][64*64];   // per-wave [t][c] swizzled
  __shared__ float w2b1[128];       // w2[0..63] | b1[64..127]
  int tid = threadIdx.x;
  if (blockIdx.x == 0 && tid == 0) cnt[0] = 0;
  for (int i = tid; i < 4096; i += 256) {
    int d = i >> 6, c = i & 63;
    float v = w1[i];
    ushort hi = f2b(v);
    int off = d*64 + swz(d, c);
    Whi[off] = hi;
    Wlo[off] = f2b(v - b2f(hi));
  }
  if (tid < 64) { w2b1[tid] = w2[tid]; w2b1[64+tid] = b1[tid]; }

  int wid = tid >> 6, lane = tid & 63;
  int n  = blockIdx.x >> 7;             // 1792 blocks = 14 n x 128 tiles
  int t0 = (blockIdx.x & 127)*256 + wid*64;

  {
    const float* px = xx + (size_t)n*64*HW + t0 + lane;
    float xv[64];
    #pragma unroll
    for (int c = 0; c < 64; ++c) xv[c] = px[(size_t)c*HW];
    ushort* xh = Xt[wid];
    #pragma unroll
    for (int c8 = 0; c8 < 8; ++c8) {
      u16x8 p;
      #pragma unroll
      for (int j = 0; j < 8; ++j) p[j] = f2b(xv[c8*8 + j]);
      *(u16x8*)(xh + lane*64 + swz(lane, c8*8)) = p;
    }
  }
  __syncthreads();

  int lr = lane & 15, kb = lane >> 4;
  const ushort* xh = Xt[wid];
  f32x4 acc[4][4];
  #pragma unroll
  for (int m = 0; m < 4; ++m)
    #pragma unroll
    for (int nt = 0; nt < 4; ++nt) acc[m][nt] = (f32x4){0.f,0.f,0.f,0.f};
  #pragma unroll
  for (int k0 = 0; k0 < 64; k0 += 32) {
    bf16x8 ah[4], al[4], bx[4];
    #pragma unroll
    for (int m = 0; m < 4; ++m) {
      ah[m] = ldfrag(Whi, 16*m + lr, k0 + kb*8, 64);
      al[m] = ldfrag(Wlo, 16*m + lr, k0 + kb*8, 64);
    }
    #pragma unroll
    for (int nt = 0; nt < 4; ++nt) bx[nt] = ldfrag(xh, 16*nt + lr, k0 + kb*8, 64);
    #pragma unroll
    for (int m = 0; m < 4; ++m)
      #pragma unroll
      for (int nt = 0; nt < 4; ++nt) {
        acc[m][nt] = __builtin_amdgcn_mfma_f32_16x16x32_bf16(ah[m], bx[nt], acc[m][nt], 0, 0, 0);
        acc[m][nt] = __builtin_amdgcn_mfma_f32_16x16x32_bf16(al[m], bx[nt], acc[m][nt], 0, 0, 0);
      }
  }
  float bb2 = b2[0];
  #pragma unroll
  for (int nt = 0; nt < 4; ++nt) {
    float s = 0.f;
    #pragma unroll
    for (int m = 0; m < 4; ++m)
      #pragma unroll
      for (int r = 0; r < 4; ++r) {
        int d = 16*m + kb*4 + r;
        float h = acc[m][nt][r] + w2b1[64 + d];
        s += fmaxf(h, 0.f) * w2b1[d];
      }
    s += __shfl_xor(s, 16);
    s += __shfl_xor(s, 32);
    if (kb == 0) scores[(size_t)n*HW + t0 + 16*nt + lr] = s + bb2;
  }
}

// ---------------------------------------------------------------------------
// K1b: per-(group,pixel) first-max argmax over fp32 scores; flag near-ties.
// ---------------------------------------------------------------------------
__global__ __launch_bounds__(256) void k_argmax(
    const float* __restrict__ scores, int* __restrict__ idx,
    int* __restrict__ cnt, int* __restrict__ list)
{
  int i = blockIdx.x*256 + threadIdx.x;      // 512 blocks: 4*HW
  int g = i >> 15, t = i & (HW-1);
  const int gs0[4] = {0,5,8,12};
  const int gl0[4] = {5,3,4,2};
  int start = gs0[g], len = gl0[g];
  float best = scores[(size_t)start*HW + t];
  float second = -3.4e38f;
  int bi = start;
  for (int j = 1; j < len; ++j) {
    float s = scores[(size_t)(start+j)*HW + t];
    if (s > best) { second = best; best = s; bi = start + j; }
    else if (s > second) second = s;
  }
  idx[i] = bi;
  if (best - second < 5e-4f) {
    int p = atomicAdd(cnt, 1);
    list[p] = i;
  }
}

// ---------------------------------------------------------------------------
// K1c: fp64 recompute of flagged pixels, ONE WAVE PER ENTRY.
// ---------------------------------------------------------------------------
__global__ __launch_bounds__(256) void k_fix(
    const float* __restrict__ xx, const float* __restrict__ w1,
    const float* __restrict__ b1, const float* __restrict__ w2,
    const float* __restrict__ b2, const int* __restrict__ cnt,
    const int* __restrict__ list, int* __restrict__ idx)
{
  __shared__ float w1f[64*65];     // [d][c] padded -> 2-way bank (free)
  __shared__ float w2f[64], b1f[64];
  int tid = threadIdx.x;
  for (int i = tid; i < 4096; i += 256) w1f[(i >> 6)*65 + (i & 63)] = w1[i];
  if (tid < 64) { w2f[tid] = w2[tid]; b1f[tid] = b1[tid]; }
  __syncthreads();
  int n = cnt[0];
  int wid = tid >> 6, lane = tid & 63;
  int nwaves = gridDim.x * 4;
  const int gs0[4] = {0,5,8,12};
  const int gl0[4] = {5,3,4,2};
  double b2d = (double)b2[0];
  for (int e = blockIdx.x*4 + wid; e < n; e += nwaves) {
    int i = list[e];
    int g = i >> 15, t = i & (HW-1);
    int start = gs0[g], len = gl0[g];
    double best = -1e300;
    int bi = start;
    for (int j = 0; j < len; ++j) {
      double xv = (double)xx[(size_t)(start+j)*64*HW + (size_t)lane*HW + t];
      double acc = (double)b1f[lane];
      #pragma unroll
      for (int c = 0; c < 64; ++c) {
        double xc = __shfl(xv, c);
        acc += xc * (double)w1f[lane*65 + c];
      }
      double sc = (acc > 0.0 ? acc : 0.0) * (double)w2f[lane];
      #pragma unroll
      for (int m = 1; m < 64; m <<= 1) sc += __shfl_xor(sc, m);
      sc += b2d;
      if (sc > best) { best = sc; bi = start + j; }   // first-max
    }
    if (lane == 0) idx[i] = bi;
  }
}

// ---------------------------------------------------------------------------
// K2: gather winner (from idx) + transpose to token-major seq (bf16).
// ---------------------------------------------------------------------------
__global__ __launch_bounds__(256) void k_fuse(
    const float* __restrict__ xx, const int* __restrict__ idx,
    ushort* __restrict__ seqb)
{
  __shared__ int idxs[64];
  __shared__ float tile[64*65];
  int tid = threadIdx.x;
  int g  = blockIdx.x >> 9;
  int t0 = (blockIdx.x & 511) << 6;
  if (tid < 64) idxs[tid] = idx[(size_t)g*HW + t0 + tid];
  __syncthreads();
  int tl = tid & 63, cq = tid >> 6;
  for (int r = 0; r < 16; ++r) {
    int c = r*4 + cq;
    tile[c*65 + tl] = xx[(size_t)idxs[tl]*64*HW + (size_t)c*HW + t0 + tl];
  }
  __syncthreads();
  for (int r = 0; r < 16; ++r) {
    int row = r*4 + cq;
    seqb[((size_t)g*HW + t0 + row)*64 + tl] = f2b(tile[tl*65 + row]);
  }
}

// ---------------------------------------------------------------------------
// K3: ctx = seq @ v_w^T + v_b (-> bf16); u = LayerNorm -> pre-swizzled bf16.
// ---------------------------------------------------------------------------
__global__ __launch_bounds__(256) void k_vln(
    const ushort* __restrict__ seqb, const float* __restrict__ vw,
    const float* __restrict__ vb, const float* __restrict__ lnw,
    const float* __restrict__ lnb, ushort* __restrict__ ctxb,
    ushort* __restrict__ usw)
{
  __shared__ float st[64*64];
  int tid = threadIdx.x;
  size_t p0 = (size_t)blockIdx.x * 64;
  for (int i = tid; i < 1024; i += 256) {
    u16x4 v = *(const u16x4*)(seqb + p0*64 + i*4);
    st[i*4+0] = b2f(v[0]); st[i*4+1] = b2f(v[1]);
    st[i*4+2] = b2f(v[2]); st[i*4+3] = b2f(v[3]);
  }
  int o = tid & 63, wv = tid >> 6;
  float w[64];
  const float4* w4 = (const float4*)(vw + o*64);
  #pragma unroll
  for (int c4 = 0; c4 < 16; ++c4) {
    float4 v = w4[c4];
    w[c4*4+0]=v.x; w[c4*4+1]=v.y; w[c4*4+2]=v.z; w[c4*4+3]=v.w;
  }
  float bias = vb[o], lw = lnw[o], lb = lnb[o];
  __syncthreads();
  const float4* st4 = (const float4*)st;
  for (int j = 0; j < 16; ++j) {
    int p = wv*16 + j;
    float acc = bias;
    #pragma unroll
    for (int c4 = 0; c4 < 16; ++c4) {
      float4 s4 = st4[p*16 + c4];
      acc += s4.x*w[c4*4] + s4.y*w[c4*4+1] + s4.z*w[c4*4+2] + s4.w*w[c4*4+3];
    }
    float s1 = acc, s2 = acc*acc;
    #pragma unroll
    for (int m = 1; m < 64; m <<= 1) {
      s1 += __shfl_xor(s1, m);
      s2 += __shfl_xor(s2, m);
    }
    float mu  = s1*(1.f/64.f);
    float var = s2*(1.f/64.f) - mu*mu;
    float rstd = rsqrtf(var + 1e-5f);
    size_t base = (p0+p)*64;
    int gt = (int)(p0 + p);
    ctxb[base + o] = f2b(acc);
    usw[base + (o ^ (((gt+3)&7)<<3))] = f2b((acc - mu)*rstd*lw + lb);
  }
}

// ---------------------------------------------------------------------------
// k_prep: ipw -> bf16 pre-swizzled wsw (rows >=386 zeroed; 400x64).
// ---------------------------------------------------------------------------
__global__ __launch_bounds__(256) void k_prep(
    const float* __restrict__ ipw, ushort* __restrict__ wsw)
{
  int i = blockIdx.x*256 + threadIdx.x;   // 100*256 = 25600 = 400*64
  int row = i >> 6, c = i & 63;
  float v = (row < 386) ? ipw[row*64 + c] : 0.f;
  wsw[row*64 + swz(row, c)] = f2b(v);
}

// ---------------------------------------------------------------------------
// k_gemm (persistent): 512 blocks, each owns 4 consecutive token tiles.
// ---------------------------------------------------------------------------
__global__ __launch_bounds__(512) void k_gemm(
    const ushort* __restrict__ usw, const ushort* __restrict__ wsw,
    const float* __restrict__ ipb, const float* __restrict__ dtbias,
    ushort* __restrict__ z, ushort* __restrict__ xbcB, float* __restrict__ dt)
{
  __shared__ ushort Wlds[400*64];   // 51200 B (pre-swizzled copy)
  __shared__ ushort Ulds[80*64];    // 10240 B
  __shared__ ushort trans[8704];    // 17408 B
  int tid = threadIdx.x;
  int b     = blockIdx.x >> 7;
  int chunk = blockIdx.x & 127;
  int w = tid >> 6, lane = tid & 63, lr = lane & 15, kb = lane >> 4;

  for (int i = tid; i < 3200; i += 512)
    *(u16x8*)(Wlds + i*8) = *(const u16x8*)(wsw + i*8);

  for (int it = 0; it < 4; ++it) {
    int s = chunk*4 + it;
    int t0 = s << 6;
    size_t pixbase = (size_t)b*HW + t0;
    size_t tilebase = ((size_t)(b*512 + s))*256*64;
    {
      const ushort* ubase = usw + ((size_t)b*HW + t0 - 3)*64;
      for (int i = tid; i < 536; i += 512) {     // 536*8 = 67*64
        u16x8 v;
        if (t0 == 0 && i < 24) v = (u16x8){0,0,0,0,0,0,0,0};
        else v = *(const u16x8*)(ubase + i*8);
        *(u16x8*)(Ulds + i*8) = v;
      }
    }
    __syncthreads();

    for (int rd = 0; rd < 3; ++rd) {
      int nt = rd*8 + w;
      f32x4 acc[5];
      #pragma unroll
      for (int mt = 0; mt < 5; ++mt) acc[mt] = (f32x4){0.f,0.f,0.f,0.f};
      #pragma unroll
      for (int kk = 0; kk < 64; kk += 32) {
        bf16x8 bfrag = ldfrag(Wlds, nt*16 + lr, kk + kb*8, 64);
        #pragma unroll
        for (int mt = 0; mt < 5; ++mt) {
          bf16x8 afrag = ldfrag(Ulds, mt*16 + lr, kk + kb*8, 64);
          acc[mt] = __builtin_amdgcn_mfma_f32_16x16x32_bf16(afrag, bfrag, acc[mt], 0, 0, 0);
        }
      }
      float bias = ipb[nt*16 + lr];
      if (rd == 0) {          // z channels: trans[t][132]
        #pragma unroll
        for (int mt = 0; mt < 5; ++mt)
          #pragma unroll
          for (int r = 0; r < 4; ++r) {
            int t = mt*16 + kb*4 + r - 3;
            if (t >= 0 && t < 64) trans[t*132 + w*16 + lr] = f2b(acc[mt][r] + bias);
          }
      } else {                // xbc channels: trans[ch][68]
        #pragma unroll
        for (int mt = 0; mt < 5; ++mt)
          #pragma unroll
          for (int r = 0; r < 4; ++r) {
            int t = mt*16 + kb*4 + r - 3;
            if (t >= 0 && t < 64) trans[(w*16 + lr)*68 + t] = f2b(acc[mt][r] + bias);
          }
      }
      __syncthreads();
      if (rd == 0) {
        for (int i = tid; i < 2048; i += 512) {
          int t = i >> 5, c4 = (i & 31)*4;
          *(u16x4*)(z + (pixbase + t)*128 + c4) = *(const u16x4*)(trans + t*132 + c4);
        }
      } else {
        int chbase = (rd - 1)*128;
        for (int i = tid; i < 2048; i += 512) {
          int ch = i >> 4, t4 = (i & 15)*4;
          *(u16x4*)(xbcB + tilebase + (size_t)(chbase + ch)*64 + t4)
              = *(const u16x4*)(trans + ch*68 + t4);
        }
      }
      __syncthreads();
    }

    if (w == 0) {    // dt rows 384/385
      f32x4 acc[5];
      #pragma unroll
      for (int mt = 0; mt < 5; ++mt) acc[mt] = (f32x4){0.f,0.f,0.f,0.f};
      #pragma unroll
      for (int kk = 0; kk < 64; kk += 32) {
        bf16x8 bfrag = ldfrag(Wlds, 384 + lr, kk + kb*8, 64);
        #pragma unroll
        for (int mt = 0; mt < 5; ++mt) {
          bf16x8 afrag = ldfrag(Ulds, mt*16 + lr, kk + kb*8, 64);
          acc[mt] = __builtin_amdgcn_mfma_f32_16x16x32_bf16(afrag, bfrag, acc[mt], 0, 0, 0);
        }
      }
      if (lr < 2) {
        float bias = ipb[384 + lr] + dtbias[lr];
        #pragma unroll
        for (int mt = 0; mt < 5; ++mt)
          #pragma unroll
          for (int r = 0; r < 4; ++r) {
            int t = mt*16 + kb*4 + r - 3;
            if (t >= 0 && t < 64) {
              float a = acc[mt][r] + bias;
              dt[(pixbase + t)*2 + lr] = (a > 20.f) ? a : log1pf(expf(a));
            }
          }
      }
    }
    __syncthreads();   // Ulds reuse hazard (dt tail reads it)
  }
}

// ---------------------------------------------------------------------------
// k_conv: depthwise conv(K=4)+silu from tile-blocked xbcB -> co2 tile-blocked.
// Pure streaming (no LDS, no barrier).
// ---------------------------------------------------------------------------
__global__ __launch_bounds__(256) void k_conv(
    const ushort* __restrict__ xbcB, const float* __restrict__ convw,
    const float* __restrict__ convb, ushort* __restrict__ co2)
{
  int tid = threadIdx.x;
  int b  = blockIdx.x >> 9;
  int s  = blockIdx.x & 511;
  int lane = tid & 63, wv = tid >> 6;
  int toct = lane & 7, chi = lane >> 3;
  size_t tilebase = ((size_t)(b*512 + s))*256*64;
  const ushort* tsrc = xbcB + tilebase;
  const ushort* psrc = xbcB + tilebase - 256*64;   // prev tile (valid if s>0)

  for (int it = 0; it < 8; ++it) {
    int ch = wv*64 + it*8 + chi;
    u16x8 v = *(const u16x8*)(tsrc + ch*64 + toct*8);
    float x0 = b2f(v[0]), x1 = b2f(v[1]), x2 = b2f(v[2]), x3 = b2f(v[3]);
    float x4 = b2f(v[4]), x5 = b2f(v[5]), x6 = b2f(v[6]), x7 = b2f(v[7]);
    float pm1 = __shfl(x7, lane - 1);
    float pm2 = __shfl(x6, lane - 1);
    float pm3 = __shfl(x5, lane - 1);
    if (toct == 0) {
      if (s > 0) {
        u16x4 hq = *(const u16x4*)(psrc + ch*64 + 60);
        pm3 = b2f(hq[1]); pm2 = b2f(hq[2]); pm1 = b2f(hq[3]);
      } else {
        pm1 = pm2 = pm3 = 0.f;
      }
    }
    float4 cw = ((const float4*)convw)[ch];
    float cb = convb[ch];
    float o0 = cb + cw.x*pm3 + cw.y*pm2 + cw.z*pm1 + cw.w*x0;
    float o1 = cb + cw.x*pm2 + cw.y*pm1 + cw.z*x0  + cw.w*x1;
    float o2 = cb + cw.x*pm1 + cw.y*x0  + cw.z*x1  + cw.w*x2;
    float o3 = cb + cw.x*x0  + cw.y*x1  + cw.z*x2  + cw.w*x3;
    float o4 = cb + cw.x*x1  + cw.y*x2  + cw.z*x3  + cw.w*x4;
    float o5 = cb + cw.x*x2  + cw.y*x3  + cw.z*x4  + cw.w*x5;
    float o6 = cb + cw.x*x3  + cw.y*x4  + cw.z*x5  + cw.w*x6;
    float o7 = cb + cw.x*x4  + cw.y*x5  + cw.z*x6  + cw.w*x7;
    u16x8 ov;
    ov[0] = f2b(o0 / (1.f + __expf(-o0)));
    ov[1] = f2b(o1 / (1.f + __expf(-o1)));
    ov[2] = f2b(o2 / (1.f + __expf(-o2)));
    ov[3] = f2b(o3 / (1.f + __expf(-o3)));
    ov[4] = f2b(o4 / (1.f + __expf(-o4)));
    ov[5] = f2b(o5 / (1.f + __expf(-o5)));
    ov[6] = f2b(o6 / (1.f + __expf(-o6)));
    ov[7] = f2b(o7 / (1.f + __expf(-o7)));
    *(u16x8*)(co2 + tilebase + (size_t)ch*64 + toct*8) = ov;
  }
}

// ---------------------------------------------------------------------------
// K5 (MFMA): states[p,n] = sum_l xd[l,p]*B[l,n]. Reads tile-blocked co2.
// ---------------------------------------------------------------------------
__global__ __launch_bounds__(256) void k_states(
    const float* __restrict__ dt, const ushort* __restrict__ co2,
    const float* __restrict__ A_log,
    float* __restrict__ states, float* __restrict__ A_last)
{
  extern __shared__ char smem[];
  float* ac  = (float*)smem;            // 256
  float* dec = ac + 256;                // 256
  ushort* xdT = (ushort*)(dec + 256);   // 64 x 256
  ushort* BT  = xdT + 16384;            // 64 x 256
  int tid = threadIdx.x;
  int ci = blockIdx.x, h = blockIdx.y, b = blockIdx.z;
  size_t tg = (size_t)b*HW + (size_t)ci*256;
  float Aneg = -expf(A_log[h]);
  float dv = dt[(tg + tid)*2 + h];
  ac[tid] = dv*Aneg;
  __syncthreads();
  for (int off = 1; off < 256; off <<= 1) {
    float v = (tid >= off) ? ac[tid - off] : 0.f;
    __syncthreads();
    ac[tid] += v;
    __syncthreads();
  }
  float alast = ac[255];
  dec[tid] = dv * __expf(alast - ac[tid]);
  __syncthreads();
  for (int i = tid; i < 64*32; i += 256) {
    int p = i >> 5, lc = (i & 31) * 8;
    int s = (ci << 2) + (lc >> 6);
    const ushort* cb2 = co2 + ((size_t)(b*512 + s))*256*64 + (lc & 63);
    u16x8 xv = *(const u16x8*)(cb2 + (size_t)(h*64 + p)*64);
    u16x8 o;
    #pragma unroll
    for (int e = 0; e < 8; ++e) o[e] = f2b(b2f(xv[e]) * dec[lc + e]);
    *(u16x8*)(xdT + p*256 + swz(p, lc)) = o;
    u16x8 bv = *(const u16x8*)(cb2 + (size_t)(128 + p)*64);
    *(u16x8*)(BT + p*256 + swz(p, lc)) = bv;
  }
  __syncthreads();
  int w = tid >> 6, lane = tid & 63, lr = lane & 15, kb = lane >> 4;
  f32x4 acc[4];
  #pragma unroll
  for (int m = 0; m < 4; ++m) acc[m] = (f32x4){0.f,0.f,0.f,0.f};
  for (int k0 = 0; k0 < 256; k0 += 32) {
    bf16x8 bfrag = ldfrag(BT, 16*w + lr, k0 + kb*8, 256);
    #pragma unroll
    for (int m = 0; m < 4; ++m) {
      bf16x8 afrag = ldfrag(xdT, 16*m + lr, k0 + kb*8, 256);
      acc[m] = __builtin_amdgcn_mfma_f32_16x16x32_bf16(afrag, bfrag, acc[m], 0, 0, 0);
    }
  }
  size_t sb = (((size_t)b*NC + ci)*NH + h)*4096;
  #pragma unroll
  for (int m = 0; m < 4; ++m)
    #pragma unroll
    for (int r = 0; r < 4; ++r)
      states[sb + (size_t)(16*m + kb*4 + r)*64 + 16*w + lr] = acc[m][r];
  if (tid == 0) A_last[((size_t)b*NH + h)*NC + ci] = alast;
}

// ---------------------------------------------------------------------------
// K6: inter-chunk scan with prefetch; 64 blocks (b,h,seg).
// ---------------------------------------------------------------------------
__global__ __launch_bounds__(256) void k_scan(
    const float* __restrict__ states, const float* __restrict__ A_last,
    float* __restrict__ states_in)
{
  __shared__ float ef[NC];
  int tid = threadIdx.x;
  int seg = blockIdx.x & 7, h = (blockIdx.x >> 3) & 1, b = blockIdx.x >> 4;
  if (tid < NC) ef[tid] = __expf(A_last[((size_t)b*NH + h)*NC + tid]);
  __syncthreads();
  size_t base0 = (((size_t)b*NC)*NH + h)*4096 + seg*512 + tid;
  const size_t cstride = (size_t)NH*4096;
  float s0 = 0.f, s1 = 0.f;
  float ld0 = states[base0], ld1 = states[base0 + 256];
  for (int zc = 0; zc < NC; ++zc) {
    size_t cur = base0 + (size_t)zc*cstride;
    float n0 = 0.f, n1 = 0.f;
    if (zc < NC-1) { n0 = states[cur + cstride]; n1 = states[cur + cstride + 256]; }
    states_in[cur] = s0; states_in[cur + 256] = s1;
    float e = ef[zc];
    s0 = ld0 + e*s0; s1 = ld1 + e*s1;
    ld0 = n0; ld1 = n1;
  }
}

// ---------------------------------------------------------------------------
// K7 (MFMA): per chunk-head SSD Y.  y -> bf16.  512 thr / 8 waves.
// Balanced strips {w, 15-w}. B/C tiles staged FROM co2 (transpose in staging,
// bank-staggered scalar writes). dt folded into W' (stride-72 no-XOR).
// ---------------------------------------------------------------------------
__global__ __launch_bounds__(512) void k_ydiag(
    const float* __restrict__ dt, const ushort* __restrict__ co2,
    const float* __restrict__ states_in, const float* __restrict__ A_log,
    const float* __restrict__ ssd_D, ushort* __restrict__ y)
{
  extern __shared__ char smem[];
  float* ac   = (float*)smem;           // 256
  float* dts  = ac + 256;               // 256
  float* segs = dts + 256;              // 8 (4 used)
  ushort* Cb  = (ushort*)(segs + 8);    // 256 x 64   [l][n] swizzled
  ushort* Bb  = Cb + 16384;             // 256 x 64   [s][n] swizzled
  ushort* xsT = Bb + 16384;             // 64 x 256   [p][s] swizzled (pure xh)
  ushort* Sb  = xsT + 16384;            // 64 x 64    [p][n] swizzled
  ushort* Wb  = Sb + 4096;              // 8 x (16 x 72) per-wave [l][s]
  int tid = threadIdx.x;
  int ci = blockIdx.x, h = blockIdx.y, b = blockIdx.z;
  size_t tg = (size_t)b*HW + (size_t)ci*256;
  int w = tid >> 6, lane = tid & 63, lr = lane & 15, kb = lane >> 4;
  float Aneg = -expf(A_log[h]);

  // cumsum of dt*A: per-wave shfl scan + segment combine
  float dv = 0.f, a = 0.f;
  if (tid < 256) {
    dv = dt[(tg + tid)*2 + h];
    a = dv*Aneg;
    #pragma unroll
    for (int d = 1; d < 64; d <<= 1) {
      float t = __shfl_up(a, d);
      if (lane >= d) a += t;
    }
    if (lane == 63) segs[w] = a;
  }
  __syncthreads();
  if (tid < 256) {
    float off = 0.f;
    #pragma unroll
    for (int j = 0; j < 4; ++j) if (j < w) off += segs[j];
    ac[tid] = a + off;
    dts[tid] = dv;
  }

  // staging (512 threads)
  const ushort* ctb = co2 + ((size_t)(b*512 + (ci << 2)))*16384;
  // B tile (ch 128..191) and C tile (ch 192..255): transpose from co2
  for (int i = tid; i < 2048; i += 512) {
    int n = i >> 5, sub = i & 31;
    int j = sub >> 3, toct = sub & 7;
    u16x8 bv = *(const u16x8*)(ctb + (size_t)j*16384 + (size_t)(128 + n)*64 + toct*8);
    u16x8 cv = *(const u16x8*)(ctb + (size_t)j*16384 + (size_t)(192 + n)*64 + toct*8);
    int lbase = j*64 + toct*8;
    #pragma unroll
    for (int ee = 0; ee < 8; ++ee) {
      int e = (ee + toct) & 7;   // bank-stagger
      Bb[(lbase + e)*64 + swz(lbase + e, n)] = bv[e];
      Cb[(lbase + e)*64 + swz(lbase + e, n)] = cv[e];
    }
  }
  // xh tile (pure copy)
  {
    const ushort* ct0 = ctb + (size_t)h*4096;
    for (int i = tid; i < 64*32; i += 512) {
      int p = i >> 5, sc = (i & 31) * 8;
      u16x8 xv = *(const u16x8*)(ct0 + (size_t)(sc >> 6)*16384 + (size_t)p*64 + (sc & 63));
      *(u16x8*)(xsT + p*256 + swz(p, sc)) = xv;
    }
  }
  size_t sbg = (((size_t)b*NC + ci)*NH + h)*4096;
  for (int i = tid; i < 1024; i += 512) {
    int p = i >> 4, n4 = (i & 15) * 4;
    float4 sv = *(const float4*)(states_in + sbg + p*64 + n4);
    u16x4 pk = { f2b(sv.x), f2b(sv.y), f2b(sv.z), f2b(sv.w) };
    *(u16x4*)(Sb + p*64 + swz(p, n4)) = pk;
  }
  __syncthreads();

  int strips[2] = { w, 15 - w };
  ushort* Ww = Wb + w*1152;   // 16 x 72

  // Y2 = C @ S_in^T (both strips), row-scaled by exp(ac[l])
  f32x4 yy[2][4];
  #pragma unroll
  for (int sp = 0; sp < 2; ++sp)
    #pragma unroll
    for (int n = 0; n < 4; ++n) yy[sp][n] = (f32x4){0.f,0.f,0.f,0.f};
  #pragma unroll
  for (int kk = 0; kk < 64; kk += 32) {
    bf16x8 af[2], bf[4];
    #pragma unroll
    for (int sp = 0; sp < 2; ++sp) af[sp] = ldfrag(Cb, strips[sp]*16 + lr, kk + kb*8, 64);
    #pragma unroll
    for (int n = 0; n < 4; ++n) bf[n] = ldfrag(Sb, 16*n + lr, kk + kb*8, 64);
    #pragma unroll
    for (int sp = 0; sp < 2; ++sp)
      #pragma unroll
      for (int n = 0; n < 4; ++n)
        yy[sp][n] = __builtin_amdgcn_mfma_f32_16x16x32_bf16(af[sp], bf[n], yy[sp][n], 0, 0, 0);
  }
  #pragma unroll
  for (int sp = 0; sp < 2; ++sp)
    #pragma unroll
    for (int r = 0; r < 4; ++r) {
      float e = __expf(ac[strips[sp]*16 + kb*4 + r]);
      #pragma unroll
      for (int n = 0; n < 4; ++n) yy[sp][n][r] *= e;
    }

  // per-strip s-tile loop (wave-local; no barriers; W' = tril-decay*G*dts[s])
  #pragma unroll
  for (int sp = 0; sp < 2; ++sp) {
    int strip = strips[sp];
    int l0 = strip*16;
    int nst = (strip >> 2) + 1;
    for (int st = 0; st < nst; ++st) {
      int s0 = st*64;
      f32x4 g[4];
      #pragma unroll
      for (int n = 0; n < 4; ++n) g[n] = (f32x4){0.f,0.f,0.f,0.f};
      #pragma unroll
      for (int kk = 0; kk < 64; kk += 32) {
        bf16x8 af = ldfrag(Cb, l0 + lr, kk + kb*8, 64);
        bf16x8 bf[4];
        #pragma unroll
        for (int n = 0; n < 4; ++n) bf[n] = ldfrag(Bb, s0 + 16*n + lr, kk + kb*8, 64);
        #pragma unroll
        for (int n = 0; n < 4; ++n)
          g[n] = __builtin_amdgcn_mfma_f32_16x16x32_bf16(af, bf[n], g[n], 0, 0, 0);
      }
      #pragma unroll
      for (int r = 0; r < 4; ++r) {
        int lrow = kb*4 + r;
        int lg = l0 + lrow;
        float acl = ac[lg];
        #pragma unroll
        for (int n = 0; n < 4; ++n) {
          int sl = 16*n + lr;
          int sg = s0 + sl;
          float v = (sg <= lg) ? g[n][r] * __expf(acl - ac[sg]) * dts[sg] : 0.f;
          Ww[lrow*72 + sl] = f2b(v);
        }
      }
      // same-wave LDS write->read: ordered by lgkmcnt, no barrier needed
      #pragma unroll
      for (int kk = 0; kk < 64; kk += 32) {
        bf16x8 af = *(const bf16x8*)(Ww + lr*72 + kk + kb*8);
        bf16x8 bf[4];
        #pragma unroll
        for (int n = 0; n < 4; ++n) bf[n] = ldfrag(xsT, 16*n + lr, s0 + kk + kb*8, 256);
        #pragma unroll
        for (int n = 0; n < 4; ++n)
          yy[sp][n] = __builtin_amdgcn_mfma_f32_16x16x32_bf16(af, bf[n], yy[sp][n], 0, 0, 0);
      }
    }
  }

  // + D*xh and store
  float Dh = ssd_D[h];
  #pragma unroll
  for (int sp = 0; sp < 2; ++sp)
    #pragma unroll
    for (int r = 0; r < 4; ++r) {
      int lg = strips[sp]*16 + kb*4 + r;
      #pragma unroll
      for (int n = 0; n < 4; ++n) {
        int p = 16*n + lr;
        float val = yy[sp][n][r] + Dh * b2f(xsT[p*256 + swz(p, lg)]);
        y[(tg + lg)*128 + h*64 + p] = f2b(val);
      }
    }
}

// ---------------------------------------------------------------------------
// K8 (MFMA): yz = y*silu(z); RMS over 128; out = ctx + yn @ (opw*rms_w)^T.
// ---------------------------------------------------------------------------
__global__ __launch_bounds__(256) void k_final(
    const ushort* __restrict__ y, const ushort* __restrict__ z,
    const ushort* __restrict__ ctxb, const float* __restrict__ rms_w,
    const float* __restrict__ opw, float* __restrict__ out)
{
  __shared__ ushort yn[64*128];    // swizzled [t][k]
  __shared__ ushort wop[64*128];   // swizzled [c][k]
  __shared__ float otile[64*65];
  int tid = threadIdx.x;
  size_t p0 = (size_t)blockIdx.x * 64;

  for (int i = tid; i < 2048; i += 256) {
    int row = i >> 5, c4 = (i & 31) * 4;
    float4 v = ((const float4*)(opw + row*128))[c4 >> 2];
    float4 rw = ((const float4*)rms_w)[c4 >> 2];
    u16x4 p = { f2b(v.x*rw.x), f2b(v.y*rw.y), f2b(v.z*rw.z), f2b(v.w*rw.w) };
    *(u16x4*)(wop + row*128 + swz(row, c4)) = p;
  }

  {
    int t = tid >> 2, q = tid & 3;
    const u16x4* yp = (const u16x4*)(y + (p0 + t)*128 + q*32);
    const u16x4* zp = (const u16x4*)(z + (p0 + t)*128 + q*32);
    float vals[32];
    float ss = 0.f;
    #pragma unroll
    for (int j = 0; j < 8; ++j) {
      u16x4 yv = yp[j];
      u16x4 zv = zp[j];
      #pragma unroll
      for (int e = 0; e < 4; ++e) {
        float zf = b2f(zv[e]);
        float x = b2f(yv[e]) * (zf / (1.f + __expf(-zf)));
        vals[j*4+e] = x; ss += x*x;
      }
    }
    ss += __shfl_xor(ss, 1);
    ss += __shfl_xor(ss, 2);
    float rinv = rsqrtf(ss*(1.f/128.f) + 1e-5f);
    #pragma unroll
    for (int j = 0; j < 8; ++j) {
      int c4 = q*32 + j*4;
      u16x4 p = { f2b(vals[j*4]*rinv), f2b(vals[j*4+1]*rinv),
                  f2b(vals[j*4+2]*rinv), f2b(vals[j*4+3]*rinv) };
      *(u16x4*)(yn + t*128 + swz(t, c4)) = p;
    }
  }
  __syncthreads();

  int w = tid >> 6, lane = tid & 63, lr = lane & 15, kb = lane >> 4;
  f32x4 acc[4];
  #pragma unroll
  for (int n = 0; n < 4; ++n) acc[n] = (f32x4){0.f,0.f,0.f,0.f};
  #pragma unroll
  for (int kk = 0; kk < 128; kk += 32) {
    bf16x8 a = ldfrag(yn, w*16 + lr, kk + kb*8, 128);
    #pragma unroll
    for (int n = 0; n < 4; ++n) {
      bf16x8 bf = ldfrag(wop, n*16 + lr, kk + kb*8, 128);
      acc[n] = __builtin_amdgcn_mfma_f32_16x16x32_bf16(a, bf, acc[n], 0, 0, 0);
    }
  }
  #pragma unroll
  for (int n = 0; n < 4; ++n)
    #pragma unroll
    for (int r = 0; r < 4; ++r) {
      int tok = w*16 + kb*4 + r, ch = n*16 + lr;
      otile[ch*65 + tok] = acc[n][r] + b2f(ctxb[(p0 + tok)*64 + ch]);
    }
  __syncthreads();
  {
    size_t b  = p0 >> 15;
    size_t t0 = p0 & (HW-1);
    for (int r = 0; r < 16; ++r) {
      int cc = r*4 + (tid >> 6);
      int pp = tid & 63;
      out[(b*64 + cc)*HW + t0 + pp] = otile[cc*65 + pp];
    }
  }
}

// ---------------------------------------------------------------------------
extern "C" void kernel_launch(void* const* d_in, const int* in_sizes, int n_in,
                              void* d_out, int out_size, void* d_ws, size_t ws_size,
                              hipStream_t stream) {
  (void)in_sizes; (void)n_in; (void)out_size; (void)ws_size;
  const float* xx   = (const float*)d_in[0];
  const float* sw1  = (const float*)d_in[2];
  const float* sb1  = (const float*)d_in[3];
  const float* sw2  = (const float*)d_in[4];
  const float* sb2  = (const float*)d_in[5];
  const float* vw   = (const float*)d_in[10];
  const float* vb   = (const float*)d_in[11];
  const float* lnw  = (const float*)d_in[12];
  const float* lnb  = (const float*)d_in[13];
  const float* ipw  = (const float*)d_in[14];
  const float* ipb  = (const float*)d_in[15];
  const float* cw   = (const float*)d_in[16];
  const float* cb   = (const float*)d_in[17];
  const float* dtb  = (const float*)d_in[18];
  const float* alog = (const float*)d_in[19];
  const float* sd   = (const float*)d_in[20];
  const float* rmsw = (const float*)d_in[21];
  const float* opw  = (const float*)d_in[22];

  float* ws = (float*)d_ws;
  float*  scores32 = ws;                       // [0, 458752)
  int*    idxb     = (int*)(ws + 458752);      // [458752, 589824)
  int*    cntb     = (int*)(ws + 589824);      // 1
  int*    listb    = (int*)(ws + 589832);      // [589832, 720904)
  float*  dtp      = ws;                       // alias after k_fix (262144 floats)
  ushort* seqb     = (ushort*)(ws + 917504);   // bf16 [917504, ...)
  ushort* ctxb     = (ushort*)(ws + 9306112);  // bf16 ctx
  ushort* uswb     = (ushort*)(ws + 17694720); // dead after k_gemm
  float*  states   = ws + 17694720;            // alias after k_gemm
  float*  states_in= ws + 21889024;
  ushort* zb       = (ushort*)(ws + 26083328); // [26083328, 34471936)
  ushort* xbcBb    = (ushort*)(ws + 34471936); // tile-blocked
  ushort* co2b     = (ushort*)(ws + 51249152); // tile-blocked
  ushort* yb       = (ushort*)(ws + 68026368);
  float*  Alast    = ws + 84803584;
  ushort* wswb     = (ushort*)(ws + 84804608); // 25600 ushorts

  k_score_mfma<<<1792, 256, 0, stream>>>(xx, sw1, sb1, sw2, sb2, scores32, cntb);
  k_argmax<<<512, 256, 0, stream>>>(scores32, idxb, cntb, listb);
  k_fix<<<512, 256, 0, stream>>>(xx, sw1, sb1, sw2, sb2, cntb, listb, idxb);
  k_fuse<<<2048, 256, 0, stream>>>(xx, idxb, seqb);
  k_vln<<<2048, 256, 0, stream>>>(seqb, vw, vb, lnw, lnb, ctxb, uswb);
  k_prep<<<100, 256, 0, stream>>>(ipw, wswb);
  k_gemm<<<512, 512, 0, stream>>>(uswb, wswb, ipb, dtb, zb, xbcBb, dtp);
  k_conv<<<2048, 256, 0, stream>>>(xbcBb, cw, cb, co2b);
  dim3 gssd(NC, NH, B4);
  k_states<<<gssd, 256, 67584, stream>>>(dtp, co2b, alog, states, Alast);
  k_scan<<<64, 256, 0, stream>>>(states, Alast, states_in);
  k_ydiag<<<gssd, 512, 127008, stream>>>(dtp, co2b, states_in, alog, sd, yb);
  k_final<<<2048, 256, 0, stream>>>(yb, zb, ctxb, rmsw, opw, (float*)d_out);
}

// Round 17
// 381.091 us; speedup vs baseline: 1.1855x; 1.0183x over previous
//
#include <hip/hip_runtime.h>
#include <cmath>

#define HW 32768      // H*W
#define NC 128        // chunks per batch (HW/256)
#define NH 2          // heads
#define B4 4          // batch (num groups)

typedef __attribute__((ext_vector_type(8))) short bf16x8;
typedef __attribute__((ext_vector_type(4))) float f32x4;
typedef __attribute__((ext_vector_type(4))) ushort u16x4;
typedef __attribute__((ext_vector_type(8))) ushort u16x8;

__device__ __forceinline__ ushort f2b(float x) {
  union { float f; unsigned u; } v; v.f = x;
  unsigned r = v.u + 0x7FFFu + ((v.u >> 16) & 1u);   // RNE
  return (ushort)(r >> 16);
}
__device__ __forceinline__ float b2f(ushort b) {
  union { unsigned u; float f; } v; v.u = ((unsigned)b) << 16;
  return v.f;
}
// XOR-swizzle of element index k within a row (bf16 tiles, 16B-group spread)
__device__ __forceinline__ int swz(int row, int k) { return k ^ ((row & 7) << 3); }
// A-frag: row-major [M][K] (K contig); B-frag: [N][K] (i.e. B^T row-major).
__device__ __forceinline__ bf16x8 ldfrag(const ushort* base, int row, int k, int stride) {
  return *(const bf16x8*)(base + row * stride + swz(row, k));
}

// ---------------------------------------------------------------------------
// K1a (MFMA): score MLP via split-precision weights.
// ---------------------------------------------------------------------------
__global__ __launch_bounds__(256) void k_score_mfma(
    const float* __restrict__ xx, const float* __restrict__ w1,
    const float* __restrict__ b1, const float* __restrict__ w2,
    const float* __restrict__ b2, float* __restrict__ scores,
    int* __restrict__ cnt)
{
  __shared__ ushort Whi[64*64];     // [d][c] swizzled
  __shared__ ushort Wlo[64*64];
  __shared__ ushort Xt[4][64*64];   // per-wave [t][c] swizzled
  __shared__ float w2b1[128];       // w2[0..63] | b1[64..127]
  int tid = threadIdx.x;
  if (blockIdx.x == 0 && tid == 0) cnt[0] = 0;
  for (int i = tid; i < 4096; i += 256) {
    int d = i >> 6, c = i & 63;
    float v = w1[i];
    ushort hi = f2b(v);
    int off = d*64 + swz(d, c);
    Whi[off] = hi;
    Wlo[off] = f2b(v - b2f(hi));
  }
  if (tid < 64) { w2b1[tid] = w2[tid]; w2b1[64+tid] = b1[tid]; }

  int wid = tid >> 6, lane = tid & 63;
  int n  = blockIdx.x >> 7;             // 1792 blocks = 14 n x 128 tiles
  int t0 = (blockIdx.x & 127)*256 + wid*64;

  {
    const float* px = xx + (size_t)n*64*HW + t0 + lane;
    float xv[64];
    #pragma unroll
    for (int c = 0; c < 64; ++c) xv[c] = px[(size_t)c*HW];
    ushort* xh = Xt[wid];
    #pragma unroll
    for (int c8 = 0; c8 < 8; ++c8) {
      u16x8 p;
      #pragma unroll
      for (int j = 0; j < 8; ++j) p[j] = f2b(xv[c8*8 + j]);
      *(u16x8*)(xh + lane*64 + swz(lane, c8*8)) = p;
    }
  }
  __syncthreads();

  int lr = lane & 15, kb = lane >> 4;
  const ushort* xh = Xt[wid];
  f32x4 acc[4][4];
  #pragma unroll
  for (int m = 0; m < 4; ++m)
    #pragma unroll
    for (int nt = 0; nt < 4; ++nt) acc[m][nt] = (f32x4){0.f,0.f,0.f,0.f};
  #pragma unroll
  for (int k0 = 0; k0 < 64; k0 += 32) {
    bf16x8 ah[4], al[4], bx[4];
    #pragma unroll
    for (int m = 0; m < 4; ++m) {
      ah[m] = ldfrag(Whi, 16*m + lr, k0 + kb*8, 64);
      al[m] = ldfrag(Wlo, 16*m + lr, k0 + kb*8, 64);
    }
    #pragma unroll
    for (int nt = 0; nt < 4; ++nt) bx[nt] = ldfrag(xh, 16*nt + lr, k0 + kb*8, 64);
    #pragma unroll
    for (int m = 0; m < 4; ++m)
      #pragma unroll
      for (int nt = 0; nt < 4; ++nt) {
        acc[m][nt] = __builtin_amdgcn_mfma_f32_16x16x32_bf16(ah[m], bx[nt], acc[m][nt], 0, 0, 0);
        acc[m][nt] = __builtin_amdgcn_mfma_f32_16x16x32_bf16(al[m], bx[nt], acc[m][nt], 0, 0, 0);
      }
  }
  float bb2 = b2[0];
  #pragma unroll
  for (int nt = 0; nt < 4; ++nt) {
    float s = 0.f;
    #pragma unroll
    for (int m = 0; m < 4; ++m)
      #pragma unroll
      for (int r = 0; r < 4; ++r) {
        int d = 16*m + kb*4 + r;
        float h = acc[m][nt][r] + w2b1[64 + d];
        s += fmaxf(h, 0.f) * w2b1[d];
      }
    s += __shfl_xor(s, 16);
    s += __shfl_xor(s, 32);
    if (kb == 0) scores[(size_t)n*HW + t0 + 16*nt + lr] = s + bb2;
  }
}

// ---------------------------------------------------------------------------
// K1b: per-(group,pixel) first-max argmax over fp32 scores; flag near-ties.
// ---------------------------------------------------------------------------
__global__ __launch_bounds__(256) void k_argmax(
    const float* __restrict__ scores, int* __restrict__ idx,
    int* __restrict__ cnt, int* __restrict__ list)
{
  int i = blockIdx.x*256 + threadIdx.x;      // 512 blocks: 4*HW
  int g = i >> 15, t = i & (HW-1);
  const int gs0[4] = {0,5,8,12};
  const int gl0[4] = {5,3,4,2};
  int start = gs0[g], len = gl0[g];
  float best = scores[(size_t)start*HW + t];
  float second = -3.4e38f;
  int bi = start;
  for (int j = 1; j < len; ++j) {
    float s = scores[(size_t)(start+j)*HW + t];
    if (s > best) { second = best; best = s; bi = start + j; }
    else if (s > second) second = s;
  }
  idx[i] = bi;
  if (best - second < 5e-4f) {
    int p = atomicAdd(cnt, 1);
    list[p] = i;
  }
}

// ---------------------------------------------------------------------------
// K1c: fp64 recompute of flagged pixels, ONE WAVE PER ENTRY.
// ---------------------------------------------------------------------------
__global__ __launch_bounds__(256) void k_fix(
    const float* __restrict__ xx, const float* __restrict__ w1,
    const float* __restrict__ b1, const float* __restrict__ w2,
    const float* __restrict__ b2, const int* __restrict__ cnt,
    const int* __restrict__ list, int* __restrict__ idx)
{
  __shared__ float w1f[64*65];     // [d][c] padded -> 2-way bank (free)
  __shared__ float w2f[64], b1f[64];
  int tid = threadIdx.x;
  for (int i = tid; i < 4096; i += 256) w1f[(i >> 6)*65 + (i & 63)] = w1[i];
  if (tid < 64) { w2f[tid] = w2[tid]; b1f[tid] = b1[tid]; }
  __syncthreads();
  int n = cnt[0];
  int wid = tid >> 6, lane = tid & 63;
  int nwaves = gridDim.x * 4;
  const int gs0[4] = {0,5,8,12};
  const int gl0[4] = {5,3,4,2};
  double b2d = (double)b2[0];
  for (int e = blockIdx.x*4 + wid; e < n; e += nwaves) {
    int i = list[e];
    int g = i >> 15, t = i & (HW-1);
    int start = gs0[g], len = gl0[g];
    double best = -1e300;
    int bi = start;
    for (int j = 0; j < len; ++j) {
      double xv = (double)xx[(size_t)(start+j)*64*HW + (size_t)lane*HW + t];
      double acc = (double)b1f[lane];
      #pragma unroll
      for (int c = 0; c < 64; ++c) {
        double xc = __shfl(xv, c);
        acc += xc * (double)w1f[lane*65 + c];
      }
      double sc = (acc > 0.0 ? acc : 0.0) * (double)w2f[lane];
      #pragma unroll
      for (int m = 1; m < 64; m <<= 1) sc += __shfl_xor(sc, m);
      sc += b2d;
      if (sc > best) { best = sc; bi = start + j; }   // first-max
    }
    if (lane == 0) idx[i] = bi;
  }
}

// ---------------------------------------------------------------------------
// K2+K3 fused: gather winner -> LDS -> v-proj + LayerNorm. seq never in HBM.
// ---------------------------------------------------------------------------
__global__ __launch_bounds__(256) void k_fusevln(
    const float* __restrict__ xx, const int* __restrict__ idx,
    const float* __restrict__ vw, const float* __restrict__ vb,
    const float* __restrict__ lnw, const float* __restrict__ lnb,
    ushort* __restrict__ ctxb, ushort* __restrict__ usw)
{
  __shared__ int idxs[64];
  __shared__ float tile[64*65];   // [c][t]
  __shared__ float st[64*68];     // [t][c], stride 68 (float4-aligned rows)
  int tid = threadIdx.x;
  int g  = blockIdx.x >> 9;
  int t0 = (blockIdx.x & 511) << 6;
  if (tid < 64) idxs[tid] = idx[(size_t)g*HW + t0 + tid];
  __syncthreads();
  int tl = tid & 63, cq = tid >> 6;
  for (int r = 0; r < 16; ++r) {
    int c = r*4 + cq;
    tile[c*65 + tl] = xx[(size_t)idxs[tl]*64*HW + (size_t)c*HW + t0 + tl];
  }
  __syncthreads();
  for (int r = 0; r < 16; ++r) {
    int row = r*4 + cq;
    st[row*68 + tl] = tile[tl*65 + row];   // bank (4*row+tl)%32: 2-way, free
  }
  int o = tl, wv = cq;
  float w[64];
  const float4* w4 = (const float4*)(vw + o*64);
  #pragma unroll
  for (int c4 = 0; c4 < 16; ++c4) {
    float4 v = w4[c4];
    w[c4*4+0]=v.x; w[c4*4+1]=v.y; w[c4*4+2]=v.z; w[c4*4+3]=v.w;
  }
  float bias = vb[o], lw = lnw[o], lb = lnb[o];
  __syncthreads();
  size_t p0 = (size_t)g*HW + t0;
  for (int j = 0; j < 16; ++j) {
    int p = wv*16 + j;
    const float4* row4 = (const float4*)(st + p*68);
    float acc = bias;
    #pragma unroll
    for (int c4 = 0; c4 < 16; ++c4) {
      float4 s4 = row4[c4];
      acc += s4.x*w[c4*4] + s4.y*w[c4*4+1] + s4.z*w[c4*4+2] + s4.w*w[c4*4+3];
    }
    float s1 = acc, s2 = acc*acc;
    #pragma unroll
    for (int m = 1; m < 64; m <<= 1) {
      s1 += __shfl_xor(s1, m);
      s2 += __shfl_xor(s2, m);
    }
    float mu  = s1*(1.f/64.f);
    float var = s2*(1.f/64.f) - mu*mu;
    float rstd = rsqrtf(var + 1e-5f);
    size_t base = (p0 + p)*64;
    int gt = t0 + p;
    ctxb[base + o] = f2b(acc);
    usw[base + (o ^ (((gt+3)&7)<<3))] = f2b((acc - mu)*rstd*lw + lb);
  }
}

// ---------------------------------------------------------------------------
// k_prep: ipw -> bf16 pre-swizzled wsw (rows >=386 zeroed; 400x64).
// ---------------------------------------------------------------------------
__global__ __launch_bounds__(256) void k_prep(
    const float* __restrict__ ipw, ushort* __restrict__ wsw)
{
  int i = blockIdx.x*256 + threadIdx.x;   // 100*256 = 25600 = 400*64
  int row = i >> 6, c = i & 63;
  float v = (row < 386) ? ipw[row*64 + c] : 0.f;
  wsw[row*64 + swz(row, c)] = f2b(v);
}

// ---------------------------------------------------------------------------
// k_gemm (persistent): 512 blocks, each owns 4 consecutive token tiles.
// ---------------------------------------------------------------------------
__global__ __launch_bounds__(512) void k_gemm(
    const ushort* __restrict__ usw, const ushort* __restrict__ wsw,
    const float* __restrict__ ipb, const float* __restrict__ dtbias,
    ushort* __restrict__ z, ushort* __restrict__ xbcB, float* __restrict__ dt)
{
  __shared__ ushort Wlds[400*64];   // 51200 B (pre-swizzled copy)
  __shared__ ushort Ulds[80*64];    // 10240 B
  __shared__ ushort trans[8704];    // 17408 B
  int tid = threadIdx.x;
  int b     = blockIdx.x >> 7;
  int chunk = blockIdx.x & 127;
  int w = tid >> 6, lane = tid & 63, lr = lane & 15, kb = lane >> 4;

  for (int i = tid; i < 3200; i += 512)
    *(u16x8*)(Wlds + i*8) = *(const u16x8*)(wsw + i*8);

  for (int it = 0; it < 4; ++it) {
    int s = chunk*4 + it;
    int t0 = s << 6;
    size_t pixbase = (size_t)b*HW + t0;
    size_t tilebase = ((size_t)(b*512 + s))*256*64;
    {
      const ushort* ubase = usw + ((size_t)b*HW + t0 - 3)*64;
      for (int i = tid; i < 536; i += 512) {     // 536*8 = 67*64
        u16x8 v;
        if (t0 == 0 && i < 24) v = (u16x8){0,0,0,0,0,0,0,0};
        else v = *(const u16x8*)(ubase + i*8);
        *(u16x8*)(Ulds + i*8) = v;
      }
    }
    __syncthreads();

    for (int rd = 0; rd < 3; ++rd) {
      int nt = rd*8 + w;
      f32x4 acc[5];
      #pragma unroll
      for (int mt = 0; mt < 5; ++mt) acc[mt] = (f32x4){0.f,0.f,0.f,0.f};
      #pragma unroll
      for (int kk = 0; kk < 64; kk += 32) {
        bf16x8 bfrag = ldfrag(Wlds, nt*16 + lr, kk + kb*8, 64);
        #pragma unroll
        for (int mt = 0; mt < 5; ++mt) {
          bf16x8 afrag = ldfrag(Ulds, mt*16 + lr, kk + kb*8, 64);
          acc[mt] = __builtin_amdgcn_mfma_f32_16x16x32_bf16(afrag, bfrag, acc[mt], 0, 0, 0);
        }
      }
      float bias = ipb[nt*16 + lr];
      if (rd == 0) {          // z channels: trans[t][132]
        #pragma unroll
        for (int mt = 0; mt < 5; ++mt)
          #pragma unroll
          for (int r = 0; r < 4; ++r) {
            int t = mt*16 + kb*4 + r - 3;
            if (t >= 0 && t < 64) trans[t*132 + w*16 + lr] = f2b(acc[mt][r] + bias);
          }
      } else {                // xbc channels: trans[ch][68]
        #pragma unroll
        for (int mt = 0; mt < 5; ++mt)
          #pragma unroll
          for (int r = 0; r < 4; ++r) {
            int t = mt*16 + kb*4 + r - 3;
            if (t >= 0 && t < 64) trans[(w*16 + lr)*68 + t] = f2b(acc[mt][r] + bias);
          }
      }
      __syncthreads();
      if (rd == 0) {
        for (int i = tid; i < 2048; i += 512) {
          int t = i >> 5, c4 = (i & 31)*4;
          *(u16x4*)(z + (pixbase + t)*128 + c4) = *(const u16x4*)(trans + t*132 + c4);
        }
      } else {
        int chbase = (rd - 1)*128;
        for (int i = tid; i < 2048; i += 512) {
          int ch = i >> 4, t4 = (i & 15)*4;
          *(u16x4*)(xbcB + tilebase + (size_t)(chbase + ch)*64 + t4)
              = *(const u16x4*)(trans + ch*68 + t4);
        }
      }
      __syncthreads();
    }

    if (w == 0) {    // dt rows 384/385
      f32x4 acc[5];
      #pragma unroll
      for (int mt = 0; mt < 5; ++mt) acc[mt] = (f32x4){0.f,0.f,0.f,0.f};
      #pragma unroll
      for (int kk = 0; kk < 64; kk += 32) {
        bf16x8 bfrag = ldfrag(Wlds, 384 + lr, kk + kb*8, 64);
        #pragma unroll
        for (int mt = 0; mt < 5; ++mt) {
          bf16x8 afrag = ldfrag(Ulds, mt*16 + lr, kk + kb*8, 64);
          acc[mt] = __builtin_amdgcn_mfma_f32_16x16x32_bf16(afrag, bfrag, acc[mt], 0, 0, 0);
        }
      }
      if (lr < 2) {
        float bias = ipb[384 + lr] + dtbias[lr];
        #pragma unroll
        for (int mt = 0; mt < 5; ++mt)
          #pragma unroll
          for (int r = 0; r < 4; ++r) {
            int t = mt*16 + kb*4 + r - 3;
            if (t >= 0 && t < 64) {
              float a = acc[mt][r] + bias;
              dt[(pixbase + t)*2 + lr] = (a > 20.f) ? a : log1pf(expf(a));
            }
          }
      }
    }
    __syncthreads();   // Ulds reuse hazard (dt tail reads it)
  }
}

// ---------------------------------------------------------------------------
// k_conv: depthwise conv(K=4)+silu from tile-blocked xbcB -> co2 tile-blocked
// + Bm/Cm token-major via bank-swizzled LDS transpose.
// ---------------------------------------------------------------------------
__global__ __launch_bounds__(256) void k_conv(
    const ushort* __restrict__ xbcB, const float* __restrict__ convw,
    const float* __restrict__ convb, ushort* __restrict__ co2,
    ushort* __restrict__ Bm, ushort* __restrict__ Cm)
{
  __shared__ ushort bmc[64*132];    // [t][128] swizzled: col = c ^ ((t>>3)<<2)
  int tid = threadIdx.x;
  int b  = blockIdx.x >> 9;
  int s  = blockIdx.x & 511;
  int lane = tid & 63, wv = tid >> 6;
  int toct = lane & 7, chi = lane >> 3;
  size_t tilebase = ((size_t)(b*512 + s))*256*64;
  const ushort* tsrc = xbcB + tilebase;
  const ushort* psrc = xbcB + tilebase - 256*64;   // prev tile (valid if s>0)

  for (int it = 0; it < 8; ++it) {
    int ch = wv*64 + it*8 + chi;
    u16x8 v = *(const u16x8*)(tsrc + ch*64 + toct*8);
    float x0 = b2f(v[0]), x1 = b2f(v[1]), x2 = b2f(v[2]), x3 = b2f(v[3]);
    float x4 = b2f(v[4]), x5 = b2f(v[5]), x6 = b2f(v[6]), x7 = b2f(v[7]);
    float pm1 = __shfl(x7, lane - 1);
    float pm2 = __shfl(x6, lane - 1);
    float pm3 = __shfl(x5, lane - 1);
    if (toct == 0) {
      if (s > 0) {
        u16x4 hq = *(const u16x4*)(psrc + ch*64 + 60);
        pm3 = b2f(hq[1]); pm2 = b2f(hq[2]); pm1 = b2f(hq[3]);
      } else {
        pm1 = pm2 = pm3 = 0.f;
      }
    }
    float4 cw = ((const float4*)convw)[ch];
    float cb = convb[ch];
    float o0 = cb + cw.x*pm3 + cw.y*pm2 + cw.z*pm1 + cw.w*x0;
    float o1 = cb + cw.x*pm2 + cw.y*pm1 + cw.z*x0  + cw.w*x1;
    float o2 = cb + cw.x*pm1 + cw.y*x0  + cw.z*x1  + cw.w*x2;
    float o3 = cb + cw.x*x0  + cw.y*x1  + cw.z*x2  + cw.w*x3;
    float o4 = cb + cw.x*x1  + cw.y*x2  + cw.z*x3  + cw.w*x4;
    float o5 = cb + cw.x*x2  + cw.y*x3  + cw.z*x4  + cw.w*x5;
    float o6 = cb + cw.x*x3  + cw.y*x4  + cw.z*x5  + cw.w*x6;
    float o7 = cb + cw.x*x4  + cw.y*x5  + cw.z*x6  + cw.w*x7;
    u16x8 ov;
    ov[0] = f2b(o0 / (1.f + __expf(-o0)));
    ov[1] = f2b(o1 / (1.f + __expf(-o1)));
    ov[2] = f2b(o2 / (1.f + __expf(-o2)));
    ov[3] = f2b(o3 / (1.f + __expf(-o3)));
    ov[4] = f2b(o4 / (1.f + __expf(-o4)));
    ov[5] = f2b(o5 / (1.f + __expf(-o5)));
    ov[6] = f2b(o6 / (1.f + __expf(-o6)));
    ov[7] = f2b(o7 / (1.f + __expf(-o7)));
    *(u16x8*)(co2 + tilebase + (size_t)ch*64 + toct*8) = ov;
    if (ch >= 128) {
      int c = ch - 128;
      int csw = c ^ (toct << 2);
      #pragma unroll
      for (int j = 0; j < 8; ++j)
        bmc[(toct*8 + j)*132 + csw] = ov[j];
    }
  }
  __syncthreads();
  size_t tg = (size_t)b*HW + s*64;
  for (int i = tid; i < 1024; i += 256) {
    int tt = i >> 4, n4 = (i & 15)*4;
    int sw = (tt >> 3) << 2;
    *(u16x4*)(Bm + (tg + tt)*64 + n4) = *(const u16x4*)(bmc + tt*132 + (n4 ^ sw));
    *(u16x4*)(Cm + (tg + tt)*64 + n4) = *(const u16x4*)(bmc + tt*132 + ((64 + n4) ^ sw));
  }
}

// ---------------------------------------------------------------------------
// K5 (MFMA): states[p,n] = sum_l xd[l,p]*B[l,n]. Reads tile-blocked co2.
// ---------------------------------------------------------------------------
__global__ __launch_bounds__(256) void k_states(
    const float* __restrict__ dt, const ushort* __restrict__ co2,
    const float* __restrict__ A_log,
    float* __restrict__ states, float* __restrict__ A_last)
{
  extern __shared__ char smem[];
  float* ac  = (float*)smem;            // 256
  float* dec = ac + 256;                // 256
  ushort* xdT = (ushort*)(dec + 256);   // 64 x 256
  ushort* BT  = xdT + 16384;            // 64 x 256
  int tid = threadIdx.x;
  int ci = blockIdx.x, h = blockIdx.y, b = blockIdx.z;
  size_t tg = (size_t)b*HW + (size_t)ci*256;
  float Aneg = -expf(A_log[h]);
  float dv = dt[(tg + tid)*2 + h];
  ac[tid] = dv*Aneg;
  __syncthreads();
  for (int off = 1; off < 256; off <<= 1) {
    float v = (tid >= off) ? ac[tid - off] : 0.f;
    __syncthreads();
    ac[tid] += v;
    __syncthreads();
  }
  float alast = ac[255];
  dec[tid] = dv * __expf(alast - ac[tid]);
  __syncthreads();
  for (int i = tid; i < 64*32; i += 256) {
    int p = i >> 5, lc = (i & 31) * 8;
    int s = (ci << 2) + (lc >> 6);
    const ushort* cb2 = co2 + ((size_t)(b*512 + s))*256*64 + (lc & 63);
    u16x8 xv = *(const u16x8*)(cb2 + (size_t)(h*64 + p)*64);
    u16x8 o;
    #pragma unroll
    for (int e = 0; e < 8; ++e) o[e] = f2b(b2f(xv[e]) * dec[lc + e]);
    *(u16x8*)(xdT + p*256 + swz(p, lc)) = o;
    u16x8 bv = *(const u16x8*)(cb2 + (size_t)(128 + p)*64);
    *(u16x8*)(BT + p*256 + swz(p, lc)) = bv;
  }
  __syncthreads();
  int w = tid >> 6, lane = tid & 63, lr = lane & 15, kb = lane >> 4;
  f32x4 acc[4];
  #pragma unroll
  for (int m = 0; m < 4; ++m) acc[m] = (f32x4){0.f,0.f,0.f,0.f};
  for (int k0 = 0; k0 < 256; k0 += 32) {
    bf16x8 bfrag = ldfrag(BT, 16*w + lr, k0 + kb*8, 256);
    #pragma unroll
    for (int m = 0; m < 4; ++m) {
      bf16x8 afrag = ldfrag(xdT, 16*m + lr, k0 + kb*8, 256);
      acc[m] = __builtin_amdgcn_mfma_f32_16x16x32_bf16(afrag, bfrag, acc[m], 0, 0, 0);
    }
  }
  size_t sb = (((size_t)b*NC + ci)*NH + h)*4096;
  #pragma unroll
  for (int m = 0; m < 4; ++m)
    #pragma unroll
    for (int r = 0; r < 4; ++r)
      states[sb + (size_t)(16*m + kb*4 + r)*64 + 16*w + lr] = acc[m][r];
  if (tid == 0) A_last[((size_t)b*NH + h)*NC + ci] = alast;
}

// ---------------------------------------------------------------------------
// K6: inter-chunk scan with prefetch; 64 blocks (b,h,seg).
// ---------------------------------------------------------------------------
__global__ __launch_bounds__(256) void k_scan(
    const float* __restrict__ states, const float* __restrict__ A_last,
    float* __restrict__ states_in)
{
  __shared__ float ef[NC];
  int tid = threadIdx.x;
  int seg = blockIdx.x & 7, h = (blockIdx.x >> 3) & 1, b = blockIdx.x >> 4;
  if (tid < NC) ef[tid] = __expf(A_last[((size_t)b*NH + h)*NC + tid]);
  __syncthreads();
  size_t base0 = (((size_t)b*NC)*NH + h)*4096 + seg*512 + tid;
  const size_t cstride = (size_t)NH*4096;
  float s0 = 0.f, s1 = 0.f;
  float ld0 = states[base0], ld1 = states[base0 + 256];
  for (int zc = 0; zc < NC; ++zc) {
    size_t cur = base0 + (size_t)zc*cstride;
    float n0 = 0.f, n1 = 0.f;
    if (zc < NC-1) { n0 = states[cur + cstride]; n1 = states[cur + cstride + 256]; }
    states_in[cur] = s0; states_in[cur + 256] = s1;
    float e = ef[zc];
    s0 = ld0 + e*s0; s1 = ld1 + e*s1;
    ld0 = n0; ld1 = n1;
  }
}

// ---------------------------------------------------------------------------
// K7 (MFMA): per chunk-head SSD Y.  y -> bf16.  512 thr / 8 waves.
// Balanced strips {w, 15-w}; LDS staging from token-major Bm/Cm (vector
// writes); Ww stride-72 no-XOR; dt folded into W'; exp2-scaled cumsum.
// ---------------------------------------------------------------------------
__global__ __launch_bounds__(512) void k_ydiag(
    const float* __restrict__ dt, const ushort* __restrict__ co2,
    const ushort* __restrict__ Bm, const ushort* __restrict__ Cm,
    const float* __restrict__ states_in, const float* __restrict__ A_log,
    const float* __restrict__ ssd_D, ushort* __restrict__ y)
{
  extern __shared__ char smem[];
  float* ac   = (float*)smem;           // 256 (log2-scaled)
  float* dts  = ac + 256;               // 256
  float* segs = dts + 256;              // 8 (4 used)
  ushort* Cb  = (ushort*)(segs + 8);    // 256 x 64   [l][n] swizzled
  ushort* Bb  = Cb + 16384;             // 256 x 64   [s][n] swizzled
  ushort* xsT = Bb + 16384;             // 64 x 256   [p][s] swizzled (pure xh)
  ushort* Sb  = xsT + 16384;            // 64 x 64    [p][n] swizzled
  ushort* Wb  = Sb + 4096;              // 8 x (16 x 72) per-wave [l][s]
  int tid = threadIdx.x;
  int ci = blockIdx.x, h = blockIdx.y, b = blockIdx.z;
  size_t tg = (size_t)b*HW + (size_t)ci*256;
  int w = tid >> 6, lane = tid & 63, lr = lane & 15, kb = lane >> 4;
  float Aneg = -expf(A_log[h]);
  const float LOG2E = 1.44269504088896f;

  // cumsum of dt*A: per-wave shfl scan + segment combine (log2-scaled out)
  float dv = 0.f, a = 0.f;
  if (tid < 256) {
    dv = dt[(tg + tid)*2 + h];
    a = dv*Aneg;
    #pragma unroll
    for (int d = 1; d < 64; d <<= 1) {
      float t = __shfl_up(a, d);
      if (lane >= d) a += t;
    }
    if (lane == 63) segs[w] = a;
  }
  __syncthreads();
  if (tid < 256) {
    float off = 0.f;
    #pragma unroll
    for (int j = 0; j < 4; ++j) if (j < w) off += segs[j];
    ac[tid] = (a + off) * LOG2E;
    dts[tid] = dv;
  }

  // staging (512 threads)
  for (int i = tid; i < 256*16; i += 512) {
    int l = i >> 4, n4 = (i & 15) * 4;
    u16x4 cv = *(const u16x4*)(Cm + (tg + l)*64 + n4);
    *(u16x4*)(Cb + l*64 + swz(l, n4)) = cv;
    u16x4 bv = *(const u16x4*)(Bm + (tg + l)*64 + n4);
    *(u16x4*)(Bb + l*64 + swz(l, n4)) = bv;
  }
  {
    const ushort* ct0 = co2 + ((size_t)(b*512 + (ci << 2)))*16384 + (size_t)h*4096;
    for (int i = tid; i < 64*32; i += 512) {
      int p = i >> 5, sc = (i & 31) * 8;
      u16x8 xv = *(const u16x8*)(ct0 + (size_t)(sc >> 6)*16384 + (size_t)p*64 + (sc & 63));
      *(u16x8*)(xsT + p*256 + swz(p, sc)) = xv;
    }
  }
  size_t sbg = (((size_t)b*NC + ci)*NH + h)*4096;
  for (int i = tid; i < 1024; i += 512) {
    int p = i >> 4, n4 = (i & 15) * 4;
    float4 sv = *(const float4*)(states_in + sbg + p*64 + n4);
    u16x4 pk = { f2b(sv.x), f2b(sv.y), f2b(sv.z), f2b(sv.w) };
    *(u16x4*)(Sb + p*64 + swz(p, n4)) = pk;
  }
  __syncthreads();

  int strips[2] = { w, 15 - w };
  ushort* Ww = Wb + w*1152;   // 16 x 72

  // Y2 = C @ S_in^T (both strips), row-scaled by exp2(ac[l])
  f32x4 yy[2][4];
  #pragma unroll
  for (int sp = 0; sp < 2; ++sp)
    #pragma unroll
    for (int n = 0; n < 4; ++n) yy[sp][n] = (f32x4){0.f,0.f,0.f,0.f};
  #pragma unroll
  for (int kk = 0; kk < 64; kk += 32) {
    bf16x8 af[2], bf[4];
    #pragma unroll
    for (int sp = 0; sp < 2; ++sp) af[sp] = ldfrag(Cb, strips[sp]*16 + lr, kk + kb*8, 64);
    #pragma unroll
    for (int n = 0; n < 4; ++n) bf[n] = ldfrag(Sb, 16*n + lr, kk + kb*8, 64);
    #pragma unroll
    for (int sp = 0; sp < 2; ++sp)
      #pragma unroll
      for (int n = 0; n < 4; ++n)
        yy[sp][n] = __builtin_amdgcn_mfma_f32_16x16x32_bf16(af[sp], bf[n], yy[sp][n], 0, 0, 0);
  }
  #pragma unroll
  for (int sp = 0; sp < 2; ++sp)
    #pragma unroll
    for (int r = 0; r < 4; ++r) {
      float e = exp2f(ac[strips[sp]*16 + kb*4 + r]);
      #pragma unroll
      for (int n = 0; n < 4; ++n) yy[sp][n][r] *= e;
    }

  // per-strip s-tile loop (wave-local; no barriers; W' = tril-decay*G*dts[s])
  #pragma unroll
  for (int sp = 0; sp < 2; ++sp) {
    int strip = strips[sp];
    int l0 = strip*16;
    int nst = (strip >> 2) + 1;
    for (int st = 0; st < nst; ++st) {
      int s0 = st*64;
      f32x4 g[4];
      #pragma unroll
      for (int n = 0; n < 4; ++n) g[n] = (f32x4){0.f,0.f,0.f,0.f};
      #pragma unroll
      for (int kk = 0; kk < 64; kk += 32) {
        bf16x8 af = ldfrag(Cb, l0 + lr, kk + kb*8, 64);
        bf16x8 bf[4];
        #pragma unroll
        for (int n = 0; n < 4; ++n) bf[n] = ldfrag(Bb, s0 + 16*n + lr, kk + kb*8, 64);
        #pragma unroll
        for (int n = 0; n < 4; ++n)
          g[n] = __builtin_amdgcn_mfma_f32_16x16x32_bf16(af, bf[n], g[n], 0, 0, 0);
      }
      #pragma unroll
      for (int r = 0; r < 4; ++r) {
        int lrow = kb*4 + r;
        int lg = l0 + lrow;
        float acl = ac[lg];
        #pragma unroll
        for (int n = 0; n < 4; ++n) {
          int sl = 16*n + lr;
          int sg = s0 + sl;
          float v = (sg <= lg) ? g[n][r] * exp2f(acl - ac[sg]) * dts[sg] : 0.f;
          Ww[lrow*72 + sl] = f2b(v);
        }
      }
      // same-wave LDS write->read: ordered by lgkmcnt, no barrier needed
      #pragma unroll
      for (int kk = 0; kk < 64; kk += 32) {
        bf16x8 af = *(const bf16x8*)(Ww + lr*72 + kk + kb*8);
        bf16x8 bf[4];
        #pragma unroll
        for (int n = 0; n < 4; ++n) bf[n] = ldfrag(xsT, 16*n + lr, s0 + kk + kb*8, 256);
        #pragma unroll
        for (int n = 0; n < 4; ++n)
          yy[sp][n] = __builtin_amdgcn_mfma_f32_16x16x32_bf16(af, bf[n], yy[sp][n], 0, 0, 0);
      }
    }
  }

  // + D*xh and store
  float Dh = ssd_D[h];
  #pragma unroll
  for (int sp = 0; sp < 2; ++sp)
    #pragma unroll
    for (int r = 0; r < 4; ++r) {
      int lg = strips[sp]*16 + kb*4 + r;
      #pragma unroll
      for (int n = 0; n < 4; ++n) {
        int p = 16*n + lr;
        float val = yy[sp][n][r] + Dh * b2f(xsT[p*256 + swz(p, lg)]);
        y[(tg + lg)*128 + h*64 + p] = f2b(val);
      }
    }
}

// ---------------------------------------------------------------------------
// K8 (MFMA): yz = y*silu(z); RMS over 128; out = ctx + yn @ (opw*rms_w)^T.
// ---------------------------------------------------------------------------
__global__ __launch_bounds__(256) void k_final(
    const ushort* __restrict__ y, const ushort* __restrict__ z,
    const ushort* __restrict__ ctxb, const float* __restrict__ rms_w,
    const float* __restrict__ opw, float* __restrict__ out)
{
  __shared__ ushort yn[64*128];    // swizzled [t][k]
  __shared__ ushort wop[64*128];   // swizzled [c][k]
  __shared__ float otile[64*65];
  int tid = threadIdx.x;
  size_t p0 = (size_t)blockIdx.x * 64;

  for (int i = tid; i < 2048; i += 256) {
    int row = i >> 5, c4 = (i & 31) * 4;
    float4 v = ((const float4*)(opw + row*128))[c4 >> 2];
    float4 rw = ((const float4*)rms_w)[c4 >> 2];
    u16x4 p = { f2b(v.x*rw.x), f2b(v.y*rw.y), f2b(v.z*rw.z), f2b(v.w*rw.w) };
    *(u16x4*)(wop + row*128 + swz(row, c4)) = p;
  }

  {
    int t = tid >> 2, q = tid & 3;
    const u16x4* yp = (const u16x4*)(y + (p0 + t)*128 + q*32);
    const u16x4* zp = (const u16x4*)(z + (p0 + t)*128 + q*32);
    float vals[32];
    float ss = 0.f;
    #pragma unroll
    for (int j = 0; j < 8; ++j) {
      u16x4 yv = yp[j];
      u16x4 zv = zp[j];
      #pragma unroll
      for (int e = 0; e < 4; ++e) {
        float zf = b2f(zv[e]);
        float x = b2f(yv[e]) * (zf / (1.f + __expf(-zf)));
        vals[j*4+e] = x; ss += x*x;
      }
    }
    ss += __shfl_xor(ss, 1);
    ss += __shfl_xor(ss, 2);
    float rinv = rsqrtf(ss*(1.f/128.f) + 1e-5f);
    #pragma unroll
    for (int j = 0; j < 8; ++j) {
      int c4 = q*32 + j*4;
      u16x4 p = { f2b(vals[j*4]*rinv), f2b(vals[j*4+1]*rinv),
                  f2b(vals[j*4+2]*rinv), f2b(vals[j*4+3]*rinv) };
      *(u16x4*)(yn + t*128 + swz(t, c4)) = p;
    }
  }
  __syncthreads();

  int w = tid >> 6, lane = tid & 63, lr = lane & 15, kb = lane >> 4;
  f32x4 acc[4];
  #pragma unroll
  for (int n = 0; n < 4; ++n) acc[n] = (f32x4){0.f,0.f,0.f,0.f};
  #pragma unroll
  for (int kk = 0; kk < 128; kk += 32) {
    bf16x8 a = ldfrag(yn, w*16 + lr, kk + kb*8, 128);
    #pragma unroll
    for (int n = 0; n < 4; ++n) {
      bf16x8 bf = ldfrag(wop, n*16 + lr, kk + kb*8, 128);
      acc[n] = __builtin_amdgcn_mfma_f32_16x16x32_bf16(a, bf, acc[n], 0, 0, 0);
    }
  }
  #pragma unroll
  for (int n = 0; n < 4; ++n)
    #pragma unroll
    for (int r = 0; r < 4; ++r) {
      int tok = w*16 + kb*4 + r, ch = n*16 + lr;
      otile[ch*65 + tok] = acc[n][r] + b2f(ctxb[(p0 + tok)*64 + ch]);
    }
  __syncthreads();
  {
    size_t b  = p0 >> 15;
    size_t t0 = p0 & (HW-1);
    for (int r = 0; r < 16; ++r) {
      int cc = r*4 + (tid >> 6);
      int pp = tid & 63;
      out[(b*64 + cc)*HW + t0 + pp] = otile[cc*65 + pp];
    }
  }
}

// ---------------------------------------------------------------------------
extern "C" void kernel_launch(void* const* d_in, const int* in_sizes, int n_in,
                              void* d_out, int out_size, void* d_ws, size_t ws_size,
                              hipStream_t stream) {
  (void)in_sizes; (void)n_in; (void)out_size; (void)ws_size;
  const float* xx   = (const float*)d_in[0];
  const float* sw1  = (const float*)d_in[2];
  const float* sb1  = (const float*)d_in[3];
  const float* sw2  = (const float*)d_in[4];
  const float* sb2  = (const float*)d_in[5];
  const float* vw   = (const float*)d_in[10];
  const float* vb   = (const float*)d_in[11];
  const float* lnw  = (const float*)d_in[12];
  const float* lnb  = (const float*)d_in[13];
  const float* ipw  = (const float*)d_in[14];
  const float* ipb  = (const float*)d_in[15];
  const float* cw   = (const float*)d_in[16];
  const float* cb   = (const float*)d_in[17];
  const float* dtb  = (const float*)d_in[18];
  const float* alog = (const float*)d_in[19];
  const float* sd   = (const float*)d_in[20];
  const float* rmsw = (const float*)d_in[21];
  const float* opw  = (const float*)d_in[22];

  float* ws = (float*)d_ws;
  float*  scores32 = ws;                       // [0, 458752)
  int*    idxb     = (int*)(ws + 458752);      // [458752, 589824)
  int*    cntb     = (int*)(ws + 589824);      // 1
  int*    listb    = (int*)(ws + 589832);      // [589832, 720904)
  float*  dtp      = ws;                       // alias after k_fix (262144 floats)
  ushort* Cmb      = (ushort*)(ws + 917504);   // token-major bf16
  ushort* Bmb      = (ushort*)(ws + 5111808);  // token-major bf16
  ushort* ctxb     = (ushort*)(ws + 9306112);  // bf16 ctx
  ushort* uswb     = (ushort*)(ws + 17694720); // dead after k_gemm
  float*  states   = ws + 17694720;            // alias after k_gemm
  float*  states_in= ws + 21889024;
  ushort* zb       = (ushort*)(ws + 26083328); // [26083328, 34471936)
  ushort* xbcBb    = (ushort*)(ws + 34471936); // tile-blocked
  ushort* co2b     = (ushort*)(ws + 51249152); // tile-blocked
  ushort* yb       = (ushort*)(ws + 68026368);
  float*  Alast    = ws + 84803584;
  ushort* wswb     = (ushort*)(ws + 84804608); // 25600 ushorts

  k_score_mfma<<<1792, 256, 0, stream>>>(xx, sw1, sb1, sw2, sb2, scores32, cntb);
  k_argmax<<<512, 256, 0, stream>>>(scores32, idxb, cntb, listb);
  k_fix<<<512, 256, 0, stream>>>(xx, sw1, sb1, sw2, sb2, cntb, listb, idxb);
  k_fusevln<<<2048, 256, 0, stream>>>(xx, idxb, vw, vb, lnw, lnb, ctxb, uswb);
  k_prep<<<100, 256, 0, stream>>>(ipw, wswb);
  k_gemm<<<512, 512, 0, stream>>>(uswb, wswb, ipb, dtb, zb, xbcBb, dtp);
  k_conv<<<2048, 256, 0, stream>>>(xbcBb, cw, cb, co2b, Bmb, Cmb);
  dim3 gssd(NC, NH, B4);
  k_states<<<gssd, 256, 67584, stream>>>(dtp, co2b, alog, states, Alast);
  k_scan<<<64, 256, 0, stream>>>(states, Alast, states_in);
  k_ydiag<<<gssd, 512, 127008, stream>>>(dtp, co2b, Bmb, Cmb, states_in, alog, sd, yb);
  k_final<<<2048, 256, 0, stream>>>(yb, zb, ctxb, rmsw, opw, (float*)d_out);
}

// Round 18
// 372.176 us; speedup vs baseline: 1.2139x; 1.0240x over previous
//
#include <hip/hip_runtime.h>
#include <cmath>

#define HW 32768      // H*W
#define NC 128        // chunks per batch (HW/256)
#define NH 2          // heads
#define B4 4          // batch (num groups)

typedef __attribute__((ext_vector_type(8))) short bf16x8;
typedef __attribute__((ext_vector_type(4))) float f32x4;
typedef __attribute__((ext_vector_type(4))) ushort u16x4;
typedef __attribute__((ext_vector_type(8))) ushort u16x8;

__device__ __forceinline__ ushort f2b(float x) {
  union { float f; unsigned u; } v; v.f = x;
  unsigned r = v.u + 0x7FFFu + ((v.u >> 16) & 1u);   // RNE
  return (ushort)(r >> 16);
}
__device__ __forceinline__ float b2f(ushort b) {
  union { unsigned u; float f; } v; v.u = ((unsigned)b) << 16;
  return v.f;
}
// XOR-swizzle of element index k within a row (bf16 tiles, 16B-group spread)
__device__ __forceinline__ int swz(int row, int k) { return k ^ ((row & 7) << 3); }
// A-frag: row-major [M][K] (K contig); B-frag: [N][K] (i.e. B^T row-major).
__device__ __forceinline__ bf16x8 ldfrag(const ushort* base, int row, int k, int stride) {
  return *(const bf16x8*)(base + row * stride + swz(row, k));
}

// ---------------------------------------------------------------------------
// K1a (MFMA): score MLP via split-precision weights.
// ---------------------------------------------------------------------------
__global__ __launch_bounds__(256) void k_score_mfma(
    const float* __restrict__ xx, const float* __restrict__ w1,
    const float* __restrict__ b1, const float* __restrict__ w2,
    const float* __restrict__ b2, float* __restrict__ scores,
    int* __restrict__ cnt)
{
  __shared__ ushort Whi[64*64];     // [d][c] swizzled
  __shared__ ushort Wlo[64*64];
  __shared__ ushort Xt[4][64*64];   // per-wave [t][c] swizzled
  __shared__ float w2b1[128];       // w2[0..63] | b1[64..127]
  int tid = threadIdx.x;
  if (blockIdx.x == 0 && tid == 0) cnt[0] = 0;
  for (int i = tid; i < 4096; i += 256) {
    int d = i >> 6, c = i & 63;
    float v = w1[i];
    ushort hi = f2b(v);
    int off = d*64 + swz(d, c);
    Whi[off] = hi;
    Wlo[off] = f2b(v - b2f(hi));
  }
  if (tid < 64) { w2b1[tid] = w2[tid]; w2b1[64+tid] = b1[tid]; }

  int wid = tid >> 6, lane = tid & 63;
  int n  = blockIdx.x >> 7;             // 1792 blocks = 14 n x 128 tiles
  int t0 = (blockIdx.x & 127)*256 + wid*64;

  {
    const float* px = xx + (size_t)n*64*HW + t0 + lane;
    float xv[64];
    #pragma unroll
    for (int c = 0; c < 64; ++c) xv[c] = px[(size_t)c*HW];
    ushort* xh = Xt[wid];
    #pragma unroll
    for (int c8 = 0; c8 < 8; ++c8) {
      u16x8 p;
      #pragma unroll
      for (int j = 0; j < 8; ++j) p[j] = f2b(xv[c8*8 + j]);
      *(u16x8*)(xh + lane*64 + swz(lane, c8*8)) = p;
    }
  }
  __syncthreads();

  int lr = lane & 15, kb = lane >> 4;
  const ushort* xh = Xt[wid];
  f32x4 acc[4][4];
  #pragma unroll
  for (int m = 0; m < 4; ++m)
    #pragma unroll
    for (int nt = 0; nt < 4; ++nt) acc[m][nt] = (f32x4){0.f,0.f,0.f,0.f};
  #pragma unroll
  for (int k0 = 0; k0 < 64; k0 += 32) {
    bf16x8 ah[4], al[4], bx[4];
    #pragma unroll
    for (int m = 0; m < 4; ++m) {
      ah[m] = ldfrag(Whi, 16*m + lr, k0 + kb*8, 64);
      al[m] = ldfrag(Wlo, 16*m + lr, k0 + kb*8, 64);
    }
    #pragma unroll
    for (int nt = 0; nt < 4; ++nt) bx[nt] = ldfrag(xh, 16*nt + lr, k0 + kb*8, 64);
    #pragma unroll
    for (int m = 0; m < 4; ++m)
      #pragma unroll
      for (int nt = 0; nt < 4; ++nt) {
        acc[m][nt] = __builtin_amdgcn_mfma_f32_16x16x32_bf16(ah[m], bx[nt], acc[m][nt], 0, 0, 0);
        acc[m][nt] = __builtin_amdgcn_mfma_f32_16x16x32_bf16(al[m], bx[nt], acc[m][nt], 0, 0, 0);
      }
  }
  float bb2 = b2[0];
  #pragma unroll
  for (int nt = 0; nt < 4; ++nt) {
    float s = 0.f;
    #pragma unroll
    for (int m = 0; m < 4; ++m)
      #pragma unroll
      for (int r = 0; r < 4; ++r) {
        int d = 16*m + kb*4 + r;
        float h = acc[m][nt][r] + w2b1[64 + d];
        s += fmaxf(h, 0.f) * w2b1[d];
      }
    s += __shfl_xor(s, 16);
    s += __shfl_xor(s, 32);
    if (kb == 0) scores[(size_t)n*HW + t0 + 16*nt + lr] = s + bb2;
  }
}

// ---------------------------------------------------------------------------
// K1b: per-(group,pixel) first-max argmax over fp32 scores; flag near-ties.
// ---------------------------------------------------------------------------
__global__ __launch_bounds__(256) void k_argmax(
    const float* __restrict__ scores, int* __restrict__ idx,
    int* __restrict__ cnt, int* __restrict__ list)
{
  int i = blockIdx.x*256 + threadIdx.x;      // 512 blocks: 4*HW
  int g = i >> 15, t = i & (HW-1);
  const int gs0[4] = {0,5,8,12};
  const int gl0[4] = {5,3,4,2};
  int start = gs0[g], len = gl0[g];
  float best = scores[(size_t)start*HW + t];
  float second = -3.4e38f;
  int bi = start;
  for (int j = 1; j < len; ++j) {
    float s = scores[(size_t)(start+j)*HW + t];
    if (s > best) { second = best; best = s; bi = start + j; }
    else if (s > second) second = s;
  }
  idx[i] = bi;
  if (best - second < 5e-4f) {
    int p = atomicAdd(cnt, 1);
    list[p] = i;
  }
}

// ---------------------------------------------------------------------------
// K1c: fp64 recompute of flagged pixels, ONE WAVE PER ENTRY.
// ---------------------------------------------------------------------------
__global__ __launch_bounds__(256) void k_fix(
    const float* __restrict__ xx, const float* __restrict__ w1,
    const float* __restrict__ b1, const float* __restrict__ w2,
    const float* __restrict__ b2, const int* __restrict__ cnt,
    const int* __restrict__ list, int* __restrict__ idx)
{
  __shared__ float w1f[64*65];     // [d][c] padded -> 2-way bank (free)
  __shared__ float w2f[64], b1f[64];
  int tid = threadIdx.x;
  for (int i = tid; i < 4096; i += 256) w1f[(i >> 6)*65 + (i & 63)] = w1[i];
  if (tid < 64) { w2f[tid] = w2[tid]; b1f[tid] = b1[tid]; }
  __syncthreads();
  int n = cnt[0];
  int wid = tid >> 6, lane = tid & 63;
  int nwaves = gridDim.x * 4;
  const int gs0[4] = {0,5,8,12};
  const int gl0[4] = {5,3,4,2};
  double b2d = (double)b2[0];
  for (int e = blockIdx.x*4 + wid; e < n; e += nwaves) {
    int i = list[e];
    int g = i >> 15, t = i & (HW-1);
    int start = gs0[g], len = gl0[g];
    double best = -1e300;
    int bi = start;
    for (int j = 0; j < len; ++j) {
      double xv = (double)xx[(size_t)(start+j)*64*HW + (size_t)lane*HW + t];
      double acc = (double)b1f[lane];
      #pragma unroll
      for (int c = 0; c < 64; ++c) {
        double xc = __shfl(xv, c);
        acc += xc * (double)w1f[lane*65 + c];
      }
      double sc = (acc > 0.0 ? acc : 0.0) * (double)w2f[lane];
      #pragma unroll
      for (int m = 1; m < 64; m <<= 1) sc += __shfl_xor(sc, m);
      sc += b2d;
      if (sc > best) { best = sc; bi = start + j; }   // first-max
    }
    if (lane == 0) idx[i] = bi;
  }
}

// ---------------------------------------------------------------------------
// K2+K3 fused: gather winner -> LDS -> v-proj + LayerNorm. seq never in HBM.
// ---------------------------------------------------------------------------
__global__ __launch_bounds__(256) void k_fusevln(
    const float* __restrict__ xx, const int* __restrict__ idx,
    const float* __restrict__ vw, const float* __restrict__ vb,
    const float* __restrict__ lnw, const float* __restrict__ lnb,
    ushort* __restrict__ ctxb, ushort* __restrict__ usw)
{
  __shared__ int idxs[64];
  __shared__ float tile[64*65];   // [c][t]
  __shared__ float st[64*68];     // [t][c], stride 68 (float4-aligned rows)
  int tid = threadIdx.x;
  int g  = blockIdx.x >> 9;
  int t0 = (blockIdx.x & 511) << 6;
  if (tid < 64) idxs[tid] = idx[(size_t)g*HW + t0 + tid];
  __syncthreads();
  int tl = tid & 63, cq = tid >> 6;
  for (int r = 0; r < 16; ++r) {
    int c = r*4 + cq;
    tile[c*65 + tl] = xx[(size_t)idxs[tl]*64*HW + (size_t)c*HW + t0 + tl];
  }
  __syncthreads();
  for (int r = 0; r < 16; ++r) {
    int row = r*4 + cq;
    st[row*68 + tl] = tile[tl*65 + row];   // bank (4*row+tl)%32: 2-way, free
  }
  int o = tl, wv = cq;
  float w[64];
  const float4* w4 = (const float4*)(vw + o*64);
  #pragma unroll
  for (int c4 = 0; c4 < 16; ++c4) {
    float4 v = w4[c4];
    w[c4*4+0]=v.x; w[c4*4+1]=v.y; w[c4*4+2]=v.z; w[c4*4+3]=v.w;
  }
  float bias = vb[o], lw = lnw[o], lb = lnb[o];
  __syncthreads();
  size_t p0 = (size_t)g*HW + t0;
  for (int j = 0; j < 16; ++j) {
    int p = wv*16 + j;
    const float4* row4 = (const float4*)(st + p*68);
    float acc = bias;
    #pragma unroll
    for (int c4 = 0; c4 < 16; ++c4) {
      float4 s4 = row4[c4];
      acc += s4.x*w[c4*4] + s4.y*w[c4*4+1] + s4.z*w[c4*4+2] + s4.w*w[c4*4+3];
    }
    float s1 = acc, s2 = acc*acc;
    #pragma unroll
    for (int m = 1; m < 64; m <<= 1) {
      s1 += __shfl_xor(s1, m);
      s2 += __shfl_xor(s2, m);
    }
    float mu  = s1*(1.f/64.f);
    float var = s2*(1.f/64.f) - mu*mu;
    float rstd = rsqrtf(var + 1e-5f);
    size_t base = (p0 + p)*64;
    int gt = t0 + p;
    ctxb[base + o] = f2b(acc);
    usw[base + (o ^ (((gt+3)&7)<<3))] = f2b((acc - mu)*rstd*lw + lb);
  }
}

// ---------------------------------------------------------------------------
// k_prep: ipw -> bf16 pre-swizzled wsw (rows >=386 zeroed; 400x64).
// ---------------------------------------------------------------------------
__global__ __launch_bounds__(256) void k_prep(
    const float* __restrict__ ipw, ushort* __restrict__ wsw)
{
  int i = blockIdx.x*256 + threadIdx.x;   // 100*256 = 25600 = 400*64
  int row = i >> 6, c = i & 63;
  float v = (row < 386) ? ipw[row*64 + c] : 0.f;
  wsw[row*64 + swz(row, c)] = f2b(v);
}

// ---------------------------------------------------------------------------
// k_gemm (persistent): 512 blocks, each owns 4 consecutive token tiles.
// ---------------------------------------------------------------------------
__global__ __launch_bounds__(512) void k_gemm(
    const ushort* __restrict__ usw, const ushort* __restrict__ wsw,
    const float* __restrict__ ipb, const float* __restrict__ dtbias,
    ushort* __restrict__ z, ushort* __restrict__ xbcB, float* __restrict__ dt)
{
  __shared__ ushort Wlds[400*64];   // 51200 B (pre-swizzled copy)
  __shared__ ushort Ulds[80*64];    // 10240 B
  __shared__ ushort trans[8704];    // 17408 B
  int tid = threadIdx.x;
  int b     = blockIdx.x >> 7;
  int chunk = blockIdx.x & 127;
  int w = tid >> 6, lane = tid & 63, lr = lane & 15, kb = lane >> 4;

  for (int i = tid; i < 3200; i += 512)
    *(u16x8*)(Wlds + i*8) = *(const u16x8*)(wsw + i*8);

  for (int it = 0; it < 4; ++it) {
    int s = chunk*4 + it;
    int t0 = s << 6;
    size_t pixbase = (size_t)b*HW + t0;
    size_t tilebase = ((size_t)(b*512 + s))*256*64;
    {
      const ushort* ubase = usw + ((size_t)b*HW + t0 - 3)*64;
      for (int i = tid; i < 536; i += 512) {     // 536*8 = 67*64
        u16x8 v;
        if (t0 == 0 && i < 24) v = (u16x8){0,0,0,0,0,0,0,0};
        else v = *(const u16x8*)(ubase + i*8);
        *(u16x8*)(Ulds + i*8) = v;
      }
    }
    __syncthreads();

    for (int rd = 0; rd < 3; ++rd) {
      int nt = rd*8 + w;
      f32x4 acc[5];
      #pragma unroll
      for (int mt = 0; mt < 5; ++mt) acc[mt] = (f32x4){0.f,0.f,0.f,0.f};
      #pragma unroll
      for (int kk = 0; kk < 64; kk += 32) {
        bf16x8 bfrag = ldfrag(Wlds, nt*16 + lr, kk + kb*8, 64);
        #pragma unroll
        for (int mt = 0; mt < 5; ++mt) {
          bf16x8 afrag = ldfrag(Ulds, mt*16 + lr, kk + kb*8, 64);
          acc[mt] = __builtin_amdgcn_mfma_f32_16x16x32_bf16(afrag, bfrag, acc[mt], 0, 0, 0);
        }
      }
      float bias = ipb[nt*16 + lr];
      if (rd == 0) {          // z channels: trans[t][132]
        #pragma unroll
        for (int mt = 0; mt < 5; ++mt)
          #pragma unroll
          for (int r = 0; r < 4; ++r) {
            int t = mt*16 + kb*4 + r - 3;
            if (t >= 0 && t < 64) trans[t*132 + w*16 + lr] = f2b(acc[mt][r] + bias);
          }
      } else {                // xbc channels: trans[ch][68]
        #pragma unroll
        for (int mt = 0; mt < 5; ++mt)
          #pragma unroll
          for (int r = 0; r < 4; ++r) {
            int t = mt*16 + kb*4 + r - 3;
            if (t >= 0 && t < 64) trans[(w*16 + lr)*68 + t] = f2b(acc[mt][r] + bias);
          }
      }
      __syncthreads();
      if (rd == 0) {
        for (int i = tid; i < 2048; i += 512) {
          int t = i >> 5, c4 = (i & 31)*4;
          *(u16x4*)(z + (pixbase + t)*128 + c4) = *(const u16x4*)(trans + t*132 + c4);
        }
      } else {
        int chbase = (rd - 1)*128;
        for (int i = tid; i < 2048; i += 512) {
          int ch = i >> 4, t4 = (i & 15)*4;
          *(u16x4*)(xbcB + tilebase + (size_t)(chbase + ch)*64 + t4)
              = *(const u16x4*)(trans + ch*68 + t4);
        }
      }
      __syncthreads();
    }

    if (w == 0) {    // dt rows 384/385
      f32x4 acc[5];
      #pragma unroll
      for (int mt = 0; mt < 5; ++mt) acc[mt] = (f32x4){0.f,0.f,0.f,0.f};
      #pragma unroll
      for (int kk = 0; kk < 64; kk += 32) {
        bf16x8 bfrag = ldfrag(Wlds, 384 + lr, kk + kb*8, 64);
        #pragma unroll
        for (int mt = 0; mt < 5; ++mt) {
          bf16x8 afrag = ldfrag(Ulds, mt*16 + lr, kk + kb*8, 64);
          acc[mt] = __builtin_amdgcn_mfma_f32_16x16x32_bf16(afrag, bfrag, acc[mt], 0, 0, 0);
        }
      }
      if (lr < 2) {
        float bias = ipb[384 + lr] + dtbias[lr];
        #pragma unroll
        for (int mt = 0; mt < 5; ++mt)
          #pragma unroll
          for (int r = 0; r < 4; ++r) {
            int t = mt*16 + kb*4 + r - 3;
            if (t >= 0 && t < 64) {
              float a = acc[mt][r] + bias;
              dt[(pixbase + t)*2 + lr] = (a > 20.f) ? a : log1pf(expf(a));
            }
          }
      }
    }
    __syncthreads();   // Ulds reuse hazard (dt tail reads it)
  }
}

// ---------------------------------------------------------------------------
// k_conv: depthwise conv(K=4)+silu from tile-blocked xbcB -> co2 tile-blocked
// + Bm/Cm token-major via bank-swizzled LDS transpose.
// ---------------------------------------------------------------------------
__global__ __launch_bounds__(256) void k_conv(
    const ushort* __restrict__ xbcB, const float* __restrict__ convw,
    const float* __restrict__ convb, ushort* __restrict__ co2,
    ushort* __restrict__ Bm, ushort* __restrict__ Cm)
{
  __shared__ ushort bmc[64*132];    // [t][128] swizzled: col = c ^ ((t>>3)<<2)
  int tid = threadIdx.x;
  int b  = blockIdx.x >> 9;
  int s  = blockIdx.x & 511;
  int lane = tid & 63, wv = tid >> 6;
  int toct = lane & 7, chi = lane >> 3;
  size_t tilebase = ((size_t)(b*512 + s))*256*64;
  const ushort* tsrc = xbcB + tilebase;
  const ushort* psrc = xbcB + tilebase - 256*64;   // prev tile (valid if s>0)

  for (int it = 0; it < 8; ++it) {
    int ch = wv*64 + it*8 + chi;
    u16x8 v = *(const u16x8*)(tsrc + ch*64 + toct*8);
    float x0 = b2f(v[0]), x1 = b2f(v[1]), x2 = b2f(v[2]), x3 = b2f(v[3]);
    float x4 = b2f(v[4]), x5 = b2f(v[5]), x6 = b2f(v[6]), x7 = b2f(v[7]);
    float pm1 = __shfl(x7, lane - 1);
    float pm2 = __shfl(x6, lane - 1);
    float pm3 = __shfl(x5, lane - 1);
    if (toct == 0) {
      if (s > 0) {
        u16x4 hq = *(const u16x4*)(psrc + ch*64 + 60);
        pm3 = b2f(hq[1]); pm2 = b2f(hq[2]); pm1 = b2f(hq[3]);
      } else {
        pm1 = pm2 = pm3 = 0.f;
      }
    }
    float4 cw = ((const float4*)convw)[ch];
    float cb = convb[ch];
    float o0 = cb + cw.x*pm3 + cw.y*pm2 + cw.z*pm1 + cw.w*x0;
    float o1 = cb + cw.x*pm2 + cw.y*pm1 + cw.z*x0  + cw.w*x1;
    float o2 = cb + cw.x*pm1 + cw.y*x0  + cw.z*x1  + cw.w*x2;
    float o3 = cb + cw.x*x0  + cw.y*x1  + cw.z*x2  + cw.w*x3;
    float o4 = cb + cw.x*x1  + cw.y*x2  + cw.z*x3  + cw.w*x4;
    float o5 = cb + cw.x*x2  + cw.y*x3  + cw.z*x4  + cw.w*x5;
    float o6 = cb + cw.x*x3  + cw.y*x4  + cw.z*x5  + cw.w*x6;
    float o7 = cb + cw.x*x4  + cw.y*x5  + cw.z*x6  + cw.w*x7;
    u16x8 ov;
    ov[0] = f2b(o0 / (1.f + __expf(-o0)));
    ov[1] = f2b(o1 / (1.f + __expf(-o1)));
    ov[2] = f2b(o2 / (1.f + __expf(-o2)));
    ov[3] = f2b(o3 / (1.f + __expf(-o3)));
    ov[4] = f2b(o4 / (1.f + __expf(-o4)));
    ov[5] = f2b(o5 / (1.f + __expf(-o5)));
    ov[6] = f2b(o6 / (1.f + __expf(-o6)));
    ov[7] = f2b(o7 / (1.f + __expf(-o7)));
    *(u16x8*)(co2 + tilebase + (size_t)ch*64 + toct*8) = ov;
    if (ch >= 128) {
      int c = ch - 128;
      int csw = c ^ (toct << 2);
      #pragma unroll
      for (int j = 0; j < 8; ++j)
        bmc[(toct*8 + j)*132 + csw] = ov[j];
    }
  }
  __syncthreads();
  size_t tg = (size_t)b*HW + s*64;
  for (int i = tid; i < 1024; i += 256) {
    int tt = i >> 4, n4 = (i & 15)*4;
    int sw = (tt >> 3) << 2;
    *(u16x4*)(Bm + (tg + tt)*64 + n4) = *(const u16x4*)(bmc + tt*132 + (n4 ^ sw));
    *(u16x4*)(Cm + (tg + tt)*64 + n4) = *(const u16x4*)(bmc + tt*132 + ((64 + n4) ^ sw));
  }
}

// ---------------------------------------------------------------------------
// K5 (MFMA): states[p,n] = sum_l xd[l,p]*B[l,n]. Reads tile-blocked co2.
// Reg-prefetch staging before shfl-scan cumsum (2 barriers, was 16).
// ---------------------------------------------------------------------------
__global__ __launch_bounds__(256) void k_states(
    const float* __restrict__ dt, const ushort* __restrict__ co2,
    const float* __restrict__ A_log,
    float* __restrict__ states, float* __restrict__ A_last)
{
  extern __shared__ char smem[];
  float* ac   = (float*)smem;           // 256
  float* dec  = ac + 256;               // 256
  float* segs = dec + 256;              // 8 (4 used)
  ushort* xdT = (ushort*)(segs + 8);    // 64 x 256
  ushort* BT  = xdT + 16384;            // 64 x 256
  int tid = threadIdx.x;
  int ci = blockIdx.x, h = blockIdx.y, b = blockIdx.z;
  size_t tg = (size_t)b*HW + (size_t)ci*256;
  int w = tid >> 6, lane = tid & 63;
  float Aneg = -expf(A_log[h]);

  // issue dt load first, then staging loads (overlap with scan)
  float dv = dt[(tg + tid)*2 + h];
  u16x8 xreg[8], breg[8];
  #pragma unroll
  for (int it = 0; it < 8; ++it) {
    int i = tid + it*256;
    int p = i >> 5, lc = (i & 31) * 8;
    int s = (ci << 2) + (lc >> 6);
    const ushort* cb2 = co2 + ((size_t)(b*512 + s))*256*64 + (lc & 63);
    xreg[it] = *(const u16x8*)(cb2 + (size_t)(h*64 + p)*64);
    breg[it] = *(const u16x8*)(cb2 + (size_t)(128 + p)*64);
  }

  // shfl-scan cumsum (2 barriers)
  float a = dv*Aneg;
  #pragma unroll
  for (int d = 1; d < 64; d <<= 1) {
    float t = __shfl_up(a, d);
    if (lane >= d) a += t;
  }
  if (lane == 63) segs[w] = a;
  __syncthreads();
  float off = 0.f;
  #pragma unroll
  for (int j = 0; j < 4; ++j) if (j < w) off += segs[j];
  float acv = a + off;
  float alast = segs[0] + segs[1] + segs[2] + segs[3];
  dec[tid] = dv * __expf(alast - acv);
  __syncthreads();

  // write staged regs to LDS (scale xh by dec)
  #pragma unroll
  for (int it = 0; it < 8; ++it) {
    int i = tid + it*256;
    int p = i >> 5, lc = (i & 31) * 8;
    u16x8 o;
    #pragma unroll
    for (int e = 0; e < 8; ++e) o[e] = f2b(b2f(xreg[it][e]) * dec[lc + e]);
    *(u16x8*)(xdT + p*256 + swz(p, lc)) = o;
    *(u16x8*)(BT + p*256 + swz(p, lc)) = breg[it];
  }
  __syncthreads();

  int lr = lane & 15, kb = lane >> 4;
  f32x4 acc[4];
  #pragma unroll
  for (int m = 0; m < 4; ++m) acc[m] = (f32x4){0.f,0.f,0.f,0.f};
  for (int k0 = 0; k0 < 256; k0 += 32) {
    bf16x8 bfrag = ldfrag(BT, 16*w + lr, k0 + kb*8, 256);
    #pragma unroll
    for (int m = 0; m < 4; ++m) {
      bf16x8 afrag = ldfrag(xdT, 16*m + lr, k0 + kb*8, 256);
      acc[m] = __builtin_amdgcn_mfma_f32_16x16x32_bf16(afrag, bfrag, acc[m], 0, 0, 0);
    }
  }
  size_t sb = (((size_t)b*NC + ci)*NH + h)*4096;
  #pragma unroll
  for (int m = 0; m < 4; ++m)
    #pragma unroll
    for (int r = 0; r < 4; ++r)
      states[sb + (size_t)(16*m + kb*4 + r)*64 + 16*w + lr] = acc[m][r];
  if (tid == 0) A_last[((size_t)b*NH + h)*NC + ci] = alast;
}

// ---------------------------------------------------------------------------
// K6: inter-chunk scan with prefetch; 64 blocks (b,h,seg).
// ---------------------------------------------------------------------------
__global__ __launch_bounds__(256) void k_scan(
    const float* __restrict__ states, const float* __restrict__ A_last,
    float* __restrict__ states_in)
{
  __shared__ float ef[NC];
  int tid = threadIdx.x;
  int seg = blockIdx.x & 7, h = (blockIdx.x >> 3) & 1, b = blockIdx.x >> 4;
  if (tid < NC) ef[tid] = __expf(A_last[((size_t)b*NH + h)*NC + tid]);
  __syncthreads();
  size_t base0 = (((size_t)b*NC)*NH + h)*4096 + seg*512 + tid;
  const size_t cstride = (size_t)NH*4096;
  float s0 = 0.f, s1 = 0.f;
  float ld0 = states[base0], ld1 = states[base0 + 256];
  for (int zc = 0; zc < NC; ++zc) {
    size_t cur = base0 + (size_t)zc*cstride;
    float n0 = 0.f, n1 = 0.f;
    if (zc < NC-1) { n0 = states[cur + cstride]; n1 = states[cur + cstride + 256]; }
    states_in[cur] = s0; states_in[cur + 256] = s1;
    float e = ef[zc];
    s0 = ld0 + e*s0; s1 = ld1 + e*s1;
    ld0 = n0; ld1 = n1;
  }
}

// ---------------------------------------------------------------------------
// K7 (MFMA): per chunk-head SSD Y.  y -> bf16.  512 thr / 8 waves.
// Balanced strips {w, 15-w}; reg-prefetch staging; Ww stride-72; dt in W';
// exp2-scaled cumsum.
// ---------------------------------------------------------------------------
__global__ __launch_bounds__(512) void k_ydiag(
    const float* __restrict__ dt, const ushort* __restrict__ co2,
    const ushort* __restrict__ Bm, const ushort* __restrict__ Cm,
    const float* __restrict__ states_in, const float* __restrict__ A_log,
    const float* __restrict__ ssd_D, ushort* __restrict__ y)
{
  extern __shared__ char smem[];
  float* ac   = (float*)smem;           // 256 (log2-scaled)
  float* dts  = ac + 256;               // 256
  float* segs = dts + 256;              // 8 (4 used)
  ushort* Cb  = (ushort*)(segs + 8);    // 256 x 64   [l][n] swizzled
  ushort* Bb  = Cb + 16384;             // 256 x 64   [s][n] swizzled
  ushort* xsT = Bb + 16384;             // 64 x 256   [p][s] swizzled (pure xh)
  ushort* Sb  = xsT + 16384;            // 64 x 64    [p][n] swizzled
  ushort* Wb  = Sb + 4096;              // 8 x (16 x 72) per-wave [l][s]
  int tid = threadIdx.x;
  int ci = blockIdx.x, h = blockIdx.y, b = blockIdx.z;
  size_t tg = (size_t)b*HW + (size_t)ci*256;
  int w = tid >> 6, lane = tid & 63, lr = lane & 15, kb = lane >> 4;
  float Aneg = -expf(A_log[h]);
  const float LOG2E = 1.44269504088896f;

  // issue dt load + staging loads first (overlap with scan)
  float dv = 0.f;
  if (tid < 256) dv = dt[(tg + tid)*2 + h];
  u16x4 creg[8], breg2[8];
  #pragma unroll
  for (int it = 0; it < 8; ++it) {
    int i = tid + it*512;
    int l = i >> 4, n4 = (i & 15) * 4;
    creg[it] = *(const u16x4*)(Cm + (tg + l)*64 + n4);
    breg2[it] = *(const u16x4*)(Bm + (tg + l)*64 + n4);
  }
  u16x8 xreg[4];
  const ushort* ct0 = co2 + ((size_t)(b*512 + (ci << 2)))*16384 + (size_t)h*4096;
  #pragma unroll
  for (int it = 0; it < 4; ++it) {
    int i = tid + it*512;
    int p = i >> 5, sc = (i & 31) * 8;
    xreg[it] = *(const u16x8*)(ct0 + (size_t)(sc >> 6)*16384 + (size_t)p*64 + (sc & 63));
  }
  size_t sbg = (((size_t)b*NC + ci)*NH + h)*4096;
  float4 sreg[2];
  #pragma unroll
  for (int it = 0; it < 2; ++it) {
    int i = tid + it*512;
    int p = i >> 4, n4 = (i & 15) * 4;
    sreg[it] = *(const float4*)(states_in + sbg + p*64 + n4);
  }

  // shfl-scan cumsum (log2-scaled out)
  float a = 0.f;
  if (tid < 256) {
    a = dv*Aneg;
    #pragma unroll
    for (int d = 1; d < 64; d <<= 1) {
      float t = __shfl_up(a, d);
      if (lane >= d) a += t;
    }
    if (lane == 63) segs[w] = a;
  }
  __syncthreads();
  if (tid < 256) {
    float off = 0.f;
    #pragma unroll
    for (int j = 0; j < 4; ++j) if (j < w) off += segs[j];
    ac[tid] = (a + off) * LOG2E;
    dts[tid] = dv;
  }

  // write staged regs to LDS
  #pragma unroll
  for (int it = 0; it < 8; ++it) {
    int i = tid + it*512;
    int l = i >> 4, n4 = (i & 15) * 4;
    *(u16x4*)(Cb + l*64 + swz(l, n4)) = creg[it];
    *(u16x4*)(Bb + l*64 + swz(l, n4)) = breg2[it];
  }
  #pragma unroll
  for (int it = 0; it < 4; ++it) {
    int i = tid + it*512;
    int p = i >> 5, sc = (i & 31) * 8;
    *(u16x8*)(xsT + p*256 + swz(p, sc)) = xreg[it];
  }
  #pragma unroll
  for (int it = 0; it < 2; ++it) {
    int i = tid + it*512;
    int p = i >> 4, n4 = (i & 15) * 4;
    u16x4 pk = { f2b(sreg[it].x), f2b(sreg[it].y), f2b(sreg[it].z), f2b(sreg[it].w) };
    *(u16x4*)(Sb + p*64 + swz(p, n4)) = pk;
  }
  __syncthreads();

  int strips[2] = { w, 15 - w };
  ushort* Ww = Wb + w*1152;   // 16 x 72

  // Y2 = C @ S_in^T (both strips), row-scaled by exp2(ac[l])
  f32x4 yy[2][4];
  #pragma unroll
  for (int sp = 0; sp < 2; ++sp)
    #pragma unroll
    for (int n = 0; n < 4; ++n) yy[sp][n] = (f32x4){0.f,0.f,0.f,0.f};
  #pragma unroll
  for (int kk = 0; kk < 64; kk += 32) {
    bf16x8 af[2], bf[4];
    #pragma unroll
    for (int sp = 0; sp < 2; ++sp) af[sp] = ldfrag(Cb, strips[sp]*16 + lr, kk + kb*8, 64);
    #pragma unroll
    for (int n = 0; n < 4; ++n) bf[n] = ldfrag(Sb, 16*n + lr, kk + kb*8, 64);
    #pragma unroll
    for (int sp = 0; sp < 2; ++sp)
      #pragma unroll
      for (int n = 0; n < 4; ++n)
        yy[sp][n] = __builtin_amdgcn_mfma_f32_16x16x32_bf16(af[sp], bf[n], yy[sp][n], 0, 0, 0);
  }
  #pragma unroll
  for (int sp = 0; sp < 2; ++sp)
    #pragma unroll
    for (int r = 0; r < 4; ++r) {
      float e = exp2f(ac[strips[sp]*16 + kb*4 + r]);
      #pragma unroll
      for (int n = 0; n < 4; ++n) yy[sp][n][r] *= e;
    }

  // per-strip s-tile loop (wave-local; no barriers; W' = tril-decay*G*dts[s])
  #pragma unroll
  for (int sp = 0; sp < 2; ++sp) {
    int strip = strips[sp];
    int l0 = strip*16;
    int nst = (strip >> 2) + 1;
    for (int st = 0; st < nst; ++st) {
      int s0 = st*64;
      f32x4 g[4];
      #pragma unroll
      for (int n = 0; n < 4; ++n) g[n] = (f32x4){0.f,0.f,0.f,0.f};
      #pragma unroll
      for (int kk = 0; kk < 64; kk += 32) {
        bf16x8 af = ldfrag(Cb, l0 + lr, kk + kb*8, 64);
        bf16x8 bf[4];
        #pragma unroll
        for (int n = 0; n < 4; ++n) bf[n] = ldfrag(Bb, s0 + 16*n + lr, kk + kb*8, 64);
        #pragma unroll
        for (int n = 0; n < 4; ++n)
          g[n] = __builtin_amdgcn_mfma_f32_16x16x32_bf16(af, bf[n], g[n], 0, 0, 0);
      }
      #pragma unroll
      for (int r = 0; r < 4; ++r) {
        int lrow = kb*4 + r;
        int lg = l0 + lrow;
        float acl = ac[lg];
        #pragma unroll
        for (int n = 0; n < 4; ++n) {
          int sl = 16*n + lr;
          int sg = s0 + sl;
          float v = (sg <= lg) ? g[n][r] * exp2f(acl - ac[sg]) * dts[sg] : 0.f;
          Ww[lrow*72 + sl] = f2b(v);
        }
      }
      // same-wave LDS write->read: ordered by lgkmcnt, no barrier needed
      #pragma unroll
      for (int kk = 0; kk < 64; kk += 32) {
        bf16x8 af = *(const bf16x8*)(Ww + lr*72 + kk + kb*8);
        bf16x8 bf[4];
        #pragma unroll
        for (int n = 0; n < 4; ++n) bf[n] = ldfrag(xsT, 16*n + lr, s0 + kk + kb*8, 256);
        #pragma unroll
        for (int n = 0; n < 4; ++n)
          yy[sp][n] = __builtin_amdgcn_mfma_f32_16x16x32_bf16(af, bf[n], yy[sp][n], 0, 0, 0);
      }
    }
  }

  // + D*xh and store
  float Dh = ssd_D[h];
  #pragma unroll
  for (int sp = 0; sp < 2; ++sp)
    #pragma unroll
    for (int r = 0; r < 4; ++r) {
      int lg = strips[sp]*16 + kb*4 + r;
      #pragma unroll
      for (int n = 0; n < 4; ++n) {
        int p = 16*n + lr;
        float val = yy[sp][n][r] + Dh * b2f(xsT[p*256 + swz(p, lg)]);
        y[(tg + lg)*128 + h*64 + p] = f2b(val);
      }
    }
}

// ---------------------------------------------------------------------------
// K8 (MFMA): yz = y*silu(z); RMS over 128; out = ctx + yn @ (opw*rms_w)^T.
// ---------------------------------------------------------------------------
__global__ __launch_bounds__(256) void k_final(
    const ushort* __restrict__ y, const ushort* __restrict__ z,
    const ushort* __restrict__ ctxb, const float* __restrict__ rms_w,
    const float* __restrict__ opw, float* __restrict__ out)
{
  __shared__ ushort yn[64*128];    // swizzled [t][k]
  __shared__ ushort wop[64*128];   // swizzled [c][k]
  __shared__ float otile[64*65];
  int tid = threadIdx.x;
  size_t p0 = (size_t)blockIdx.x * 64;

  for (int i = tid; i < 2048; i += 256) {
    int row = i >> 5, c4 = (i & 31) * 4;
    float4 v = ((const float4*)(opw + row*128))[c4 >> 2];
    float4 rw = ((const float4*)rms_w)[c4 >> 2];
    u16x4 p = { f2b(v.x*rw.x), f2b(v.y*rw.y), f2b(v.z*rw.z), f2b(v.w*rw.w) };
    *(u16x4*)(wop + row*128 + swz(row, c4)) = p;
  }

  {
    int t = tid >> 2, q = tid & 3;
    const u16x4* yp = (const u16x4*)(y + (p0 + t)*128 + q*32);
    const u16x4* zp = (const u16x4*)(z + (p0 + t)*128 + q*32);
    float vals[32];
    float ss = 0.f;
    #pragma unroll
    for (int j = 0; j < 8; ++j) {
      u16x4 yv = yp[j];
      u16x4 zv = zp[j];
      #pragma unroll
      for (int e = 0; e < 4; ++e) {
        float zf = b2f(zv[e]);
        float x = b2f(yv[e]) * (zf / (1.f + __expf(-zf)));
        vals[j*4+e] = x; ss += x*x;
      }
    }
    ss += __shfl_xor(ss, 1);
    ss += __shfl_xor(ss, 2);
    float rinv = rsqrtf(ss*(1.f/128.f) + 1e-5f);
    #pragma unroll
    for (int j = 0; j < 8; ++j) {
      int c4 = q*32 + j*4;
      u16x4 p = { f2b(vals[j*4]*rinv), f2b(vals[j*4+1]*rinv),
                  f2b(vals[j*4+2]*rinv), f2b(vals[j*4+3]*rinv) };
      *(u16x4*)(yn + t*128 + swz(t, c4)) = p;
    }
  }
  __syncthreads();

  int w = tid >> 6, lane = tid & 63, lr = lane & 15, kb = lane >> 4;
  f32x4 acc[4];
  #pragma unroll
  for (int n = 0; n < 4; ++n) acc[n] = (f32x4){0.f,0.f,0.f,0.f};
  #pragma unroll
  for (int kk = 0; kk < 128; kk += 32) {
    bf16x8 a = ldfrag(yn, w*16 + lr, kk + kb*8, 128);
    #pragma unroll
    for (int n = 0; n < 4; ++n) {
      bf16x8 bf = ldfrag(wop, n*16 + lr, kk + kb*8, 128);
      acc[n] = __builtin_amdgcn_mfma_f32_16x16x32_bf16(a, bf, acc[n], 0, 0, 0);
    }
  }
  #pragma unroll
  for (int n = 0; n < 4; ++n)
    #pragma unroll
    for (int r = 0; r < 4; ++r) {
      int tok = w*16 + kb*4 + r, ch = n*16 + lr;
      otile[ch*65 + tok] = acc[n][r] + b2f(ctxb[(p0 + tok)*64 + ch]);
    }
  __syncthreads();
  {
    size_t b  = p0 >> 15;
    size_t t0 = p0 & (HW-1);
    for (int r = 0; r < 16; ++r) {
      int cc = r*4 + (tid >> 6);
      int pp = tid & 63;
      out[(b*64 + cc)*HW + t0 + pp] = otile[cc*65 + pp];
    }
  }
}

// ---------------------------------------------------------------------------
extern "C" void kernel_launch(void* const* d_in, const int* in_sizes, int n_in,
                              void* d_out, int out_size, void* d_ws, size_t ws_size,
                              hipStream_t stream) {
  (void)in_sizes; (void)n_in; (void)out_size; (void)ws_size;
  const float* xx   = (const float*)d_in[0];
  const float* sw1  = (const float*)d_in[2];
  const float* sb1  = (const float*)d_in[3];
  const float* sw2  = (const float*)d_in[4];
  const float* sb2  = (const float*)d_in[5];
  const float* vw   = (const float*)d_in[10];
  const float* vb   = (const float*)d_in[11];
  const float* lnw  = (const float*)d_in[12];
  const float* lnb  = (const float*)d_in[13];
  const float* ipw  = (const float*)d_in[14];
  const float* ipb  = (const float*)d_in[15];
  const float* cw   = (const float*)d_in[16];
  const float* cb   = (const float*)d_in[17];
  const float* dtb  = (const float*)d_in[18];
  const float* alog = (const float*)d_in[19];
  const float* sd   = (const float*)d_in[20];
  const float* rmsw = (const float*)d_in[21];
  const float* opw  = (const float*)d_in[22];

  float* ws = (float*)d_ws;
  float*  scores32 = ws;                       // [0, 458752)
  int*    idxb     = (int*)(ws + 458752);      // [458752, 589824)
  int*    cntb     = (int*)(ws + 589824);      // 1
  int*    listb    = (int*)(ws + 589832);      // [589832, 720904)
  float*  dtp      = ws;                       // alias after k_fix (262144 floats)
  ushort* Cmb      = (ushort*)(ws + 917504);   // token-major bf16
  ushort* Bmb      = (ushort*)(ws + 5111808);  // token-major bf16
  ushort* ctxb     = (ushort*)(ws + 9306112);  // bf16 ctx
  ushort* uswb     = (ushort*)(ws + 17694720); // dead after k_gemm
  float*  states   = ws + 17694720;            // alias after k_gemm
  float*  states_in= ws + 21889024;
  ushort* zb       = (ushort*)(ws + 26083328); // [26083328, 34471936)
  ushort* xbcBb    = (ushort*)(ws + 34471936); // tile-blocked
  ushort* co2b     = (ushort*)(ws + 51249152); // tile-blocked
  ushort* yb       = (ushort*)(ws + 68026368);
  float*  Alast    = ws + 84803584;
  ushort* wswb     = (ushort*)(ws + 84804608); // 25600 ushorts

  k_score_mfma<<<1792, 256, 0, stream>>>(xx, sw1, sb1, sw2, sb2, scores32, cntb);
  k_argmax<<<512, 256, 0, stream>>>(scores32, idxb, cntb, listb);
  k_fix<<<512, 256, 0, stream>>>(xx, sw1, sb1, sw2, sb2, cntb, listb, idxb);
  k_fusevln<<<2048, 256, 0, stream>>>(xx, idxb, vw, vb, lnw, lnb, ctxb, uswb);
  k_prep<<<100, 256, 0, stream>>>(ipw, wswb);
  k_gemm<<<512, 512, 0, stream>>>(uswb, wswb, ipb, dtb, zb, xbcBb, dtp);
  k_conv<<<2048, 256, 0, stream>>>(xbcBb, cw, cb, co2b, Bmb, Cmb);
  dim3 gssd(NC, NH, B4);
  k_states<<<gssd, 256, 67616, stream>>>(dtp, co2b, alog, states, Alast);
  k_scan<<<64, 256, 0, stream>>>(states, Alast, states_in);
  k_ydiag<<<gssd, 512, 127008, stream>>>(dtp, co2b, Bmb, Cmb, states_in, alog, sd, yb);
  k_final<<<2048, 256, 0, stream>>>(yb, zb, ctxb, rmsw, opw, (float*)d_out);
}

// Round 19
// 371.226 us; speedup vs baseline: 1.2170x; 1.0026x over previous
//
#include <hip/hip_runtime.h>
#include <cmath>

#define HW 32768      // H*W
#define NC 128        // chunks per batch (HW/256)
#define NH 2          // heads
#define B4 4          // batch (num groups)

typedef __attribute__((ext_vector_type(8))) short bf16x8;
typedef __attribute__((ext_vector_type(4))) float f32x4;
typedef __attribute__((ext_vector_type(4))) ushort u16x4;
typedef __attribute__((ext_vector_type(8))) ushort u16x8;

__device__ __forceinline__ ushort f2b(float x) {
  union { float f; unsigned u; } v; v.f = x;
  unsigned r = v.u + 0x7FFFu + ((v.u >> 16) & 1u);   // RNE
  return (ushort)(r >> 16);
}
__device__ __forceinline__ float b2f(ushort b) {
  union { unsigned u; float f; } v; v.u = ((unsigned)b) << 16;
  return v.f;
}
// XOR-swizzle of element index k within a row (bf16 tiles, 16B-group spread)
__device__ __forceinline__ int swz(int row, int k) { return k ^ ((row & 7) << 3); }
// A-frag: row-major [M][K] (K contig); B-frag: [N][K] (i.e. B^T row-major).
__device__ __forceinline__ bf16x8 ldfrag(const ushort* base, int row, int k, int stride) {
  return *(const bf16x8*)(base + row * stride + swz(row, k));
}

// ---------------------------------------------------------------------------
// K1a (MFMA): score MLP via split-precision weights.
// ---------------------------------------------------------------------------
__global__ __launch_bounds__(256) void k_score_mfma(
    const float* __restrict__ xx, const float* __restrict__ w1,
    const float* __restrict__ b1, const float* __restrict__ w2,
    const float* __restrict__ b2, float* __restrict__ scores,
    int* __restrict__ cnt)
{
  __shared__ ushort Whi[64*64];     // [d][c] swizzled
  __shared__ ushort Wlo[64*64];
  __shared__ ushort Xt[4][64*64];   // per-wave [t][c] swizzled
  __shared__ float w2b1[128];       // w2[0..63] | b1[64..127]
  int tid = threadIdx.x;
  if (blockIdx.x == 0 && tid == 0) cnt[0] = 0;
  for (int i = tid; i < 4096; i += 256) {
    int d = i >> 6, c = i & 63;
    float v = w1[i];
    ushort hi = f2b(v);
    int off = d*64 + swz(d, c);
    Whi[off] = hi;
    Wlo[off] = f2b(v - b2f(hi));
  }
  if (tid < 64) { w2b1[tid] = w2[tid]; w2b1[64+tid] = b1[tid]; }

  int wid = tid >> 6, lane = tid & 63;
  int n  = blockIdx.x >> 7;             // 1792 blocks = 14 n x 128 tiles
  int t0 = (blockIdx.x & 127)*256 + wid*64;

  {
    const float* px = xx + (size_t)n*64*HW + t0 + lane;
    float xv[64];
    #pragma unroll
    for (int c = 0; c < 64; ++c) xv[c] = px[(size_t)c*HW];
    ushort* xh = Xt[wid];
    #pragma unroll
    for (int c8 = 0; c8 < 8; ++c8) {
      u16x8 p;
      #pragma unroll
      for (int j = 0; j < 8; ++j) p[j] = f2b(xv[c8*8 + j]);
      *(u16x8*)(xh + lane*64 + swz(lane, c8*8)) = p;
    }
  }
  __syncthreads();

  int lr = lane & 15, kb = lane >> 4;
  const ushort* xh = Xt[wid];
  f32x4 acc[4][4];
  #pragma unroll
  for (int m = 0; m < 4; ++m)
    #pragma unroll
    for (int nt = 0; nt < 4; ++nt) acc[m][nt] = (f32x4){0.f,0.f,0.f,0.f};
  #pragma unroll
  for (int k0 = 0; k0 < 64; k0 += 32) {
    bf16x8 ah[4], al[4], bx[4];
    #pragma unroll
    for (int m = 0; m < 4; ++m) {
      ah[m] = ldfrag(Whi, 16*m + lr, k0 + kb*8, 64);
      al[m] = ldfrag(Wlo, 16*m + lr, k0 + kb*8, 64);
    }
    #pragma unroll
    for (int nt = 0; nt < 4; ++nt) bx[nt] = ldfrag(xh, 16*nt + lr, k0 + kb*8, 64);
    #pragma unroll
    for (int m = 0; m < 4; ++m)
      #pragma unroll
      for (int nt = 0; nt < 4; ++nt) {
        acc[m][nt] = __builtin_amdgcn_mfma_f32_16x16x32_bf16(ah[m], bx[nt], acc[m][nt], 0, 0, 0);
        acc[m][nt] = __builtin_amdgcn_mfma_f32_16x16x32_bf16(al[m], bx[nt], acc[m][nt], 0, 0, 0);
      }
  }
  float bb2 = b2[0];
  #pragma unroll
  for (int nt = 0; nt < 4; ++nt) {
    float s = 0.f;
    #pragma unroll
    for (int m = 0; m < 4; ++m)
      #pragma unroll
      for (int r = 0; r < 4; ++r) {
        int d = 16*m + kb*4 + r;
        float h = acc[m][nt][r] + w2b1[64 + d];
        s += fmaxf(h, 0.f) * w2b1[d];
      }
    s += __shfl_xor(s, 16);
    s += __shfl_xor(s, 32);
    if (kb == 0) scores[(size_t)n*HW + t0 + 16*nt + lr] = s + bb2;
  }
}

// ---------------------------------------------------------------------------
// K1b: per-(group,pixel) first-max argmax over fp32 scores; flag near-ties.
// ---------------------------------------------------------------------------
__global__ __launch_bounds__(256) void k_argmax(
    const float* __restrict__ scores, int* __restrict__ idx,
    int* __restrict__ cnt, int* __restrict__ list)
{
  int i = blockIdx.x*256 + threadIdx.x;      // 512 blocks: 4*HW
  int g = i >> 15, t = i & (HW-1);
  const int gs0[4] = {0,5,8,12};
  const int gl0[4] = {5,3,4,2};
  int start = gs0[g], len = gl0[g];
  float best = scores[(size_t)start*HW + t];
  float second = -3.4e38f;
  int bi = start;
  for (int j = 1; j < len; ++j) {
    float s = scores[(size_t)(start+j)*HW + t];
    if (s > best) { second = best; best = s; bi = start + j; }
    else if (s > second) second = s;
  }
  idx[i] = bi;
  if (best - second < 5e-4f) {
    int p = atomicAdd(cnt, 1);
    list[p] = i;
  }
}

// ---------------------------------------------------------------------------
// K1c: fp64 recompute of flagged pixels, ONE WAVE PER ENTRY.
// ---------------------------------------------------------------------------
__global__ __launch_bounds__(256) void k_fix(
    const float* __restrict__ xx, const float* __restrict__ w1,
    const float* __restrict__ b1, const float* __restrict__ w2,
    const float* __restrict__ b2, const int* __restrict__ cnt,
    const int* __restrict__ list, int* __restrict__ idx)
{
  __shared__ float w1f[64*65];     // [d][c] padded -> 2-way bank (free)
  __shared__ float w2f[64], b1f[64];
  int tid = threadIdx.x;
  for (int i = tid; i < 4096; i += 256) w1f[(i >> 6)*65 + (i & 63)] = w1[i];
  if (tid < 64) { w2f[tid] = w2[tid]; b1f[tid] = b1[tid]; }
  __syncthreads();
  int n = cnt[0];
  int wid = tid >> 6, lane = tid & 63;
  int nwaves = gridDim.x * 4;
  const int gs0[4] = {0,5,8,12};
  const int gl0[4] = {5,3,4,2};
  double b2d = (double)b2[0];
  for (int e = blockIdx.x*4 + wid; e < n; e += nwaves) {
    int i = list[e];
    int g = i >> 15, t = i & (HW-1);
    int start = gs0[g], len = gl0[g];
    double best = -1e300;
    int bi = start;
    for (int j = 0; j < len; ++j) {
      double xv = (double)xx[(size_t)(start+j)*64*HW + (size_t)lane*HW + t];
      double acc = (double)b1f[lane];
      #pragma unroll
      for (int c = 0; c < 64; ++c) {
        double xc = __shfl(xv, c);
        acc += xc * (double)w1f[lane*65 + c];
      }
      double sc = (acc > 0.0 ? acc : 0.0) * (double)w2f[lane];
      #pragma unroll
      for (int m = 1; m < 64; m <<= 1) sc += __shfl_xor(sc, m);
      sc += b2d;
      if (sc > best) { best = sc; bi = start + j; }   // first-max
    }
    if (lane == 0) idx[i] = bi;
  }
}

// ---------------------------------------------------------------------------
// K2+K3 fused: gather winner -> LDS -> v-proj + LayerNorm. seq never in HBM.
// ---------------------------------------------------------------------------
__global__ __launch_bounds__(256) void k_fusevln(
    const float* __restrict__ xx, const int* __restrict__ idx,
    const float* __restrict__ vw, const float* __restrict__ vb,
    const float* __restrict__ lnw, const float* __restrict__ lnb,
    ushort* __restrict__ ctxb, ushort* __restrict__ usw)
{
  __shared__ int idxs[64];
  __shared__ float tile[64*65];   // [c][t]
  __shared__ float st[64*68];     // [t][c], stride 68 (float4-aligned rows)
  int tid = threadIdx.x;
  int g  = blockIdx.x >> 9;
  int t0 = (blockIdx.x & 511) << 6;
  if (tid < 64) idxs[tid] = idx[(size_t)g*HW + t0 + tid];
  __syncthreads();
  int tl = tid & 63, cq = tid >> 6;
  for (int r = 0; r < 16; ++r) {
    int c = r*4 + cq;
    tile[c*65 + tl] = xx[(size_t)idxs[tl]*64*HW + (size_t)c*HW + t0 + tl];
  }
  __syncthreads();
  for (int r = 0; r < 16; ++r) {
    int row = r*4 + cq;
    st[row*68 + tl] = tile[tl*65 + row];   // bank (4*row+tl)%32: 2-way, free
  }
  int o = tl, wv = cq;
  float w[64];
  const float4* w4 = (const float4*)(vw + o*64);
  #pragma unroll
  for (int c4 = 0; c4 < 16; ++c4) {
    float4 v = w4[c4];
    w[c4*4+0]=v.x; w[c4*4+1]=v.y; w[c4*4+2]=v.z; w[c4*4+3]=v.w;
  }
  float bias = vb[o], lw = lnw[o], lb = lnb[o];
  __syncthreads();
  size_t p0 = (size_t)g*HW + t0;
  for (int j = 0; j < 16; ++j) {
    int p = wv*16 + j;
    const float4* row4 = (const float4*)(st + p*68);
    float acc = bias;
    #pragma unroll
    for (int c4 = 0; c4 < 16; ++c4) {
      float4 s4 = row4[c4];
      acc += s4.x*w[c4*4] + s4.y*w[c4*4+1] + s4.z*w[c4*4+2] + s4.w*w[c4*4+3];
    }
    float s1 = acc, s2 = acc*acc;
    #pragma unroll
    for (int m = 1; m < 64; m <<= 1) {
      s1 += __shfl_xor(s1, m);
      s2 += __shfl_xor(s2, m);
    }
    float mu  = s1*(1.f/64.f);
    float var = s2*(1.f/64.f) - mu*mu;
    float rstd = rsqrtf(var + 1e-5f);
    size_t base = (p0 + p)*64;
    int gt = t0 + p;
    ctxb[base + o] = f2b(acc);
    usw[base + (o ^ (((gt+3)&7)<<3))] = f2b((acc - mu)*rstd*lw + lb);
  }
}

// ---------------------------------------------------------------------------
// k_prep: ipw -> bf16 pre-swizzled wsw (rows >=386 zeroed; 400x64).
// ---------------------------------------------------------------------------
__global__ __launch_bounds__(256) void k_prep(
    const float* __restrict__ ipw, ushort* __restrict__ wsw)
{
  int i = blockIdx.x*256 + threadIdx.x;   // 100*256 = 25600 = 400*64
  int row = i >> 6, c = i & 63;
  float v = (row < 386) ? ipw[row*64 + c] : 0.f;
  wsw[row*64 + swz(row, c)] = f2b(v);
}

// ---------------------------------------------------------------------------
// k_gemm (persistent): 512 blocks x 4 tiles. W staged once. U double-buffered
// through REGISTERS: next tile's loads issued before current tile's rounds,
// committed to Ulds at the tile boundary (latency hidden under MFMA rounds).
// ---------------------------------------------------------------------------
__global__ __launch_bounds__(512) void k_gemm(
    const ushort* __restrict__ usw, const ushort* __restrict__ wsw,
    const float* __restrict__ ipb, const float* __restrict__ dtbias,
    ushort* __restrict__ z, ushort* __restrict__ xbcB, float* __restrict__ dt)
{
  __shared__ ushort Wlds[400*64];   // 51200 B (pre-swizzled copy)
  __shared__ ushort Ulds[80*64];    // 10240 B
  __shared__ ushort trans[8704];    // 17408 B
  int tid = threadIdx.x;
  int b     = blockIdx.x >> 7;
  int chunk = blockIdx.x & 127;
  int w = tid >> 6, lane = tid & 63, lr = lane & 15, kb = lane >> 4;

  for (int i = tid; i < 3200; i += 512)
    *(u16x8*)(Wlds + i*8) = *(const u16x8*)(wsw + i*8);

  // --- U reg-load helper pattern (i = tid and tid+512 for tid<24) ---
  u16x8 u0, u1;
  {
    int t0 = (chunk*4) << 6;
    const ushort* ubase = usw + ((size_t)b*HW + t0 - 3)*64;
    int i0 = tid;
    u0 = (t0 == 0 && i0 < 24) ? (u16x8){0,0,0,0,0,0,0,0}
                              : *(const u16x8*)(ubase + i0*8);
    if (tid < 24) u1 = *(const u16x8*)(ubase + (tid + 512)*8);
  }
  *(u16x8*)(Ulds + tid*8) = u0;
  if (tid < 24) *(u16x8*)(Ulds + (tid + 512)*8) = u1;
  __syncthreads();

  for (int it = 0; it < 4; ++it) {
    int s = chunk*4 + it;
    int t0 = s << 6;
    size_t pixbase = (size_t)b*HW + t0;
    size_t tilebase = ((size_t)(b*512 + s))*256*64;

    // issue next tile's U loads now; rounds below cover the latency
    if (it < 3) {
      int tn = (s + 1) << 6;
      const ushort* ubase = usw + ((size_t)b*HW + tn - 3)*64;
      u0 = *(const u16x8*)(ubase + tid*8);
      if (tid < 24) u1 = *(const u16x8*)(ubase + (tid + 512)*8);
    }

    for (int rd = 0; rd < 3; ++rd) {
      int nt = rd*8 + w;
      f32x4 acc[5];
      #pragma unroll
      for (int mt = 0; mt < 5; ++mt) acc[mt] = (f32x4){0.f,0.f,0.f,0.f};
      #pragma unroll
      for (int kk = 0; kk < 64; kk += 32) {
        bf16x8 bfrag = ldfrag(Wlds, nt*16 + lr, kk + kb*8, 64);
        #pragma unroll
        for (int mt = 0; mt < 5; ++mt) {
          bf16x8 afrag = ldfrag(Ulds, mt*16 + lr, kk + kb*8, 64);
          acc[mt] = __builtin_amdgcn_mfma_f32_16x16x32_bf16(afrag, bfrag, acc[mt], 0, 0, 0);
        }
      }
      float bias = ipb[nt*16 + lr];
      if (rd == 0) {          // z channels: trans[t][132]
        #pragma unroll
        for (int mt = 0; mt < 5; ++mt)
          #pragma unroll
          for (int r = 0; r < 4; ++r) {
            int t = mt*16 + kb*4 + r - 3;
            if (t >= 0 && t < 64) trans[t*132 + w*16 + lr] = f2b(acc[mt][r] + bias);
          }
      } else {                // xbc channels: trans[ch][68]
        #pragma unroll
        for (int mt = 0; mt < 5; ++mt)
          #pragma unroll
          for (int r = 0; r < 4; ++r) {
            int t = mt*16 + kb*4 + r - 3;
            if (t >= 0 && t < 64) trans[(w*16 + lr)*68 + t] = f2b(acc[mt][r] + bias);
          }
      }
      __syncthreads();
      if (rd == 0) {
        for (int i = tid; i < 2048; i += 512) {
          int t = i >> 5, c4 = (i & 31)*4;
          *(u16x4*)(z + (pixbase + t)*128 + c4) = *(const u16x4*)(trans + t*132 + c4);
        }
      } else {
        int chbase = (rd - 1)*128;
        for (int i = tid; i < 2048; i += 512) {
          int ch = i >> 4, t4 = (i & 15)*4;
          *(u16x4*)(xbcB + tilebase + (size_t)(chbase + ch)*64 + t4)
              = *(const u16x4*)(trans + ch*68 + t4);
        }
      }
      __syncthreads();
    }

    if (w == 0) {    // dt rows 384/385
      f32x4 acc[5];
      #pragma unroll
      for (int mt = 0; mt < 5; ++mt) acc[mt] = (f32x4){0.f,0.f,0.f,0.f};
      #pragma unroll
      for (int kk = 0; kk < 64; kk += 32) {
        bf16x8 bfrag = ldfrag(Wlds, 384 + lr, kk + kb*8, 64);
        #pragma unroll
        for (int mt = 0; mt < 5; ++mt) {
          bf16x8 afrag = ldfrag(Ulds, mt*16 + lr, kk + kb*8, 64);
          acc[mt] = __builtin_amdgcn_mfma_f32_16x16x32_bf16(afrag, bfrag, acc[mt], 0, 0, 0);
        }
      }
      if (lr < 2) {
        float bias = ipb[384 + lr] + dtbias[lr];
        #pragma unroll
        for (int mt = 0; mt < 5; ++mt)
          #pragma unroll
          for (int r = 0; r < 4; ++r) {
            int t = mt*16 + kb*4 + r - 3;
            if (t >= 0 && t < 64) {
              float a = acc[mt][r] + bias;
              dt[(pixbase + t)*2 + lr] = (a > 20.f) ? a : log1pf(expf(a));
            }
          }
      }
    }
    __syncthreads();   // all Ulds reads (incl. dt tail) complete
    if (it < 3) {
      *(u16x8*)(Ulds + tid*8) = u0;
      if (tid < 24) *(u16x8*)(Ulds + (tid + 512)*8) = u1;
      __syncthreads();
    }
  }
}

// ---------------------------------------------------------------------------
// k_conv: depthwise conv(K=4)+silu from tile-blocked xbcB -> co2 tile-blocked
// + Bm/Cm token-major via bank-swizzled LDS transpose.
// ---------------------------------------------------------------------------
__global__ __launch_bounds__(256) void k_conv(
    const ushort* __restrict__ xbcB, const float* __restrict__ convw,
    const float* __restrict__ convb, ushort* __restrict__ co2,
    ushort* __restrict__ Bm, ushort* __restrict__ Cm)
{
  __shared__ ushort bmc[64*132];    // [t][128] swizzled: col = c ^ ((t>>3)<<2)
  int tid = threadIdx.x;
  int b  = blockIdx.x >> 9;
  int s  = blockIdx.x & 511;
  int lane = tid & 63, wv = tid >> 6;
  int toct = lane & 7, chi = lane >> 3;
  size_t tilebase = ((size_t)(b*512 + s))*256*64;
  const ushort* tsrc = xbcB + tilebase;
  const ushort* psrc = xbcB + tilebase - 256*64;   // prev tile (valid if s>0)

  for (int it = 0; it < 8; ++it) {
    int ch = wv*64 + it*8 + chi;
    u16x8 v = *(const u16x8*)(tsrc + ch*64 + toct*8);
    float x0 = b2f(v[0]), x1 = b2f(v[1]), x2 = b2f(v[2]), x3 = b2f(v[3]);
    float x4 = b2f(v[4]), x5 = b2f(v[5]), x6 = b2f(v[6]), x7 = b2f(v[7]);
    float pm1 = __shfl(x7, lane - 1);
    float pm2 = __shfl(x6, lane - 1);
    float pm3 = __shfl(x5, lane - 1);
    if (toct == 0) {
      if (s > 0) {
        u16x4 hq = *(const u16x4*)(psrc + ch*64 + 60);
        pm3 = b2f(hq[1]); pm2 = b2f(hq[2]); pm1 = b2f(hq[3]);
      } else {
        pm1 = pm2 = pm3 = 0.f;
      }
    }
    float4 cw = ((const float4*)convw)[ch];
    float cb = convb[ch];
    float o0 = cb + cw.x*pm3 + cw.y*pm2 + cw.z*pm1 + cw.w*x0;
    float o1 = cb + cw.x*pm2 + cw.y*pm1 + cw.z*x0  + cw.w*x1;
    float o2 = cb + cw.x*pm1 + cw.y*x0  + cw.z*x1  + cw.w*x2;
    float o3 = cb + cw.x*x0  + cw.y*x1  + cw.z*x2  + cw.w*x3;
    float o4 = cb + cw.x*x1  + cw.y*x2  + cw.z*x3  + cw.w*x4;
    float o5 = cb + cw.x*x2  + cw.y*x3  + cw.z*x4  + cw.w*x5;
    float o6 = cb + cw.x*x3  + cw.y*x4  + cw.z*x5  + cw.w*x6;
    float o7 = cb + cw.x*x4  + cw.y*x5  + cw.z*x6  + cw.w*x7;
    u16x8 ov;
    ov[0] = f2b(o0 / (1.f + __expf(-o0)));
    ov[1] = f2b(o1 / (1.f + __expf(-o1)));
    ov[2] = f2b(o2 / (1.f + __expf(-o2)));
    ov[3] = f2b(o3 / (1.f + __expf(-o3)));
    ov[4] = f2b(o4 / (1.f + __expf(-o4)));
    ov[5] = f2b(o5 / (1.f + __expf(-o5)));
    ov[6] = f2b(o6 / (1.f + __expf(-o6)));
    ov[7] = f2b(o7 / (1.f + __expf(-o7)));
    *(u16x8*)(co2 + tilebase + (size_t)ch*64 + toct*8) = ov;
    if (ch >= 128) {
      int c = ch - 128;
      int csw = c ^ (toct << 2);
      #pragma unroll
      for (int j = 0; j < 8; ++j)
        bmc[(toct*8 + j)*132 + csw] = ov[j];
    }
  }
  __syncthreads();
  size_t tg = (size_t)b*HW + s*64;
  for (int i = tid; i < 1024; i += 256) {
    int tt = i >> 4, n4 = (i & 15)*4;
    int sw = (tt >> 3) << 2;
    *(u16x4*)(Bm + (tg + tt)*64 + n4) = *(const u16x4*)(bmc + tt*132 + (n4 ^ sw));
    *(u16x4*)(Cm + (tg + tt)*64 + n4) = *(const u16x4*)(bmc + tt*132 + ((64 + n4) ^ sw));
  }
}

// ---------------------------------------------------------------------------
// K5 (MFMA): states[p,n] = sum_l xd[l,p]*B[l,n]. Reads tile-blocked co2.
// Reg-prefetch staging before shfl-scan cumsum (2 barriers).
// ---------------------------------------------------------------------------
__global__ __launch_bounds__(256) void k_states(
    const float* __restrict__ dt, const ushort* __restrict__ co2,
    const float* __restrict__ A_log,
    float* __restrict__ states, float* __restrict__ A_last)
{
  extern __shared__ char smem[];
  float* ac   = (float*)smem;           // 256
  float* dec  = ac + 256;               // 256
  float* segs = dec + 256;              // 8 (4 used)
  ushort* xdT = (ushort*)(segs + 8);    // 64 x 256
  ushort* BT  = xdT + 16384;            // 64 x 256
  int tid = threadIdx.x;
  int ci = blockIdx.x, h = blockIdx.y, b = blockIdx.z;
  size_t tg = (size_t)b*HW + (size_t)ci*256;
  int w = tid >> 6, lane = tid & 63;
  float Aneg = -expf(A_log[h]);

  // issue dt load first, then staging loads (overlap with scan)
  float dv = dt[(tg + tid)*2 + h];
  u16x8 xreg[8], breg[8];
  #pragma unroll
  for (int it = 0; it < 8; ++it) {
    int i = tid + it*256;
    int p = i >> 5, lc = (i & 31) * 8;
    int s = (ci << 2) + (lc >> 6);
    const ushort* cb2 = co2 + ((size_t)(b*512 + s))*256*64 + (lc & 63);
    xreg[it] = *(const u16x8*)(cb2 + (size_t)(h*64 + p)*64);
    breg[it] = *(const u16x8*)(cb2 + (size_t)(128 + p)*64);
  }

  // shfl-scan cumsum (2 barriers)
  float a = dv*Aneg;
  #pragma unroll
  for (int d = 1; d < 64; d <<= 1) {
    float t = __shfl_up(a, d);
    if (lane >= d) a += t;
  }
  if (lane == 63) segs[w] = a;
  __syncthreads();
  float off = 0.f;
  #pragma unroll
  for (int j = 0; j < 4; ++j) if (j < w) off += segs[j];
  float acv = a + off;
  float alast = segs[0] + segs[1] + segs[2] + segs[3];
  dec[tid] = dv * __expf(alast - acv);
  __syncthreads();

  // write staged regs to LDS (scale xh by dec)
  #pragma unroll
  for (int it = 0; it < 8; ++it) {
    int i = tid + it*256;
    int p = i >> 5, lc = (i & 31) * 8;
    u16x8 o;
    #pragma unroll
    for (int e = 0; e < 8; ++e) o[e] = f2b(b2f(xreg[it][e]) * dec[lc + e]);
    *(u16x8*)(xdT + p*256 + swz(p, lc)) = o;
    *(u16x8*)(BT + p*256 + swz(p, lc)) = breg[it];
  }
  __syncthreads();

  int lr = lane & 15, kb = lane >> 4;
  f32x4 acc[4];
  #pragma unroll
  for (int m = 0; m < 4; ++m) acc[m] = (f32x4){0.f,0.f,0.f,0.f};
  for (int k0 = 0; k0 < 256; k0 += 32) {
    bf16x8 bfrag = ldfrag(BT, 16*w + lr, k0 + kb*8, 256);
    #pragma unroll
    for (int m = 0; m < 4; ++m) {
      bf16x8 afrag = ldfrag(xdT, 16*m + lr, k0 + kb*8, 256);
      acc[m] = __builtin_amdgcn_mfma_f32_16x16x32_bf16(afrag, bfrag, acc[m], 0, 0, 0);
    }
  }
  size_t sb = (((size_t)b*NC + ci)*NH + h)*4096;
  #pragma unroll
  for (int m = 0; m < 4; ++m)
    #pragma unroll
    for (int r = 0; r < 4; ++r)
      states[sb + (size_t)(16*m + kb*4 + r)*64 + 16*w + lr] = acc[m][r];
  if (tid == 0) A_last[((size_t)b*NH + h)*NC + ci] = alast;
}

// ---------------------------------------------------------------------------
// K6: inter-chunk scan with prefetch; 64 blocks (b,h,seg).
// ---------------------------------------------------------------------------
__global__ __launch_bounds__(256) void k_scan(
    const float* __restrict__ states, const float* __restrict__ A_last,
    float* __restrict__ states_in)
{
  __shared__ float ef[NC];
  int tid = threadIdx.x;
  int seg = blockIdx.x & 7, h = (blockIdx.x >> 3) & 1, b = blockIdx.x >> 4;
  if (tid < NC) ef[tid] = __expf(A_last[((size_t)b*NH + h)*NC + tid]);
  __syncthreads();
  size_t base0 = (((size_t)b*NC)*NH + h)*4096 + seg*512 + tid;
  const size_t cstride = (size_t)NH*4096;
  float s0 = 0.f, s1 = 0.f;
  float ld0 = states[base0], ld1 = states[base0 + 256];
  for (int zc = 0; zc < NC; ++zc) {
    size_t cur = base0 + (size_t)zc*cstride;
    float n0 = 0.f, n1 = 0.f;
    if (zc < NC-1) { n0 = states[cur + cstride]; n1 = states[cur + cstride + 256]; }
    states_in[cur] = s0; states_in[cur + 256] = s1;
    float e = ef[zc];
    s0 = ld0 + e*s0; s1 = ld1 + e*s1;
    ld0 = n0; ld1 = n1;
  }
}

// ---------------------------------------------------------------------------
// K7 (MFMA): per chunk-head SSD Y.  y -> bf16.  512 thr / 8 waves.
// Balanced strips {w, 15-w}; reg-prefetch staging; Ww stride-72; dt in W';
// exp2-scaled cumsum.
// ---------------------------------------------------------------------------
__global__ __launch_bounds__(512) void k_ydiag(
    const float* __restrict__ dt, const ushort* __restrict__ co2,
    const ushort* __restrict__ Bm, const ushort* __restrict__ Cm,
    const float* __restrict__ states_in, const float* __restrict__ A_log,
    const float* __restrict__ ssd_D, ushort* __restrict__ y)
{
  extern __shared__ char smem[];
  float* ac   = (float*)smem;           // 256 (log2-scaled)
  float* dts  = ac + 256;               // 256
  float* segs = dts + 256;              // 8 (4 used)
  ushort* Cb  = (ushort*)(segs + 8);    // 256 x 64   [l][n] swizzled
  ushort* Bb  = Cb + 16384;             // 256 x 64   [s][n] swizzled
  ushort* xsT = Bb + 16384;             // 64 x 256   [p][s] swizzled (pure xh)
  ushort* Sb  = xsT + 16384;            // 64 x 64    [p][n] swizzled
  ushort* Wb  = Sb + 4096;              // 8 x (16 x 72) per-wave [l][s]
  int tid = threadIdx.x;
  int ci = blockIdx.x, h = blockIdx.y, b = blockIdx.z;
  size_t tg = (size_t)b*HW + (size_t)ci*256;
  int w = tid >> 6, lane = tid & 63, lr = lane & 15, kb = lane >> 4;
  float Aneg = -expf(A_log[h]);
  const float LOG2E = 1.44269504088896f;

  // issue dt load + staging loads first (overlap with scan)
  float dv = 0.f;
  if (tid < 256) dv = dt[(tg + tid)*2 + h];
  u16x4 creg[8], breg2[8];
  #pragma unroll
  for (int it = 0; it < 8; ++it) {
    int i = tid + it*512;
    int l = i >> 4, n4 = (i & 15) * 4;
    creg[it] = *(const u16x4*)(Cm + (tg + l)*64 + n4);
    breg2[it] = *(const u16x4*)(Bm + (tg + l)*64 + n4);
  }
  u16x8 xreg[4];
  const ushort* ct0 = co2 + ((size_t)(b*512 + (ci << 2)))*16384 + (size_t)h*4096;
  #pragma unroll
  for (int it = 0; it < 4; ++it) {
    int i = tid + it*512;
    int p = i >> 5, sc = (i & 31) * 8;
    xreg[it] = *(const u16x8*)(ct0 + (size_t)(sc >> 6)*16384 + (size_t)p*64 + (sc & 63));
  }
  size_t sbg = (((size_t)b*NC + ci)*NH + h)*4096;
  float4 sreg[2];
  #pragma unroll
  for (int it = 0; it < 2; ++it) {
    int i = tid + it*512;
    int p = i >> 4, n4 = (i & 15) * 4;
    sreg[it] = *(const float4*)(states_in + sbg + p*64 + n4);
  }

  // shfl-scan cumsum (log2-scaled out)
  float a = 0.f;
  if (tid < 256) {
    a = dv*Aneg;
    #pragma unroll
    for (int d = 1; d < 64; d <<= 1) {
      float t = __shfl_up(a, d);
      if (lane >= d) a += t;
    }
    if (lane == 63) segs[w] = a;
  }
  __syncthreads();
  if (tid < 256) {
    float off = 0.f;
    #pragma unroll
    for (int j = 0; j < 4; ++j) if (j < w) off += segs[j];
    ac[tid] = (a + off) * LOG2E;
    dts[tid] = dv;
  }

  // write staged regs to LDS
  #pragma unroll
  for (int it = 0; it < 8; ++it) {
    int i = tid + it*512;
    int l = i >> 4, n4 = (i & 15) * 4;
    *(u16x4*)(Cb + l*64 + swz(l, n4)) = creg[it];
    *(u16x4*)(Bb + l*64 + swz(l, n4)) = breg2[it];
  }
  #pragma unroll
  for (int it = 0; it < 4; ++it) {
    int i = tid + it*512;
    int p = i >> 5, sc = (i & 31) * 8;
    *(u16x8*)(xsT + p*256 + swz(p, sc)) = xreg[it];
  }
  #pragma unroll
  for (int it = 0; it < 2; ++it) {
    int i = tid + it*512;
    int p = i >> 4, n4 = (i & 15) * 4;
    u16x4 pk = { f2b(sreg[it].x), f2b(sreg[it].y), f2b(sreg[it].z), f2b(sreg[it].w) };
    *(u16x4*)(Sb + p*64 + swz(p, n4)) = pk;
  }
  __syncthreads();

  int strips[2] = { w, 15 - w };
  ushort* Ww = Wb + w*1152;   // 16 x 72

  // Y2 = C @ S_in^T (both strips), row-scaled by exp2(ac[l])
  f32x4 yy[2][4];
  #pragma unroll
  for (int sp = 0; sp < 2; ++sp)
    #pragma unroll
    for (int n = 0; n < 4; ++n) yy[sp][n] = (f32x4){0.f,0.f,0.f,0.f};
  #pragma unroll
  for (int kk = 0; kk < 64; kk += 32) {
    bf16x8 af[2], bf[4];
    #pragma unroll
    for (int sp = 0; sp < 2; ++sp) af[sp] = ldfrag(Cb, strips[sp]*16 + lr, kk + kb*8, 64);
    #pragma unroll
    for (int n = 0; n < 4; ++n) bf[n] = ldfrag(Sb, 16*n + lr, kk + kb*8, 64);
    #pragma unroll
    for (int sp = 0; sp < 2; ++sp)
      #pragma unroll
      for (int n = 0; n < 4; ++n)
        yy[sp][n] = __builtin_amdgcn_mfma_f32_16x16x32_bf16(af[sp], bf[n], yy[sp][n], 0, 0, 0);
  }
  #pragma unroll
  for (int sp = 0; sp < 2; ++sp)
    #pragma unroll
    for (int r = 0; r < 4; ++r) {
      float e = exp2f(ac[strips[sp]*16 + kb*4 + r]);
      #pragma unroll
      for (int n = 0; n < 4; ++n) yy[sp][n][r] *= e;
    }

  // per-strip s-tile loop (wave-local; no barriers; W' = tril-decay*G*dts[s])
  #pragma unroll
  for (int sp = 0; sp < 2; ++sp) {
    int strip = strips[sp];
    int l0 = strip*16;
    int nst = (strip >> 2) + 1;
    for (int st = 0; st < nst; ++st) {
      int s0 = st*64;
      f32x4 g[4];
      #pragma unroll
      for (int n = 0; n < 4; ++n) g[n] = (f32x4){0.f,0.f,0.f,0.f};
      #pragma unroll
      for (int kk = 0; kk < 64; kk += 32) {
        bf16x8 af = ldfrag(Cb, l0 + lr, kk + kb*8, 64);
        bf16x8 bf[4];
        #pragma unroll
        for (int n = 0; n < 4; ++n) bf[n] = ldfrag(Bb, s0 + 16*n + lr, kk + kb*8, 64);
        #pragma unroll
        for (int n = 0; n < 4; ++n)
          g[n] = __builtin_amdgcn_mfma_f32_16x16x32_bf16(af, bf[n], g[n], 0, 0, 0);
      }
      #pragma unroll
      for (int r = 0; r < 4; ++r) {
        int lrow = kb*4 + r;
        int lg = l0 + lrow;
        float acl = ac[lg];
        #pragma unroll
        for (int n = 0; n < 4; ++n) {
          int sl = 16*n + lr;
          int sg = s0 + sl;
          float v = (sg <= lg) ? g[n][r] * exp2f(acl - ac[sg]) * dts[sg] : 0.f;
          Ww[lrow*72 + sl] = f2b(v);
        }
      }
      // same-wave LDS write->read: ordered by lgkmcnt, no barrier needed
      #pragma unroll
      for (int kk = 0; kk < 64; kk += 32) {
        bf16x8 af = *(const bf16x8*)(Ww + lr*72 + kk + kb*8);
        bf16x8 bf[4];
        #pragma unroll
        for (int n = 0; n < 4; ++n) bf[n] = ldfrag(xsT, 16*n + lr, s0 + kk + kb*8, 256);
        #pragma unroll
        for (int n = 0; n < 4; ++n)
          yy[sp][n] = __builtin_amdgcn_mfma_f32_16x16x32_bf16(af, bf[n], yy[sp][n], 0, 0, 0);
      }
    }
  }

  // + D*xh and store
  float Dh = ssd_D[h];
  #pragma unroll
  for (int sp = 0; sp < 2; ++sp)
    #pragma unroll
    for (int r = 0; r < 4; ++r) {
      int lg = strips[sp]*16 + kb*4 + r;
      #pragma unroll
      for (int n = 0; n < 4; ++n) {
        int p = 16*n + lr;
        float val = yy[sp][n][r] + Dh * b2f(xsT[p*256 + swz(p, lg)]);
        y[(tg + lg)*128 + h*64 + p] = f2b(val);
      }
    }
}

// ---------------------------------------------------------------------------
// K8 (MFMA): yz = y*silu(z); RMS over 128; out = ctx + yn @ (opw*rms_w)^T.
// ---------------------------------------------------------------------------
__global__ __launch_bounds__(256) void k_final(
    const ushort* __restrict__ y, const ushort* __restrict__ z,
    const ushort* __restrict__ ctxb, const float* __restrict__ rms_w,
    const float* __restrict__ opw, float* __restrict__ out)
{
  __shared__ ushort yn[64*128];    // swizzled [t][k]
  __shared__ ushort wop[64*128];   // swizzled [c][k]
  __shared__ float otile[64*65];
  int tid = threadIdx.x;
  size_t p0 = (size_t)blockIdx.x * 64;

  for (int i = tid; i < 2048; i += 256) {
    int row = i >> 5, c4 = (i & 31) * 4;
    float4 v = ((const float4*)(opw + row*128))[c4 >> 2];
    float4 rw = ((const float4*)rms_w)[c4 >> 2];
    u16x4 p = { f2b(v.x*rw.x), f2b(v.y*rw.y), f2b(v.z*rw.z), f2b(v.w*rw.w) };
    *(u16x4*)(wop + row*128 + swz(row, c4)) = p;
  }

  {
    int t = tid >> 2, q = tid & 3;
    const u16x4* yp = (const u16x4*)(y + (p0 + t)*128 + q*32);
    const u16x4* zp = (const u16x4*)(z + (p0 + t)*128 + q*32);
    float vals[32];
    float ss = 0.f;
    #pragma unroll
    for (int j = 0; j < 8; ++j) {
      u16x4 yv = yp[j];
      u16x4 zv = zp[j];
      #pragma unroll
      for (int e = 0; e < 4; ++e) {
        float zf = b2f(zv[e]);
        float x = b2f(yv[e]) * (zf / (1.f + __expf(-zf)));
        vals[j*4+e] = x; ss += x*x;
      }
    }
    ss += __shfl_xor(ss, 1);
    ss += __shfl_xor(ss, 2);
    float rinv = rsqrtf(ss*(1.f/128.f) + 1e-5f);
    #pragma unroll
    for (int j = 0; j < 8; ++j) {
      int c4 = q*32 + j*4;
      u16x4 p = { f2b(vals[j*4]*rinv), f2b(vals[j*4+1]*rinv),
                  f2b(vals[j*4+2]*rinv), f2b(vals[j*4+3]*rinv) };
      *(u16x4*)(yn + t*128 + swz(t, c4)) = p;
    }
  }
  __syncthreads();

  int w = tid >> 6, lane = tid & 63, lr = lane & 15, kb = lane >> 4;
  f32x4 acc[4];
  #pragma unroll
  for (int n = 0; n < 4; ++n) acc[n] = (f32x4){0.f,0.f,0.f,0.f};
  #pragma unroll
  for (int kk = 0; kk < 128; kk += 32) {
    bf16x8 a = ldfrag(yn, w*16 + lr, kk + kb*8, 128);
    #pragma unroll
    for (int n = 0; n < 4; ++n) {
      bf16x8 bf = ldfrag(wop, n*16 + lr, kk + kb*8, 128);
      acc[n] = __builtin_amdgcn_mfma_f32_16x16x32_bf16(a, bf, acc[n], 0, 0, 0);
    }
  }
  #pragma unroll
  for (int n = 0; n < 4; ++n)
    #pragma unroll
    for (int r = 0; r < 4; ++r) {
      int tok = w*16 + kb*4 + r, ch = n*16 + lr;
      otile[ch*65 + tok] = acc[n][r] + b2f(ctxb[(p0 + tok)*64 + ch]);
    }
  __syncthreads();
  {
    size_t b  = p0 >> 15;
    size_t t0 = p0 & (HW-1);
    for (int r = 0; r < 16; ++r) {
      int cc = r*4 + (tid >> 6);
      int pp = tid & 63;
      out[(b*64 + cc)*HW + t0 + pp] = otile[cc*65 + pp];
    }
  }
}

// ---------------------------------------------------------------------------
extern "C" void kernel_launch(void* const* d_in, const int* in_sizes, int n_in,
                              void* d_out, int out_size, void* d_ws, size_t ws_size,
                              hipStream_t stream) {
  (void)in_sizes; (void)n_in; (void)out_size; (void)ws_size;
  const float* xx   = (const float*)d_in[0];
  const float* sw1  = (const float*)d_in[2];
  const float* sb1  = (const float*)d_in[3];
  const float* sw2  = (const float*)d_in[4];
  const float* sb2  = (const float*)d_in[5];
  const float* vw   = (const float*)d_in[10];
  const float* vb   = (const float*)d_in[11];
  const float* lnw  = (const float*)d_in[12];
  const float* lnb  = (const float*)d_in[13];
  const float* ipw  = (const float*)d_in[14];
  const float* ipb  = (const float*)d_in[15];
  const float* cw   = (const float*)d_in[16];
  const float* cb   = (const float*)d_in[17];
  const float* dtb  = (const float*)d_in[18];
  const float* alog = (const float*)d_in[19];
  const float* sd   = (const float*)d_in[20];
  const float* rmsw = (const float*)d_in[21];
  const float* opw  = (const float*)d_in[22];

  float* ws = (float*)d_ws;
  float*  scores32 = ws;                       // [0, 458752)
  int*    idxb     = (int*)(ws + 458752);      // [458752, 589824)
  int*    cntb     = (int*)(ws + 589824);      // 1
  int*    listb    = (int*)(ws + 589832);      // [589832, 720904)
  float*  dtp      = ws;                       // alias after k_fix (262144 floats)
  ushort* Cmb      = (ushort*)(ws + 917504);   // token-major bf16
  ushort* Bmb      = (ushort*)(ws + 5111808);  // token-major bf16
  ushort* ctxb     = (ushort*)(ws + 9306112);  // bf16 ctx
  ushort* uswb     = (ushort*)(ws + 17694720); // dead after k_gemm
  float*  states   = ws + 17694720;            // alias after k_gemm
  float*  states_in= ws + 21889024;
  ushort* zb       = (ushort*)(ws + 26083328); // [26083328, 34471936)
  ushort* xbcBb    = (ushort*)(ws + 34471936); // tile-blocked
  ushort* co2b     = (ushort*)(ws + 51249152); // tile-blocked
  ushort* yb       = (ushort*)(ws + 68026368);
  float*  Alast    = ws + 84803584;
  ushort* wswb     = (ushort*)(ws + 84804608); // 25600 ushorts

  k_score_mfma<<<1792, 256, 0, stream>>>(xx, sw1, sb1, sw2, sb2, scores32, cntb);
  k_argmax<<<512, 256, 0, stream>>>(scores32, idxb, cntb, listb);
  k_fix<<<512, 256, 0, stream>>>(xx, sw1, sb1, sw2, sb2, cntb, listb, idxb);
  k_fusevln<<<2048, 256, 0, stream>>>(xx, idxb, vw, vb, lnw, lnb, ctxb, uswb);
  k_prep<<<100, 256, 0, stream>>>(ipw, wswb);
  k_gemm<<<512, 512, 0, stream>>>(uswb, wswb, ipb, dtb, zb, xbcBb, dtp);
  k_conv<<<2048, 256, 0, stream>>>(xbcBb, cw, cb, co2b, Bmb, Cmb);
  dim3 gssd(NC, NH, B4);
  k_states<<<gssd, 256, 67616, stream>>>(dtp, co2b, alog, states, Alast);
  k_scan<<<64, 256, 0, stream>>>(states, Alast, states_in);
  k_ydiag<<<gssd, 512, 127008, stream>>>(dtp, co2b, Bmb, Cmb, states_in, alog, sd, yb);
  k_final<<<2048, 256, 0, stream>>>(yb, zb, ctxb, rmsw, opw, (float*)d_out);
}